// Round 2
// baseline (507.615 us; speedup 1.0000x reference)
//
#include <hip/hip_runtime.h>

typedef unsigned short ushort_t;
typedef unsigned int uint_t;
typedef __bf16 bf16x8 __attribute__((ext_vector_type(8)));
typedef float f32x4 __attribute__((ext_vector_type(4)));

#define DIMD 1024
#define FFD 4096
#define NHEAD 16
#define HDIM 64
#define TLEN 2048
#define BATCH 2
#define MROWS (BATCH * TLEN)  // 4096
// 0.125 * log2(e): folds the 1/sqrt(64) scale and exp->exp2 conversion into Q
#define QSCALE 0.18033688011112042f

__device__ __forceinline__ ushort_t f2b(float f) {
    uint_t u = __builtin_bit_cast(uint_t, f);
    u = u + 0x7fffu + ((u >> 16) & 1u);
    return (ushort_t)(u >> 16);
}
__device__ __forceinline__ float b2f(ushort_t b) {
    uint_t u = ((uint_t)b) << 16;
    return __builtin_bit_cast(float, u);
}
__device__ __forceinline__ bf16x8 ld8(const ushort_t* p) {
    uint4 v = *(const uint4*)(p);
    return __builtin_bit_cast(bf16x8, v);
}
__device__ __forceinline__ f32x4 mfma16(bf16x8 a, bf16x8 b, f32x4 c) {
    return __builtin_amdgcn_mfma_f32_16x16x32_bf16(a, b, c, 0, 0, 0);
}
__device__ __forceinline__ uint_t cvtpk(float lo, float hi) {
    uint_t r;
    asm("v_cvt_pk_bf16_f32 %0, %1, %2" : "=v"(r) : "v"(lo), "v"(hi));
    return r;
}
__device__ __forceinline__ void gload16(const void* g, void* l) {
    __builtin_amdgcn_global_load_lds(
        (const __attribute__((address_space(1))) void*)g,
        (__attribute__((address_space(3))) void*)l, 16, 0, 0);
}

// ---------------- transpose + fp32->bf16 convert: out[C][R] = in[R][C] ----------------
__global__ __launch_bounds__(256) void transpose_cvt_kernel(
    const float* __restrict__ in, ushort_t* __restrict__ out, int R, int C) {
    __shared__ float tile[32][33];
    const int c0 = blockIdx.x * 32, r0 = blockIdx.y * 32;
    const int tx = threadIdx.x, ty = threadIdx.y;  // 32 x 8
#pragma unroll
    for (int i = 0; i < 4; ++i)
        tile[ty + i * 8][tx] = in[(size_t)(r0 + ty + i * 8) * C + c0 + tx];
    __syncthreads();
#pragma unroll
    for (int i = 0; i < 4; ++i)
        out[(size_t)(c0 + ty + i * 8) * R + r0 + tx] = f2b(tile[tx][ty + i * 8]);
}

// ---------------- rope tables: cos/sin [T][32] ----------------
__global__ __launch_bounds__(256) void rope_tables_kernel(float* __restrict__ cosv,
                                                          float* __restrict__ sinv) {
    int idx = blockIdx.x * 256 + threadIdx.x;  // T*32
    int i = idx & 31;
    int t = idx >> 5;
    float invf = powf(10000.0f, -(float)i / 32.0f);
    float a = (float)t * invf;
    cosv[idx] = cosf(a);
    sinv[idx] = sinf(a);
}

// ---------------- pack qkv bias ----------------
__global__ __launch_bounds__(256) void pack_bias_kernel(const float* __restrict__ bq,
                                                        const float* __restrict__ bk,
                                                        const float* __restrict__ bv,
                                                        float* __restrict__ out) {
    int i = blockIdx.x * 256 + threadIdx.x;
    if (i < 3072) {
        float v = (i < 1024) ? bq[i] : (i < 2048) ? bk[i - 1024] : bv[i - 2048];
        out[i] = v;
    }
}

// ---------------- layernorm fp32 -> bf16, one row (1024) per block ----------------
__global__ __launch_bounds__(256) void ln_kernel(const float* __restrict__ x,
                                                 const float* __restrict__ g,
                                                 const float* __restrict__ bta,
                                                 ushort_t* __restrict__ out) {
    const int row = blockIdx.x;
    const int tid = threadIdx.x;
    const float4 v = *(const float4*)(x + (size_t)row * DIMD + tid * 4);
    float s = v.x + v.y + v.z + v.w;
    float sq = v.x * v.x + v.y * v.y + v.z * v.z + v.w * v.w;
#pragma unroll
    for (int off = 1; off < 64; off <<= 1) {
        s += __shfl_xor(s, off);
        sq += __shfl_xor(sq, off);
    }
    __shared__ float rs[4], rq[4];
    const int wave = tid >> 6;
    if ((tid & 63) == 0) { rs[wave] = s; rq[wave] = sq; }
    __syncthreads();
    s = rs[0] + rs[1] + rs[2] + rs[3];
    sq = rq[0] + rq[1] + rq[2] + rq[3];
    const float mean = s * (1.0f / DIMD);
    const float var = sq * (1.0f / DIMD) - mean * mean;
    const float rstd = rsqrtf(var + 1e-5f);
    const float4 gv = *(const float4*)(g + tid * 4);
    const float4 bv = *(const float4*)(bta + tid * 4);
    ushort_t o[4];
    o[0] = f2b((v.x - mean) * rstd * gv.x + bv.x);
    o[1] = f2b((v.y - mean) * rstd * gv.y + bv.y);
    o[2] = f2b((v.z - mean) * rstd * gv.z + bv.z);
    o[3] = f2b((v.w - mean) * rstd * gv.w + bv.w);
    *(uint2*)(out + (size_t)row * DIMD + tid * 4) = *(uint2*)&o[0];
}

// ---------------- GEMM (m97 structure): C = A[M][K] * Bt[N][K]^T + bias ----------------
// 128x128 tile, BK=64, global_load_lds staging, 4 waves 2x2, each 64x64
template <bool GELU, bool RES, bool OUTBF16>
__global__ __launch_bounds__(256) void gemm_kernel(
    const ushort_t* __restrict__ A, const ushort_t* __restrict__ Bt,
    const float* __restrict__ bias, const float* __restrict__ res,
    float* __restrict__ outf, ushort_t* __restrict__ outb, int M, int N, int K) {
    __shared__ __align__(16) ushort_t Asm[128 * 64];
    __shared__ __align__(16) ushort_t Bsm[128 * 64];
    const int tid = threadIdx.x;
    const int lane = tid & 63;
    const int wave = tid >> 6;
    const int wr = (wave >> 1) * 64;
    const int wc = (wave & 1) * 64;
    const int bm = blockIdx.y * 128;
    const int bn = blockIdx.x * 128;
    const int lrow = lane & 15;
    const int lk = (lane >> 4) * 8;
    const int srow = lane >> 3;        // 0..7
    const int scol = (lane & 7) * 8;   // elems

    f32x4 acc[4][4] = {};

    for (int k0 = 0; k0 < K; k0 += 64) {
        __syncthreads();  // previous iteration's reads done
#pragma unroll
        for (int i = 0; i < 4; ++i) {
            const int rowi = (wave * 4 + i) * 8 + srow;
            gload16(A + (size_t)(bm + rowi) * K + k0 + scol,
                    (char*)Asm + (wave * 4 + i) * 1024);
            gload16(Bt + (size_t)(bn + rowi) * K + k0 + scol,
                    (char*)Bsm + (wave * 4 + i) * 1024);
        }
        __syncthreads();  // staging complete (compiler drains vmcnt)
#pragma unroll
        for (int s = 0; s < 2; ++s) {
            bf16x8 af[4], bfr[4];
#pragma unroll
            for (int i = 0; i < 4; ++i)
                af[i] = ld8(Asm + (wr + i * 16 + lrow) * 64 + s * 32 + lk);
#pragma unroll
            for (int j = 0; j < 4; ++j)
                bfr[j] = ld8(Bsm + (wc + j * 16 + lrow) * 64 + s * 32 + lk);
#pragma unroll
            for (int i = 0; i < 4; ++i)
#pragma unroll
                for (int j = 0; j < 4; ++j)
                    acc[i][j] = mfma16(af[i], bfr[j], acc[i][j]);
        }
    }

    const int lr4 = (lane >> 4) * 4;
#pragma unroll
    for (int i = 0; i < 4; ++i) {
#pragma unroll
        for (int j = 0; j < 4; ++j) {
#pragma unroll
            for (int q = 0; q < 4; ++q) {
                const int row = bm + wr + i * 16 + lr4 + q;
                const int col = bn + wc + j * 16 + lrow;
                float v = acc[i][j][q] + bias[col];
                if (RES) v += res[(size_t)row * N + col];
                if (GELU) v = 0.5f * v * (1.0f + erff(v * 0.70710678118f));
                if (OUTBF16)
                    outb[(size_t)row * N + col] = f2b(v);
                else
                    outf[(size_t)row * N + col] = v;
            }
        }
    }
}

// ---------------- rope apply (Q scaled by QSCALE) -> Qb,Kb [bh][t][d] bf16 ----------------
__global__ __launch_bounds__(256) void rope_apply_kernel(
    const ushort_t* __restrict__ qkv, const float* __restrict__ cosv,
    const float* __restrict__ sinv, ushort_t* __restrict__ Qb,
    ushort_t* __restrict__ Kb) {
    const int idx = blockIdx.x * 256 + threadIdx.x;  // B*H*T*32
    const int i = idx & 31;
    const int t = (idx >> 5) & (TLEN - 1);
    const int bh = idx >> 16;
    const int b = bh >> 4, h = bh & 15;
    const size_t rowoff = ((size_t)(b * TLEN + t)) * 3072 + h * 64;
    const float q1 = b2f(qkv[rowoff + i]);
    const float q2 = b2f(qkv[rowoff + 32 + i]);
    const float k1 = b2f(qkv[rowoff + 1024 + i]);
    const float k2 = b2f(qkv[rowoff + 1024 + 32 + i]);
    const float c = cosv[t * 32 + i];
    const float s = sinv[t * 32 + i];
    const size_t ooff = ((size_t)bh * TLEN + t) * 64;
    Qb[ooff + i] = f2b((q1 * c - q2 * s) * QSCALE);
    Qb[ooff + 32 + i] = f2b((q2 * c + q1 * s) * QSCALE);
    Kb[ooff + i] = f2b(k1 * c - k2 * s);
    Kb[ooff + 32 + i] = f2b(k2 * c + k1 * s);
}

// ---------------- V transpose: qkv V-section -> VtG[bh][d][t] bf16 ----------------
__global__ __launch_bounds__(256) void transpose_v_kernel(
    const ushort_t* __restrict__ qkv, ushort_t* __restrict__ VtG) {
    __shared__ ushort_t tile[64][72];
    const int bh = blockIdx.y;
    const int b = bh >> 4, h = bh & 15;
    const int t0 = blockIdx.x * 64;
    const int tid = threadIdx.x;
    const int r = tid >> 2;
    const int dp = (tid & 3) * 16;
    const ushort_t* src = qkv + (size_t)(b * TLEN + t0 + r) * 3072 + 2048 + h * 64 + dp;
    *(uint4*)&tile[r][dp] = *(const uint4*)src;
    *(uint4*)&tile[r][dp + 8] = *(const uint4*)(src + 8);
    __syncthreads();
    const int d = tid >> 2;
    const int tp = (tid & 3) * 16;
    ushort_t* dst = VtG + (size_t)bh * HDIM * TLEN + (size_t)d * TLEN + t0 + tp;
    ushort_t tmp[16];
#pragma unroll
    for (int j = 0; j < 16; ++j) tmp[j] = tile[tp + j][d];
    *(uint4*)dst = *(uint4*)&tmp[0];
    *(uint4*)(dst + 8) = *(uint4*)&tmp[8];
}

// ---------------- flash attention v2: swapped QK^T, lane-local softmax, no LDS ----------------
// grid (T/64, B*H), 256 threads; wave owns 16 q rows (q = lane&15), KVBLK=64
__global__ __launch_bounds__(256) void flash_kernel(const ushort_t* __restrict__ Qb,
                                                    const ushort_t* __restrict__ Kb,
                                                    const ushort_t* __restrict__ VtG,
                                                    ushort_t* __restrict__ attn) {
    const int bh = blockIdx.y;
    const int b = bh >> 4, h = bh & 15;
    const int lane = threadIdx.x & 63;
    const int wave = threadIdx.x >> 6;
    const int q0 = blockIdx.x * 64 + wave * 16;
    const int lrow = lane & 15;
    const int g = lane >> 4;
    const int lk = g * 8;

    const ushort_t* Qp = Qb + ((size_t)bh * TLEN + q0) * HDIM;
    const ushort_t* Kp = Kb + (size_t)bh * TLEN * HDIM;
    const ushort_t* Vt = VtG + (size_t)bh * HDIM * TLEN;

    // Q as B-operand: B[k=d][col=q]
    bf16x8 bq0 = ld8(Qp + lrow * 64 + lk);
    bf16x8 bq1 = ld8(Qp + lrow * 64 + 32 + lk);

    f32x4 o[4] = {};
    float m = -1e30f, l = 0.0f;

    const int srcA = lrow + ((g & 1) << 5);
    const int srcB = srcA + 16;
    const int csel = g >> 1;

    for (int kb = 0; kb < TLEN; kb += 64) {
        // S^T[key][q], key tiles kt: lane holds keys kt*16+g*4+{0..3} for q=lrow
        f32x4 s[4];
#pragma unroll
        for (int kt = 0; kt < 4; ++kt) {
            const ushort_t* kp = Kp + (size_t)(kb + kt * 16 + lrow) * 64 + lk;
            f32x4 a = {};
            a = mfma16(ld8(kp), bq0, a);
            a = mfma16(ld8(kp + 32), bq1, a);
            s[kt] = a;
        }
        // row max: 16 local + cross-g (lanes lrow, lrow+16, lrow+32, lrow+48)
        float pm = s[0][0];
#pragma unroll
        for (int kt = 0; kt < 4; ++kt)
#pragma unroll
            for (int r = 0; r < 4; ++r) pm = fmaxf(pm, s[kt][r]);
        pm = fmaxf(pm, __shfl_xor(pm, 16));
        pm = fmaxf(pm, __shfl_xor(pm, 32));
        const float mn = fmaxf(m, pm);
        const float alpha = exp2f(m - mn);
        m = mn;
        float rs = 0.0f;
        uint_t pk0[4], pk1[4];
#pragma unroll
        for (int kt = 0; kt < 4; ++kt) {
            const float p0 = exp2f(s[kt][0] - mn);
            const float p1 = exp2f(s[kt][1] - mn);
            const float p2 = exp2f(s[kt][2] - mn);
            const float p3 = exp2f(s[kt][3] - mn);
            rs += (p0 + p1) + (p2 + p3);
            pk0[kt] = cvtpk(p0, p1);
            pk1[kt] = cvtpk(p2, p3);
        }
        rs += __shfl_xor(rs, 16);
        rs += __shfl_xor(rs, 32);
        l = l * alpha + rs;
#pragma unroll
        for (int n = 0; n < 4; ++n)
#pragma unroll
            for (int r = 0; r < 4; ++r) o[n][r] *= alpha;
        // PV: redistribute P into B-operand layout, V^T rows from global
#pragma unroll
        for (int ks = 0; ks < 2; ++ks) {
            const int ktA = 2 * ks, ktB = 2 * ks + 1;
            const uint_t d0a = (uint_t)__shfl((int)pk0[ktA], srcA);
            const uint_t d0b = (uint_t)__shfl((int)pk0[ktB], srcA);
            const uint_t d1a = (uint_t)__shfl((int)pk1[ktA], srcA);
            const uint_t d1b = (uint_t)__shfl((int)pk1[ktB], srcA);
            const uint_t d2a = (uint_t)__shfl((int)pk0[ktA], srcB);
            const uint_t d2b = (uint_t)__shfl((int)pk0[ktB], srcB);
            const uint_t d3a = (uint_t)__shfl((int)pk1[ktA], srcB);
            const uint_t d3b = (uint_t)__shfl((int)pk1[ktB], srcB);
            uint4 bp;
            bp.x = csel ? d0b : d0a;
            bp.y = csel ? d1b : d1a;
            bp.z = csel ? d2b : d2a;
            bp.w = csel ? d3b : d3a;
            const bf16x8 bpf = __builtin_bit_cast(bf16x8, bp);
#pragma unroll
            for (int n = 0; n < 4; ++n) {
                const bf16x8 av = ld8(Vt + (size_t)(n * 16 + lrow) * TLEN + kb + ks * 32 + lk);
                o[n] = mfma16(av, bpf, o[n]);
            }
        }
    }
    const float inv_l = 1.0f / l;
    const int qrow = b * TLEN + q0 + lrow;
#pragma unroll
    for (int n = 0; n < 4; ++n) {
        ushort_t o4[4];
#pragma unroll
        for (int r = 0; r < 4; ++r) o4[r] = f2b(o[n][r] * inv_l);
        *(uint2*)(attn + (size_t)qrow * DIMD + h * HDIM + n * 16 + g * 4) = *(uint2*)&o4[0];
    }
}

extern "C" void kernel_launch(void* const* d_in, const int* in_sizes, int n_in,
                              void* d_out, int out_size, void* d_ws, size_t ws_size,
                              hipStream_t stream) {
    const float* x = (const float*)d_in[0];
    const float* ln1_g = (const float*)d_in[2];
    const float* ln1_b = (const float*)d_in[3];
    const float* Wq = (const float*)d_in[4];
    const float* bq = (const float*)d_in[5];
    const float* Wk = (const float*)d_in[6];
    const float* bk = (const float*)d_in[7];
    const float* Wv = (const float*)d_in[8];
    const float* bv = (const float*)d_in[9];
    const float* Wo = (const float*)d_in[10];
    const float* bo = (const float*)d_in[11];
    const float* ln2_g = (const float*)d_in[12];
    const float* ln2_b = (const float*)d_in[13];
    const float* W1 = (const float*)d_in[14];
    const float* b1 = (const float*)d_in[15];
    const float* W2 = (const float*)d_in[16];
    const float* b2 = (const float*)d_in[17];
    float* out = (float*)d_out;

    char* p = (char*)d_ws;
    ushort_t* wt_qkv = (ushort_t*)p; p += (size_t)3072 * 1024 * 2;
    ushort_t* wot = (ushort_t*)p;    p += (size_t)1024 * 1024 * 2;
    ushort_t* w1t = (ushort_t*)p;    p += (size_t)4096 * 1024 * 2;
    ushort_t* w2t = (ushort_t*)p;    p += (size_t)4096 * 1024 * 2;
    float* cosv = (float*)p;         p += (size_t)TLEN * 32 * 4;
    float* sinv = (float*)p;         p += (size_t)TLEN * 32 * 4;
    float* bias_qkv = (float*)p;     p += 3072 * 4;
    ushort_t* n1 = (ushort_t*)p;     p += (size_t)MROWS * DIMD * 2;
    ushort_t* qkv = (ushort_t*)p;    p += (size_t)MROWS * 3072 * 2;
    ushort_t* Qb = (ushort_t*)p;     p += (size_t)MROWS * DIMD * 2;
    ushort_t* Kb = (ushort_t*)p;     p += (size_t)MROWS * DIMD * 2;
    ushort_t* VtG = (ushort_t*)p;    p += (size_t)MROWS * DIMD * 2;
    ushort_t* attn = (ushort_t*)p;   p += (size_t)MROWS * DIMD * 2;
    float* x1 = (float*)p;           p += (size_t)MROWS * DIMD * 4;
    ushort_t* n2 = (ushort_t*)p;     p += (size_t)MROWS * DIMD * 2;
    ushort_t* ff1 = (ushort_t*)p;    p += (size_t)MROWS * FFD * 2;

    dim3 tb(32, 8);
    transpose_cvt_kernel<<<dim3(32, 32), tb, 0, stream>>>(Wq, wt_qkv, 1024, 1024);
    transpose_cvt_kernel<<<dim3(32, 32), tb, 0, stream>>>(Wk, wt_qkv + (size_t)1024 * 1024, 1024, 1024);
    transpose_cvt_kernel<<<dim3(32, 32), tb, 0, stream>>>(Wv, wt_qkv + (size_t)2048 * 1024, 1024, 1024);
    transpose_cvt_kernel<<<dim3(32, 32), tb, 0, stream>>>(Wo, wot, 1024, 1024);
    transpose_cvt_kernel<<<dim3(128, 32), tb, 0, stream>>>(W1, w1t, 1024, 4096);
    transpose_cvt_kernel<<<dim3(32, 128), tb, 0, stream>>>(W2, w2t, 4096, 1024);
    rope_tables_kernel<<<TLEN * 32 / 256, 256, 0, stream>>>(cosv, sinv);
    pack_bias_kernel<<<12, 256, 0, stream>>>(bq, bk, bv, bias_qkv);
    ln_kernel<<<MROWS, 256, 0, stream>>>(x, ln1_g, ln1_b, n1);
    gemm_kernel<false, false, true><<<dim3(3072 / 128, MROWS / 128), 256, 0, stream>>>(
        n1, wt_qkv, bias_qkv, nullptr, nullptr, qkv, MROWS, 3072, 1024);
    rope_apply_kernel<<<BATCH * NHEAD * TLEN * 32 / 256, 256, 0, stream>>>(qkv, cosv, sinv, Qb, Kb);
    transpose_v_kernel<<<dim3(TLEN / 64, BATCH * NHEAD), 256, 0, stream>>>(qkv, VtG);
    flash_kernel<<<dim3(TLEN / 64, BATCH * NHEAD), 256, 0, stream>>>(Qb, Kb, VtG, attn);
    gemm_kernel<false, true, false><<<dim3(1024 / 128, MROWS / 128), 256, 0, stream>>>(
        attn, wot, bo, x, x1, nullptr, MROWS, 1024, 1024);
    ln_kernel<<<MROWS, 256, 0, stream>>>(x1, ln2_g, ln2_b, n2);
    gemm_kernel<true, false, true><<<dim3(4096 / 128, MROWS / 128), 256, 0, stream>>>(
        n2, w1t, b1, nullptr, nullptr, ff1, MROWS, 4096, 1024);
    gemm_kernel<false, true, false><<<dim3(1024 / 128, MROWS / 128), 256, 0, stream>>>(
        ff1, w2t, b2, x1, out, nullptr, MROWS, 1024, 4096);
}

// Round 3
// 352.922 us; speedup vs baseline: 1.4383x; 1.4383x over previous
//
#include <hip/hip_runtime.h>

typedef unsigned short ushort_t;
typedef unsigned int uint_t;
typedef __bf16 bf16x8 __attribute__((ext_vector_type(8)));
typedef float f32x4 __attribute__((ext_vector_type(4)));

#define DIMD 1024
#define FFD 4096
#define NHEAD 16
#define HDIM 64
#define TLEN 2048
#define BATCH 2
#define MROWS (BATCH * TLEN)  // 4096
// 0.125 * log2(e): folds the 1/sqrt(64) scale and exp->exp2 conversion into Q
#define QSCALE 0.18033688011112042f

__device__ __forceinline__ ushort_t f2b(float f) {
    uint_t u = __builtin_bit_cast(uint_t, f);
    u = u + 0x7fffu + ((u >> 16) & 1u);
    return (ushort_t)(u >> 16);
}
__device__ __forceinline__ float b2f(ushort_t b) {
    uint_t u = ((uint_t)b) << 16;
    return __builtin_bit_cast(float, u);
}
__device__ __forceinline__ bf16x8 ld8(const ushort_t* p) {
    uint4 v = *(const uint4*)(p);
    return __builtin_bit_cast(bf16x8, v);
}
__device__ __forceinline__ f32x4 mfma16(bf16x8 a, bf16x8 b, f32x4 c) {
    return __builtin_amdgcn_mfma_f32_16x16x32_bf16(a, b, c, 0, 0, 0);
}
__device__ __forceinline__ uint_t cvtpk(float lo, float hi) {
    uint_t r;
    asm("v_cvt_pk_bf16_f32 %0, %1, %2" : "=v"(r) : "v"(lo), "v"(hi));
    return r;
}
__device__ __forceinline__ void gload16(const void* g, void* l) {
    __builtin_amdgcn_global_load_lds(
        (const __attribute__((address_space(1))) void*)g,
        (__attribute__((address_space(3))) void*)l, 16, 0, 0);
}

// ---------------- transpose + fp32->bf16 convert: out[C][R] = in[R][C] ----------------
__global__ __launch_bounds__(256) void transpose_cvt_kernel(
    const float* __restrict__ in, ushort_t* __restrict__ out, int R, int C) {
    __shared__ float tile[32][33];
    const int c0 = blockIdx.x * 32, r0 = blockIdx.y * 32;
    const int tx = threadIdx.x, ty = threadIdx.y;  // 32 x 8
#pragma unroll
    for (int i = 0; i < 4; ++i)
        tile[ty + i * 8][tx] = in[(size_t)(r0 + ty + i * 8) * C + c0 + tx];
    __syncthreads();
#pragma unroll
    for (int i = 0; i < 4; ++i)
        out[(size_t)(c0 + ty + i * 8) * R + r0 + tx] = f2b(tile[tx][ty + i * 8]);
}

// ---------------- rope tables: cos/sin [T][32] ----------------
__global__ __launch_bounds__(256) void rope_tables_kernel(float* __restrict__ cosv,
                                                          float* __restrict__ sinv) {
    int idx = blockIdx.x * 256 + threadIdx.x;  // T*32
    int i = idx & 31;
    int t = idx >> 5;
    float invf = powf(10000.0f, -(float)i / 32.0f);
    float a = (float)t * invf;
    cosv[idx] = cosf(a);
    sinv[idx] = sinf(a);
}

// ---------------- pack qkv bias ----------------
__global__ __launch_bounds__(256) void pack_bias_kernel(const float* __restrict__ bq,
                                                        const float* __restrict__ bk,
                                                        const float* __restrict__ bv,
                                                        float* __restrict__ out) {
    int i = blockIdx.x * 256 + threadIdx.x;
    if (i < 3072) {
        float v = (i < 1024) ? bq[i] : (i < 2048) ? bk[i - 1024] : bv[i - 2048];
        out[i] = v;
    }
}

// ---------------- layernorm fp32 -> bf16, one row (1024) per block ----------------
__global__ __launch_bounds__(256) void ln_kernel(const float* __restrict__ x,
                                                 const float* __restrict__ g,
                                                 const float* __restrict__ bta,
                                                 ushort_t* __restrict__ out) {
    const int row = blockIdx.x;
    const int tid = threadIdx.x;
    const float4 v = *(const float4*)(x + (size_t)row * DIMD + tid * 4);
    float s = v.x + v.y + v.z + v.w;
    float sq = v.x * v.x + v.y * v.y + v.z * v.z + v.w * v.w;
#pragma unroll
    for (int off = 1; off < 64; off <<= 1) {
        s += __shfl_xor(s, off);
        sq += __shfl_xor(sq, off);
    }
    __shared__ float rs[4], rq[4];
    const int wave = tid >> 6;
    if ((tid & 63) == 0) { rs[wave] = s; rq[wave] = sq; }
    __syncthreads();
    s = rs[0] + rs[1] + rs[2] + rs[3];
    sq = rq[0] + rq[1] + rq[2] + rq[3];
    const float mean = s * (1.0f / DIMD);
    const float var = sq * (1.0f / DIMD) - mean * mean;
    const float rstd = rsqrtf(var + 1e-5f);
    const float4 gv = *(const float4*)(g + tid * 4);
    const float4 bv = *(const float4*)(bta + tid * 4);
    ushort_t o[4];
    o[0] = f2b((v.x - mean) * rstd * gv.x + bv.x);
    o[1] = f2b((v.y - mean) * rstd * gv.y + bv.y);
    o[2] = f2b((v.z - mean) * rstd * gv.z + bv.z);
    o[3] = f2b((v.w - mean) * rstd * gv.w + bv.w);
    *(uint2*)(out + (size_t)row * DIMD + tid * 4) = *(uint2*)&o[0];
}

// ---------------- GEMM: 2-phase dbuf, BK=32 ----------------
// C = A[M][K](bf16) * Bt[N][K](bf16)^T + bias; 128x128 tile, 4 waves 2x2
template <bool GELU, bool RES, bool OUTBF16>
__global__ __launch_bounds__(256) void gemm_kernel(
    const ushort_t* __restrict__ A, const ushort_t* __restrict__ Bt,
    const float* __restrict__ bias, const float* __restrict__ res,
    float* __restrict__ outf, ushort_t* __restrict__ outb, int M, int N, int K) {
    __shared__ __align__(16) ushort_t Asm[2][128 * 32];
    __shared__ __align__(16) ushort_t Bsm[2][128 * 32];
    const int tid = threadIdx.x;
    const int lane = tid & 63;
    const int wave = tid >> 6;
    const int wr = (wave >> 1) * 64;
    const int wc = (wave & 1) * 64;
    const int bm = blockIdx.y * 128;
    const int bn = blockIdx.x * 128;
    const int lrow = lane & 15;
    const int lk = (lane >> 4) * 8;

    // stage addressing: chunk ch covers LDS bytes [ch*1024, ch*1024+1024)
    // linear: row = o>>6 (64B rows), colbyte = o&63  (no swizzle: 64B rows self-rotate banks)
    const int ch = wave * 2;
    const int o0 = (ch << 10) + lane * 16;
    const int o1 = ((ch + 1) << 10) + lane * 16;
    const int r0s = o0 >> 6, r1s = o1 >> 6;
    const ushort_t* Ag0 = A + (size_t)(bm + r0s) * K + ((o0 & 63) >> 1);
    const ushort_t* Ag1 = A + (size_t)(bm + r1s) * K + ((o1 & 63) >> 1);
    const ushort_t* Bg0 = Bt + (size_t)(bn + r0s) * K + ((o0 & 63) >> 1);
    const ushort_t* Bg1 = Bt + (size_t)(bn + r1s) * K + ((o1 & 63) >> 1);

#define GEMM_STAGE(buf, k0)                                        \
    {                                                              \
        gload16(Ag0 + (k0), (char*)Asm[buf] + (ch << 10));         \
        gload16(Ag1 + (k0), (char*)Asm[buf] + ((ch + 1) << 10));   \
        gload16(Bg0 + (k0), (char*)Bsm[buf] + (ch << 10));         \
        gload16(Bg1 + (k0), (char*)Bsm[buf] + ((ch + 1) << 10));   \
    }

    f32x4 acc[4][4] = {};
    const int nst = K >> 5;

    GEMM_STAGE(0, 0);
    __syncthreads();  // drains vmcnt: buf0 ready
    for (int t = 0; t < nst; ++t) {
        const int buf = t & 1;
        if (t + 1 < nst) GEMM_STAGE(buf ^ 1, (t + 1) << 5);
        bf16x8 af[4], bfr[4];
#pragma unroll
        for (int i = 0; i < 4; ++i)
            af[i] = ld8(Asm[buf] + (wr + i * 16 + lrow) * 32 + lk);
#pragma unroll
        for (int j = 0; j < 4; ++j)
            bfr[j] = ld8(Bsm[buf] + (wc + j * 16 + lrow) * 32 + lk);
        __builtin_amdgcn_s_setprio(1);
#pragma unroll
        for (int i = 0; i < 4; ++i)
#pragma unroll
            for (int j = 0; j < 4; ++j)
                acc[i][j] = mfma16(af[i], bfr[j], acc[i][j]);
        __builtin_amdgcn_s_setprio(0);
        __syncthreads();  // drains vmcnt: next buf staged; reads of buf done
    }
#undef GEMM_STAGE

    const int lr4 = (lane >> 4) * 4;
#pragma unroll
    for (int i = 0; i < 4; ++i) {
#pragma unroll
        for (int j = 0; j < 4; ++j) {
#pragma unroll
            for (int q = 0; q < 4; ++q) {
                const int row = bm + wr + i * 16 + lr4 + q;
                const int col = bn + wc + j * 16 + lrow;
                float v = acc[i][j][q] + bias[col];
                if (RES) v += res[(size_t)row * N + col];
                if (GELU) v = 0.5f * v * (1.0f + erff(v * 0.70710678118f));
                if (OUTBF16)
                    outb[(size_t)row * N + col] = f2b(v);
                else
                    outf[(size_t)row * N + col] = v;
            }
        }
    }
}

// ---------------- rope apply (Q scaled by QSCALE) -> Qb,Kb [bh][t][d] bf16 ----------------
__global__ __launch_bounds__(256) void rope_apply_kernel(
    const ushort_t* __restrict__ qkv, const float* __restrict__ cosv,
    const float* __restrict__ sinv, ushort_t* __restrict__ Qb,
    ushort_t* __restrict__ Kb) {
    const int idx = blockIdx.x * 256 + threadIdx.x;  // B*H*T*32
    const int i = idx & 31;
    const int t = (idx >> 5) & (TLEN - 1);
    const int bh = idx >> 16;
    const int b = bh >> 4, h = bh & 15;
    const size_t rowoff = ((size_t)(b * TLEN + t)) * 3072 + h * 64;
    const float q1 = b2f(qkv[rowoff + i]);
    const float q2 = b2f(qkv[rowoff + 32 + i]);
    const float k1 = b2f(qkv[rowoff + 1024 + i]);
    const float k2 = b2f(qkv[rowoff + 1024 + 32 + i]);
    const float c = cosv[t * 32 + i];
    const float s = sinv[t * 32 + i];
    const size_t ooff = ((size_t)bh * TLEN + t) * 64;
    Qb[ooff + i] = f2b((q1 * c - q2 * s) * QSCALE);
    Qb[ooff + 32 + i] = f2b((q2 * c + q1 * s) * QSCALE);
    Kb[ooff + i] = f2b(k1 * c - k2 * s);
    Kb[ooff + 32 + i] = f2b(k2 * c + k1 * s);
}

// ---------------- V transpose: qkv V-section -> VtG[bh][d][t] bf16 ----------------
__global__ __launch_bounds__(256) void transpose_v_kernel(
    const ushort_t* __restrict__ qkv, ushort_t* __restrict__ VtG) {
    __shared__ ushort_t tile[64][72];
    const int bh = blockIdx.y;
    const int b = bh >> 4, h = bh & 15;
    const int t0 = blockIdx.x * 64;
    const int tid = threadIdx.x;
    const int r = tid >> 2;
    const int dp = (tid & 3) * 16;
    const ushort_t* src = qkv + (size_t)(b * TLEN + t0 + r) * 3072 + 2048 + h * 64 + dp;
    *(uint4*)&tile[r][dp] = *(const uint4*)src;
    *(uint4*)&tile[r][dp + 8] = *(const uint4*)(src + 8);
    __syncthreads();
    const int d = tid >> 2;
    const int tp = (tid & 3) * 16;
    ushort_t* dst = VtG + (size_t)bh * HDIM * TLEN + (size_t)d * TLEN + t0 + tp;
    ushort_t tmp[16];
#pragma unroll
    for (int j = 0; j < 16; ++j) tmp[j] = tile[tp + j][d];
    *(uint4*)dst = *(uint4*)&tmp[0];
    *(uint4*)(dst + 8) = *(uint4*)&tmp[8];
}

// ---------------- flash attention v3: LDS-staged K/V^T, 2-phase dbuf ----------------
// grid (T/64, B*H), 256 threads; wave owns 16 q rows (q = lane&15), KVBLK=64
// K tile [64 keys][64 d], V^T tile [64 d][64 keys]; both 128B rows with
// both-sides XOR swizzle (cb ^= (row&7)<<4): pre-swizzled global source +
// linear gload_lds dest + swizzled ds_read addr (rule #21).
__global__ __launch_bounds__(256) void flash_kernel(const ushort_t* __restrict__ Qb,
                                                    const ushort_t* __restrict__ Kb,
                                                    const ushort_t* __restrict__ VtG,
                                                    ushort_t* __restrict__ attn) {
    __shared__ __align__(16) ushort_t Ksm[2][64 * 64];
    __shared__ __align__(16) ushort_t Vsm[2][64 * 64];
    const int bh = blockIdx.y;
    const int b = bh >> 4, h = bh & 15;
    const int lane = threadIdx.x & 63;
    const int wave = threadIdx.x >> 6;
    const int q0 = blockIdx.x * 64 + wave * 16;
    const int lrow = lane & 15;
    const int g = lane >> 4;
    const int lk = g * 8;

    const ushort_t* Qp = Qb + ((size_t)bh * TLEN + q0) * HDIM;
    const ushort_t* Kp = Kb + (size_t)bh * TLEN * HDIM;
    const ushort_t* Vt = VtG + (size_t)bh * HDIM * TLEN;

    // staging addresses (hoisted): chunk ch -> LDS bytes [ch*1024, +1024)
    // row = o>>7 (128B rows), swizzled global col byte cb = (o&127) ^ ((row&7)<<4)
    const int ch0 = wave * 2, ch1 = wave * 2 + 1;
    const int so0 = (ch0 << 10) + lane * 16;
    const int so1 = (ch1 << 10) + lane * 16;
    const int sr0 = so0 >> 7, sr1 = so1 >> 7;
    const int cb0 = (so0 & 127) ^ ((sr0 & 7) << 4);
    const int cb1 = (so1 & 127) ^ ((sr1 & 7) << 4);
    const ushort_t* Kg0 = Kp + (size_t)sr0 * HDIM + (cb0 >> 1);
    const ushort_t* Kg1 = Kp + (size_t)sr1 * HDIM + (cb1 >> 1);
    const ushort_t* Vg0 = Vt + (size_t)sr0 * TLEN + (cb0 >> 1);
    const ushort_t* Vg1 = Vt + (size_t)sr1 * TLEN + (cb1 >> 1);

#define FLASH_STAGE(buf, kb)                                         \
    {                                                                \
        gload16(Kg0 + (size_t)(kb) * HDIM, (char*)Ksm[buf] + (ch0 << 10)); \
        gload16(Kg1 + (size_t)(kb) * HDIM, (char*)Ksm[buf] + (ch1 << 10)); \
        gload16(Vg0 + (kb), (char*)Vsm[buf] + (ch0 << 10));          \
        gload16(Vg1 + (kb), (char*)Vsm[buf] + (ch1 << 10));          \
    }

    // Q as B-operand: B[k=d][col=q]
    bf16x8 bq0 = ld8(Qp + lrow * 64 + lk);
    bf16x8 bq1 = ld8(Qp + lrow * 64 + 32 + lk);

    f32x4 o[4] = {};
    float m = -1e30f, l = 0.0f;

    const int srcA = lrow + ((g & 1) << 5);
    const int srcB = srcA + 16;
    const int csel = g >> 1;

    FLASH_STAGE(0, 0);
    __syncthreads();  // drains vmcnt: buf0 ready

    for (int it = 0; it < TLEN / 64; ++it) {
        const int buf = it & 1;
        if (it + 1 < TLEN / 64) FLASH_STAGE(buf ^ 1, (it + 1) * 64);

        // S^T[key][q]: lane holds keys kt*16+g*4+{0..3} for q=lrow
        f32x4 s[4];
        __builtin_amdgcn_s_setprio(1);
#pragma unroll
        for (int kt = 0; kt < 4; ++kt) {
            const int r = kt * 16 + lrow;
            const int sw = (r & 7) << 4;
            const char* krow = (const char*)(Ksm[buf] + r * 64);
            f32x4 a = {};
            a = mfma16(ld8((const ushort_t*)(krow + ((lk * 2) ^ sw))), bq0, a);
            a = mfma16(ld8((const ushort_t*)(krow + ((64 + lk * 2) ^ sw))), bq1, a);
            s[kt] = a;
        }
        __builtin_amdgcn_s_setprio(0);
        // row max across the 4 lanes holding this q-row
        float pm = s[0][0];
#pragma unroll
        for (int kt = 0; kt < 4; ++kt)
#pragma unroll
            for (int r = 0; r < 4; ++r) pm = fmaxf(pm, s[kt][r]);
        pm = fmaxf(pm, __shfl_xor(pm, 16));
        pm = fmaxf(pm, __shfl_xor(pm, 32));
        const float mn = fmaxf(m, pm);
        const float alpha = exp2f(m - mn);
        m = mn;
        float rs = 0.0f;
        uint_t pk0[4], pk1[4];
#pragma unroll
        for (int kt = 0; kt < 4; ++kt) {
            const float p0 = exp2f(s[kt][0] - mn);
            const float p1 = exp2f(s[kt][1] - mn);
            const float p2 = exp2f(s[kt][2] - mn);
            const float p3 = exp2f(s[kt][3] - mn);
            rs += (p0 + p1) + (p2 + p3);
            pk0[kt] = cvtpk(p0, p1);
            pk1[kt] = cvtpk(p2, p3);
        }
        rs += __shfl_xor(rs, 16);
        rs += __shfl_xor(rs, 32);
        l = l * alpha + rs;
#pragma unroll
        for (int n = 0; n < 4; ++n)
#pragma unroll
            for (int r = 0; r < 4; ++r) o[n][r] *= alpha;
        // PV: redistribute P into B-operand layout, V^T rows from LDS
#pragma unroll
        for (int ks = 0; ks < 2; ++ks) {
            const int ktA = 2 * ks, ktB = 2 * ks + 1;
            const uint_t d0a = (uint_t)__shfl((int)pk0[ktA], srcA);
            const uint_t d0b = (uint_t)__shfl((int)pk0[ktB], srcA);
            const uint_t d1a = (uint_t)__shfl((int)pk1[ktA], srcA);
            const uint_t d1b = (uint_t)__shfl((int)pk1[ktB], srcA);
            const uint_t d2a = (uint_t)__shfl((int)pk0[ktA], srcB);
            const uint_t d2b = (uint_t)__shfl((int)pk0[ktB], srcB);
            const uint_t d3a = (uint_t)__shfl((int)pk1[ktA], srcB);
            const uint_t d3b = (uint_t)__shfl((int)pk1[ktB], srcB);
            uint4 bp;
            bp.x = csel ? d0b : d0a;
            bp.y = csel ? d1b : d1a;
            bp.z = csel ? d2b : d2a;
            bp.w = csel ? d3b : d3a;
            const bf16x8 bpf = __builtin_bit_cast(bf16x8, bp);
            __builtin_amdgcn_s_setprio(1);
#pragma unroll
            for (int n = 0; n < 4; ++n) {
                const int r = n * 16 + lrow;
                const int sw = (r & 7) << 4;
                const char* vrow = (const char*)(Vsm[buf] + r * 64);
                const bf16x8 av =
                    ld8((const ushort_t*)(vrow + ((ks * 64 + lk * 2) ^ sw)));
                o[n] = mfma16(av, bpf, o[n]);
            }
            __builtin_amdgcn_s_setprio(0);
        }
        __syncthreads();  // drains vmcnt: next buf staged; reads of buf done
    }
#undef FLASH_STAGE

    const float inv_l = 1.0f / l;
    const int qrow = b * TLEN + q0 + lrow;
#pragma unroll
    for (int n = 0; n < 4; ++n) {
        ushort_t o4[4];
#pragma unroll
        for (int r = 0; r < 4; ++r) o4[r] = f2b(o[n][r] * inv_l);
        *(uint2*)(attn + (size_t)qrow * DIMD + h * HDIM + n * 16 + g * 4) = *(uint2*)&o4[0];
    }
}

extern "C" void kernel_launch(void* const* d_in, const int* in_sizes, int n_in,
                              void* d_out, int out_size, void* d_ws, size_t ws_size,
                              hipStream_t stream) {
    const float* x = (const float*)d_in[0];
    const float* ln1_g = (const float*)d_in[2];
    const float* ln1_b = (const float*)d_in[3];
    const float* Wq = (const float*)d_in[4];
    const float* bq = (const float*)d_in[5];
    const float* Wk = (const float*)d_in[6];
    const float* bk = (const float*)d_in[7];
    const float* Wv = (const float*)d_in[8];
    const float* bv = (const float*)d_in[9];
    const float* Wo = (const float*)d_in[10];
    const float* bo = (const float*)d_in[11];
    const float* ln2_g = (const float*)d_in[12];
    const float* ln2_b = (const float*)d_in[13];
    const float* W1 = (const float*)d_in[14];
    const float* b1 = (const float*)d_in[15];
    const float* W2 = (const float*)d_in[16];
    const float* b2 = (const float*)d_in[17];
    float* out = (float*)d_out;

    char* p = (char*)d_ws;
    ushort_t* wt_qkv = (ushort_t*)p; p += (size_t)3072 * 1024 * 2;
    ushort_t* wot = (ushort_t*)p;    p += (size_t)1024 * 1024 * 2;
    ushort_t* w1t = (ushort_t*)p;    p += (size_t)4096 * 1024 * 2;
    ushort_t* w2t = (ushort_t*)p;    p += (size_t)4096 * 1024 * 2;
    float* cosv = (float*)p;         p += (size_t)TLEN * 32 * 4;
    float* sinv = (float*)p;         p += (size_t)TLEN * 32 * 4;
    float* bias_qkv = (float*)p;     p += 3072 * 4;
    ushort_t* n1 = (ushort_t*)p;     p += (size_t)MROWS * DIMD * 2;
    ushort_t* qkv = (ushort_t*)p;    p += (size_t)MROWS * 3072 * 2;
    ushort_t* Qb = (ushort_t*)p;     p += (size_t)MROWS * DIMD * 2;
    ushort_t* Kb = (ushort_t*)p;     p += (size_t)MROWS * DIMD * 2;
    ushort_t* VtG = (ushort_t*)p;    p += (size_t)MROWS * DIMD * 2;
    ushort_t* attn = (ushort_t*)p;   p += (size_t)MROWS * DIMD * 2;
    float* x1 = (float*)p;           p += (size_t)MROWS * DIMD * 4;
    ushort_t* n2 = (ushort_t*)p;     p += (size_t)MROWS * DIMD * 2;
    ushort_t* ff1 = (ushort_t*)p;    p += (size_t)MROWS * FFD * 2;

    dim3 tb(32, 8);
    transpose_cvt_kernel<<<dim3(32, 32), tb, 0, stream>>>(Wq, wt_qkv, 1024, 1024);
    transpose_cvt_kernel<<<dim3(32, 32), tb, 0, stream>>>(Wk, wt_qkv + (size_t)1024 * 1024, 1024, 1024);
    transpose_cvt_kernel<<<dim3(32, 32), tb, 0, stream>>>(Wv, wt_qkv + (size_t)2048 * 1024, 1024, 1024);
    transpose_cvt_kernel<<<dim3(32, 32), tb, 0, stream>>>(Wo, wot, 1024, 1024);
    transpose_cvt_kernel<<<dim3(128, 32), tb, 0, stream>>>(W1, w1t, 1024, 4096);
    transpose_cvt_kernel<<<dim3(32, 128), tb, 0, stream>>>(W2, w2t, 4096, 1024);
    rope_tables_kernel<<<TLEN * 32 / 256, 256, 0, stream>>>(cosv, sinv);
    pack_bias_kernel<<<12, 256, 0, stream>>>(bq, bk, bv, bias_qkv);
    ln_kernel<<<MROWS, 256, 0, stream>>>(x, ln1_g, ln1_b, n1);
    gemm_kernel<false, false, true><<<dim3(3072 / 128, MROWS / 128), 256, 0, stream>>>(
        n1, wt_qkv, bias_qkv, nullptr, nullptr, qkv, MROWS, 3072, 1024);
    rope_apply_kernel<<<BATCH * NHEAD * TLEN * 32 / 256, 256, 0, stream>>>(qkv, cosv, sinv, Qb, Kb);
    transpose_v_kernel<<<dim3(TLEN / 64, BATCH * NHEAD), 256, 0, stream>>>(qkv, VtG);
    flash_kernel<<<dim3(TLEN / 64, BATCH * NHEAD), 256, 0, stream>>>(Qb, Kb, VtG, attn);
    gemm_kernel<false, true, false><<<dim3(1024 / 128, MROWS / 128), 256, 0, stream>>>(
        attn, wot, bo, x, x1, nullptr, MROWS, 1024, 1024);
    ln_kernel<<<MROWS, 256, 0, stream>>>(x1, ln2_g, ln2_b, n2);
    gemm_kernel<true, false, true><<<dim3(4096 / 128, MROWS / 128), 256, 0, stream>>>(
        n2, w1t, b1, nullptr, nullptr, ff1, MROWS, 4096, 1024);
    gemm_kernel<false, true, false><<<dim3(1024 / 128, MROWS / 128), 256, 0, stream>>>(
        ff1, w2t, b2, x1, out, nullptr, MROWS, 1024, 4096);
}

// Round 4
// 345.807 us; speedup vs baseline: 1.4679x; 1.0206x over previous
//
#include <hip/hip_runtime.h>

typedef unsigned short ushort_t;
typedef unsigned int uint_t;
typedef __bf16 bf16x8 __attribute__((ext_vector_type(8)));
typedef float f32x4 __attribute__((ext_vector_type(4)));

#define DIMD 1024
#define FFD 4096
#define NHEAD 16
#define HDIM 64
#define TLEN 2048
#define BATCH 2
#define MROWS (BATCH * TLEN)  // 4096
// 0.125 * log2(e): folds the 1/sqrt(64) scale and exp->exp2 conversion into Q
#define QSCALE 0.18033688011112042f

__device__ __forceinline__ ushort_t f2b(float f) {
    uint_t u = __builtin_bit_cast(uint_t, f);
    u = u + 0x7fffu + ((u >> 16) & 1u);
    return (ushort_t)(u >> 16);
}
__device__ __forceinline__ float b2f(ushort_t b) {
    uint_t u = ((uint_t)b) << 16;
    return __builtin_bit_cast(float, u);
}
__device__ __forceinline__ bf16x8 ld8(const ushort_t* p) {
    uint4 v = *(const uint4*)(p);
    return __builtin_bit_cast(bf16x8, v);
}
__device__ __forceinline__ bf16x8 ld8b(const char* p) {
    uint4 v = *(const uint4*)(p);
    return __builtin_bit_cast(bf16x8, v);
}
__device__ __forceinline__ f32x4 mfma16(bf16x8 a, bf16x8 b, f32x4 c) {
    return __builtin_amdgcn_mfma_f32_16x16x32_bf16(a, b, c, 0, 0, 0);
}
__device__ __forceinline__ uint_t cvtpk(float lo, float hi) {
    uint_t r;
    asm("v_cvt_pk_bf16_f32 %0, %1, %2" : "=v"(r) : "v"(lo), "v"(hi));
    return r;
}
__device__ __forceinline__ void gload16(const void* g, void* l) {
    __builtin_amdgcn_global_load_lds(
        (const __attribute__((address_space(1))) void*)g,
        (__attribute__((address_space(3))) void*)l, 16, 0, 0);
}

// ---------------- transpose + fp32->bf16 convert: out[C][R] = in[R][C] ----------------
__global__ __launch_bounds__(256) void transpose_cvt_kernel(
    const float* __restrict__ in, ushort_t* __restrict__ out, int R, int C) {
    __shared__ float tile[32][33];
    const int c0 = blockIdx.x * 32, r0 = blockIdx.y * 32;
    const int tx = threadIdx.x, ty = threadIdx.y;  // 32 x 8
#pragma unroll
    for (int i = 0; i < 4; ++i)
        tile[ty + i * 8][tx] = in[(size_t)(r0 + ty + i * 8) * C + c0 + tx];
    __syncthreads();
#pragma unroll
    for (int i = 0; i < 4; ++i)
        out[(size_t)(c0 + ty + i * 8) * R + r0 + tx] = f2b(tile[tx][ty + i * 8]);
}

// ---------------- rope tables: cos/sin [T][32] ----------------
__global__ __launch_bounds__(256) void rope_tables_kernel(float* __restrict__ cosv,
                                                          float* __restrict__ sinv) {
    int idx = blockIdx.x * 256 + threadIdx.x;  // T*32
    int i = idx & 31;
    int t = idx >> 5;
    float invf = powf(10000.0f, -(float)i / 32.0f);
    float a = (float)t * invf;
    cosv[idx] = cosf(a);
    sinv[idx] = sinf(a);
}

// ---------------- pack qkv bias ----------------
__global__ __launch_bounds__(256) void pack_bias_kernel(const float* __restrict__ bq,
                                                        const float* __restrict__ bk,
                                                        const float* __restrict__ bv,
                                                        float* __restrict__ out) {
    int i = blockIdx.x * 256 + threadIdx.x;
    if (i < 3072) {
        float v = (i < 1024) ? bq[i] : (i < 2048) ? bk[i - 1024] : bv[i - 2048];
        out[i] = v;
    }
}

// ---------------- layernorm fp32 -> bf16, one row (1024) per block ----------------
__global__ __launch_bounds__(256) void ln_kernel(const float* __restrict__ x,
                                                 const float* __restrict__ g,
                                                 const float* __restrict__ bta,
                                                 ushort_t* __restrict__ out) {
    const int row = blockIdx.x;
    const int tid = threadIdx.x;
    const float4 v = *(const float4*)(x + (size_t)row * DIMD + tid * 4);
    float s = v.x + v.y + v.z + v.w;
    float sq = v.x * v.x + v.y * v.y + v.z * v.z + v.w * v.w;
#pragma unroll
    for (int off = 1; off < 64; off <<= 1) {
        s += __shfl_xor(s, off);
        sq += __shfl_xor(sq, off);
    }
    __shared__ float rs[4], rq[4];
    const int wave = tid >> 6;
    if ((tid & 63) == 0) { rs[wave] = s; rq[wave] = sq; }
    __syncthreads();
    s = rs[0] + rs[1] + rs[2] + rs[3];
    sq = rq[0] + rq[1] + rq[2] + rq[3];
    const float mean = s * (1.0f / DIMD);
    const float var = sq * (1.0f / DIMD) - mean * mean;
    const float rstd = rsqrtf(var + 1e-5f);
    const float4 gv = *(const float4*)(g + tid * 4);
    const float4 bv = *(const float4*)(bta + tid * 4);
    ushort_t o[4];
    o[0] = f2b((v.x - mean) * rstd * gv.x + bv.x);
    o[1] = f2b((v.y - mean) * rstd * gv.y + bv.y);
    o[2] = f2b((v.z - mean) * rstd * gv.z + bv.z);
    o[3] = f2b((v.w - mean) * rstd * gv.w + bv.w);
    *(uint2*)(out + (size_t)row * DIMD + tid * 4) = *(uint2*)&o[0];
}

// ================= GEMM 256x256 8-phase (m201 template, plain HIP) =================
// C[M][N] = A[M][K](bf16) * Bt[N][K]^T + bias.  512 thr = 8 waves (2M x 4N),
// BK=64, LDS 128KB: [2 buf][2 half][128 rows][64 k] per operand, XOR-swizzled.
// Per K-tile-pair iteration: 8 phases, counted vmcnt(4) at ph3/ph7 only.
template <bool GELU, bool OUTBF16>
__global__ __launch_bounds__(512, 2) void gemm8_kernel(
    const ushort_t* __restrict__ A, const ushort_t* __restrict__ Bt,
    const float* __restrict__ bias,
    float* __restrict__ outf, ushort_t* __restrict__ outb,
    int M, int N, int K) {
    __shared__ __align__(16) ushort_t Abuf[2][2][128 * 64];
    __shared__ __align__(16) ushort_t Bbuf[2][2][128 * 64];
    const int tid = threadIdx.x;
    const int lane = tid & 63;
    const int wave = tid >> 6;
    const int wm = wave >> 2;  // 0..1
    const int wn = wave & 3;   // 0..3
    const int bm = blockIdx.y * 256;
    const int bn = blockIdx.x * 256;
    const int lrow = lane & 15;
    const int lk16 = (lane >> 4) << 4;  // byte offset of k-group
    const int swz = (lrow & 7) << 4;

    // staging: wave covers LDS bytes [wave*2048, +2048) of a 16KB half (2 slots)
    // dest byte o = wave*2048 + slot*1024 + lane*16 -> row = o>>7, col=(o&127)
    // pre-swizzled global source col (involution with read-side swizzle)
    const int srow = (wave << 4) + (lane >> 3);
    const int scol = ((lane & 7) ^ (lane >> 3)) << 4;  // bytes
    const ushort_t* aLane = A + (size_t)(bm + srow) * K + (scol >> 1);
    const ushort_t* bLane = Bt + (size_t)(bn + srow) * K + (scol >> 1);
    const size_t h1 = (size_t)128 * K;  // half-1 offset (elements)

    char* const stA00 = (char*)&Abuf[0][0][0];
    char* const stA01 = (char*)&Abuf[0][1][0];
    char* const stA10 = (char*)&Abuf[1][0][0];
    char* const stA11 = (char*)&Abuf[1][1][0];
    char* const stB00 = (char*)&Bbuf[0][0][0];
    char* const stB01 = (char*)&Bbuf[0][1][0];
    char* const stB10 = (char*)&Bbuf[1][0][0];
    char* const stB11 = (char*)&Bbuf[1][1][0];
    const char* const ArdB[2] = {(const char*)&Abuf[0][wm][0],
                                 (const char*)&Abuf[1][wm][0]};
    const char* const BrdB[2] = {(const char*)&Bbuf[0][wn >> 1][0],
                                 (const char*)&Bbuf[1][wn >> 1][0]};
    const int brow0 = (wn & 1) * 64;

#define STG(gp, ldsp)                                                \
    do {                                                             \
        gload16((gp), (ldsp) + (wave << 11));                        \
        gload16((gp) + 8 * (size_t)K, (ldsp) + (wave << 11) + 1024); \
    } while (0)

#define RD_A(buf, MH)                                                          \
    _Pragma("unroll") for (int ii = 0; ii < 4; ++ii)                           \
    _Pragma("unroll") for (int ss = 0; ss < 2; ++ss)                           \
        af[ii][ss] = ld8b(ArdB[buf] + ((((MH)*4 + ii) * 16 + lrow) << 7) +     \
                          (((ss * 64) + lk16) ^ swz));

#define RD_B(buf, NH, DST)                                                     \
    _Pragma("unroll") for (int jj = 0; jj < 2; ++jj)                           \
    _Pragma("unroll") for (int ss = 0; ss < 2; ++ss)                           \
        DST[jj][ss] =                                                          \
            ld8b(BrdB[buf] + ((brow0 + ((NH)*2 + jj) * 16 + lrow) << 7) +      \
                 (((ss * 64) + lk16) ^ swz));

#define MMA(MH, NH, BF)                                                        \
    __builtin_amdgcn_s_setprio(1);                                             \
    _Pragma("unroll") for (int ii = 0; ii < 4; ++ii)                           \
    _Pragma("unroll") for (int jj = 0; jj < 2; ++jj)                           \
    _Pragma("unroll") for (int ss = 0; ss < 2; ++ss)                           \
        acc[(MH)*4 + ii][(NH)*2 + jj] = mfma16(                                \
            af[ii][ss], BF[jj][ss], acc[(MH)*4 + ii][(NH)*2 + jj]);            \
    __builtin_amdgcn_s_setprio(0);

#define BAR() __builtin_amdgcn_s_barrier()

    // One K-tile-pair iteration: tiles t (buf0, ph0-3) and t+1 (buf1, ph4-7).
    // Stages: ph0/1: buf1.A (t+1); ph2/3: buf0.B (t+2); ph4/5: buf0.A (t+2);
    //         ph6/7: buf1.B (t+3).  vmcnt(4) at ph3 (buf1 ready), ph7 (buf0 ready).
#define GITER(t, LAST)                                                         \
    {                                                                          \
        RD_A(0, 0); RD_B(0, 0, bf0);                                           \
        STG(aLane + (size_t)((t) + 1) * 64, stA10);                            \
        BAR(); MMA(0, 0, bf0); BAR();                                          \
        RD_B(0, 1, bf1);                                                       \
        STG(aLane + h1 + (size_t)((t) + 1) * 64, stA11);                       \
        BAR(); MMA(0, 1, bf1); BAR();                                          \
        RD_A(0, 1);                                                            \
        if (!(LAST)) STG(bLane + (size_t)((t) + 2) * 64, stB00);               \
        BAR(); MMA(1, 1, bf1); BAR();                                          \
        if (!(LAST)) STG(bLane + h1 + (size_t)((t) + 2) * 64, stB01);          \
        BAR(); MMA(1, 0, bf0);                                                 \
        if (LAST) { asm volatile("s_waitcnt vmcnt(0)" ::: "memory"); }         \
        else      { asm volatile("s_waitcnt vmcnt(4)" ::: "memory"); }         \
        BAR();                                                                 \
        RD_A(1, 0); RD_B(1, 0, bf0);                                           \
        if (!(LAST)) STG(aLane + (size_t)((t) + 2) * 64, stA00);               \
        BAR(); MMA(0, 0, bf0); BAR();                                          \
        RD_B(1, 1, bf1);                                                       \
        if (!(LAST)) STG(aLane + h1 + (size_t)((t) + 2) * 64, stA01);          \
        BAR(); MMA(0, 1, bf1); BAR();                                          \
        RD_A(1, 1);                                                            \
        if (!(LAST)) STG(bLane + (size_t)((t) + 3) * 64, stB10);               \
        BAR(); MMA(1, 1, bf1); BAR();                                          \
        if (!(LAST)) STG(bLane + h1 + (size_t)((t) + 3) * 64, stB11);          \
        BAR(); MMA(1, 0, bf0);                                                 \
        if (!(LAST)) { asm volatile("s_waitcnt vmcnt(4)" ::: "memory"); }      \
        BAR();                                                                 \
    }

    f32x4 acc[8][4] = {};
    bf16x8 af[4][2], bf0[2][2], bf1[2][2];

    // prologue: tile0 (all 4 halves) -> buf0; tile1 B halves -> buf1
    STG(aLane, stA00);
    STG(aLane + h1, stA01);
    STG(bLane, stB00);
    STG(bLane + h1, stB01);
    STG(bLane + 64, stB10);
    STG(bLane + h1 + 64, stB11);
    asm volatile("s_waitcnt vmcnt(4)" ::: "memory");
    BAR();

    const int niter = K >> 7;  // K/128, even #tiles guaranteed
    for (int i = 0; i < niter - 1; ++i) GITER(2 * i, false);
    GITER(2 * (niter - 1), true);

#undef GITER
#undef BAR
#undef MMA
#undef RD_B
#undef RD_A
#undef STG

    const int erow = (lane >> 4) << 2;
#pragma unroll
    for (int i = 0; i < 8; ++i) {
#pragma unroll
        for (int j = 0; j < 4; ++j) {
            const int row = bm + wm * 128 + i * 16 + erow;
            const int col = bn + wn * 64 + j * 16 + lrow;
            const float bz = bias[col];
#pragma unroll
            for (int q = 0; q < 4; ++q) {
                float v = acc[i][j][q] + bz;
                if (GELU) v = 0.5f * v * (1.0f + erff(v * 0.70710678118f));
                if (OUTBF16)
                    outb[(size_t)(row + q) * N + col] = f2b(v);
                else
                    outf[(size_t)(row + q) * N + col] = v;
            }
        }
    }
}

// ---------------- GEMM: 2-phase dbuf, BK=32, 128x128 (for N=1024 shapes) ----------------
template <bool GELU, bool RES, bool OUTBF16>
__global__ __launch_bounds__(256) void gemm_kernel(
    const ushort_t* __restrict__ A, const ushort_t* __restrict__ Bt,
    const float* __restrict__ bias, const float* __restrict__ res,
    float* __restrict__ outf, ushort_t* __restrict__ outb, int M, int N, int K) {
    __shared__ __align__(16) ushort_t Asm[2][128 * 32];
    __shared__ __align__(16) ushort_t Bsm[2][128 * 32];
    const int tid = threadIdx.x;
    const int lane = tid & 63;
    const int wave = tid >> 6;
    const int wr = (wave >> 1) * 64;
    const int wc = (wave & 1) * 64;
    const int bm = blockIdx.y * 128;
    const int bn = blockIdx.x * 128;
    const int lrow = lane & 15;
    const int lk = (lane >> 4) * 8;

    const int ch = wave * 2;
    const int o0 = (ch << 10) + lane * 16;
    const int o1 = ((ch + 1) << 10) + lane * 16;
    const int r0s = o0 >> 6, r1s = o1 >> 6;
    const ushort_t* Ag0 = A + (size_t)(bm + r0s) * K + ((o0 & 63) >> 1);
    const ushort_t* Ag1 = A + (size_t)(bm + r1s) * K + ((o1 & 63) >> 1);
    const ushort_t* Bg0 = Bt + (size_t)(bn + r0s) * K + ((o0 & 63) >> 1);
    const ushort_t* Bg1 = Bt + (size_t)(bn + r1s) * K + ((o1 & 63) >> 1);

#define GEMM_STAGE(buf, k0)                                      \
    {                                                            \
        gload16(Ag0 + (k0), (char*)Asm[buf] + (ch << 10));       \
        gload16(Ag1 + (k0), (char*)Asm[buf] + ((ch + 1) << 10)); \
        gload16(Bg0 + (k0), (char*)Bsm[buf] + (ch << 10));       \
        gload16(Bg1 + (k0), (char*)Bsm[buf] + ((ch + 1) << 10)); \
    }

    f32x4 acc[4][4] = {};
    const int nst = K >> 5;

    GEMM_STAGE(0, 0);
    __syncthreads();
    for (int t = 0; t < nst; ++t) {
        const int buf = t & 1;
        if (t + 1 < nst) GEMM_STAGE(buf ^ 1, (t + 1) << 5);
        bf16x8 af[4], bfr[4];
#pragma unroll
        for (int i = 0; i < 4; ++i)
            af[i] = ld8(Asm[buf] + (wr + i * 16 + lrow) * 32 + lk);
#pragma unroll
        for (int j = 0; j < 4; ++j)
            bfr[j] = ld8(Bsm[buf] + (wc + j * 16 + lrow) * 32 + lk);
        __builtin_amdgcn_s_setprio(1);
#pragma unroll
        for (int i = 0; i < 4; ++i)
#pragma unroll
            for (int j = 0; j < 4; ++j)
                acc[i][j] = mfma16(af[i], bfr[j], acc[i][j]);
        __builtin_amdgcn_s_setprio(0);
        __syncthreads();
    }
#undef GEMM_STAGE

    const int lr4 = (lane >> 4) * 4;
#pragma unroll
    for (int i = 0; i < 4; ++i) {
#pragma unroll
        for (int j = 0; j < 4; ++j) {
#pragma unroll
            for (int q = 0; q < 4; ++q) {
                const int row = bm + wr + i * 16 + lr4 + q;
                const int col = bn + wc + j * 16 + lrow;
                float v = acc[i][j][q] + bias[col];
                if (RES) v += res[(size_t)row * N + col];
                if (GELU) v = 0.5f * v * (1.0f + erff(v * 0.70710678118f));
                if (OUTBF16)
                    outb[(size_t)row * N + col] = f2b(v);
                else
                    outf[(size_t)row * N + col] = v;
            }
        }
    }
}

// ---------------- rope apply (Q scaled by QSCALE) -> Qb,Kb [bh][t][d] bf16 ----------------
__global__ __launch_bounds__(256) void rope_apply_kernel(
    const ushort_t* __restrict__ qkv, const float* __restrict__ cosv,
    const float* __restrict__ sinv, ushort_t* __restrict__ Qb,
    ushort_t* __restrict__ Kb) {
    const int idx = blockIdx.x * 256 + threadIdx.x;  // B*H*T*32
    const int i = idx & 31;
    const int t = (idx >> 5) & (TLEN - 1);
    const int bh = idx >> 16;
    const int b = bh >> 4, h = bh & 15;
    const size_t rowoff = ((size_t)(b * TLEN + t)) * 3072 + h * 64;
    const float q1 = b2f(qkv[rowoff + i]);
    const float q2 = b2f(qkv[rowoff + 32 + i]);
    const float k1 = b2f(qkv[rowoff + 1024 + i]);
    const float k2 = b2f(qkv[rowoff + 1024 + 32 + i]);
    const float c = cosv[t * 32 + i];
    const float s = sinv[t * 32 + i];
    const size_t ooff = ((size_t)bh * TLEN + t) * 64;
    Qb[ooff + i] = f2b((q1 * c - q2 * s) * QSCALE);
    Qb[ooff + 32 + i] = f2b((q2 * c + q1 * s) * QSCALE);
    Kb[ooff + i] = f2b(k1 * c - k2 * s);
    Kb[ooff + 32 + i] = f2b(k2 * c + k1 * s);
}

// ---------------- V transpose: qkv V-section -> VtG[bh][d][t] bf16 ----------------
__global__ __launch_bounds__(256) void transpose_v_kernel(
    const ushort_t* __restrict__ qkv, ushort_t* __restrict__ VtG) {
    __shared__ ushort_t tile[64][72];
    const int bh = blockIdx.y;
    const int b = bh >> 4, h = bh & 15;
    const int t0 = blockIdx.x * 64;
    const int tid = threadIdx.x;
    const int r = tid >> 2;
    const int dp = (tid & 3) * 16;
    const ushort_t* src = qkv + (size_t)(b * TLEN + t0 + r) * 3072 + 2048 + h * 64 + dp;
    *(uint4*)&tile[r][dp] = *(const uint4*)src;
    *(uint4*)&tile[r][dp + 8] = *(const uint4*)(src + 8);
    __syncthreads();
    const int d = tid >> 2;
    const int tp = (tid & 3) * 16;
    ushort_t* dst = VtG + (size_t)bh * HDIM * TLEN + (size_t)d * TLEN + t0 + tp;
    ushort_t tmp[16];
#pragma unroll
    for (int j = 0; j < 16; ++j) tmp[j] = tile[tp + j][d];
    *(uint4*)dst = *(uint4*)&tmp[0];
    *(uint4*)(dst + 8) = *(uint4*)&tmp[8];
}

// ---------------- flash attention v3.1: LDS-staged K/V^T, 2-phase dbuf, defer-max ----------------
__global__ __launch_bounds__(256) void flash_kernel(const ushort_t* __restrict__ Qb,
                                                    const ushort_t* __restrict__ Kb,
                                                    const ushort_t* __restrict__ VtG,
                                                    ushort_t* __restrict__ attn) {
    __shared__ __align__(16) ushort_t Ksm[2][64 * 64];
    __shared__ __align__(16) ushort_t Vsm[2][64 * 64];
    const int bh = blockIdx.y;
    const int b = bh >> 4, h = bh & 15;
    const int lane = threadIdx.x & 63;
    const int wave = threadIdx.x >> 6;
    const int q0 = blockIdx.x * 64 + wave * 16;
    const int lrow = lane & 15;
    const int g = lane >> 4;
    const int lk = g * 8;

    const ushort_t* Qp = Qb + ((size_t)bh * TLEN + q0) * HDIM;
    const ushort_t* Kp = Kb + (size_t)bh * TLEN * HDIM;
    const ushort_t* Vt = VtG + (size_t)bh * HDIM * TLEN;

    const int ch0 = wave * 2, ch1 = wave * 2 + 1;
    const int so0 = (ch0 << 10) + lane * 16;
    const int so1 = (ch1 << 10) + lane * 16;
    const int sr0 = so0 >> 7, sr1 = so1 >> 7;
    const int cb0 = (so0 & 127) ^ ((sr0 & 7) << 4);
    const int cb1 = (so1 & 127) ^ ((sr1 & 7) << 4);
    const ushort_t* Kg0 = Kp + (size_t)sr0 * HDIM + (cb0 >> 1);
    const ushort_t* Kg1 = Kp + (size_t)sr1 * HDIM + (cb1 >> 1);
    const ushort_t* Vg0 = Vt + (size_t)sr0 * TLEN + (cb0 >> 1);
    const ushort_t* Vg1 = Vt + (size_t)sr1 * TLEN + (cb1 >> 1);

#define FLASH_STAGE(buf, kb)                                               \
    {                                                                      \
        gload16(Kg0 + (size_t)(kb) * HDIM, (char*)Ksm[buf] + (ch0 << 10)); \
        gload16(Kg1 + (size_t)(kb) * HDIM, (char*)Ksm[buf] + (ch1 << 10)); \
        gload16(Vg0 + (kb), (char*)Vsm[buf] + (ch0 << 10));                \
        gload16(Vg1 + (kb), (char*)Vsm[buf] + (ch1 << 10));                \
    }

    bf16x8 bq0 = ld8(Qp + lrow * 64 + lk);
    bf16x8 bq1 = ld8(Qp + lrow * 64 + 32 + lk);

    f32x4 o[4] = {};
    float m = -1e30f, l = 0.0f;

    const int srcA = lrow + ((g & 1) << 5);
    const int srcB = srcA + 16;
    const int csel = g >> 1;

    FLASH_STAGE(0, 0);
    __syncthreads();

    for (int it = 0; it < TLEN / 64; ++it) {
        const int buf = it & 1;
        if (it + 1 < TLEN / 64) FLASH_STAGE(buf ^ 1, (it + 1) * 64);

        f32x4 s[4];
        __builtin_amdgcn_s_setprio(1);
#pragma unroll
        for (int kt = 0; kt < 4; ++kt) {
            const int r = kt * 16 + lrow;
            const int sw = (r & 7) << 4;
            const char* krow = (const char*)(Ksm[buf] + r * 64);
            f32x4 a = {};
            a = mfma16(ld8((const ushort_t*)(krow + ((lk * 2) ^ sw))), bq0, a);
            a = mfma16(ld8((const ushort_t*)(krow + ((64 + lk * 2) ^ sw))), bq1, a);
            s[kt] = a;
        }
        __builtin_amdgcn_s_setprio(0);
        float pm = s[0][0];
#pragma unroll
        for (int kt = 0; kt < 4; ++kt)
#pragma unroll
            for (int r = 0; r < 4; ++r) pm = fmaxf(pm, s[kt][r]);
        pm = fmaxf(pm, __shfl_xor(pm, 16));
        pm = fmaxf(pm, __shfl_xor(pm, 32));
        // defer-max (T13): only rescale when some row's max grew by >8 (log2 units)
        if (!__all(pm - m <= 8.0f)) {
            const float mn = fmaxf(m, pm);
            const float alpha = exp2f(m - mn);
            m = mn;
            l *= alpha;
#pragma unroll
            for (int n = 0; n < 4; ++n)
#pragma unroll
                for (int r = 0; r < 4; ++r) o[n][r] *= alpha;
        }
        float rs = 0.0f;
        uint_t pk0[4], pk1[4];
#pragma unroll
        for (int kt = 0; kt < 4; ++kt) {
            const float p0 = exp2f(s[kt][0] - m);
            const float p1 = exp2f(s[kt][1] - m);
            const float p2 = exp2f(s[kt][2] - m);
            const float p3 = exp2f(s[kt][3] - m);
            rs += (p0 + p1) + (p2 + p3);
            pk0[kt] = cvtpk(p0, p1);
            pk1[kt] = cvtpk(p2, p3);
        }
        rs += __shfl_xor(rs, 16);
        rs += __shfl_xor(rs, 32);
        l += rs;
#pragma unroll
        for (int ks = 0; ks < 2; ++ks) {
            const int ktA = 2 * ks, ktB = 2 * ks + 1;
            const uint_t d0a = (uint_t)__shfl((int)pk0[ktA], srcA);
            const uint_t d0b = (uint_t)__shfl((int)pk0[ktB], srcA);
            const uint_t d1a = (uint_t)__shfl((int)pk1[ktA], srcA);
            const uint_t d1b = (uint_t)__shfl((int)pk1[ktB], srcA);
            const uint_t d2a = (uint_t)__shfl((int)pk0[ktA], srcB);
            const uint_t d2b = (uint_t)__shfl((int)pk0[ktB], srcB);
            const uint_t d3a = (uint_t)__shfl((int)pk1[ktA], srcB);
            const uint_t d3b = (uint_t)__shfl((int)pk1[ktB], srcB);
            uint4 bp;
            bp.x = csel ? d0b : d0a;
            bp.y = csel ? d1b : d1a;
            bp.z = csel ? d2b : d2a;
            bp.w = csel ? d3b : d3a;
            const bf16x8 bpf = __builtin_bit_cast(bf16x8, bp);
            __builtin_amdgcn_s_setprio(1);
#pragma unroll
            for (int n = 0; n < 4; ++n) {
                const int r = n * 16 + lrow;
                const int sw = (r & 7) << 4;
                const char* vrow = (const char*)(Vsm[buf] + r * 64);
                const bf16x8 av =
                    ld8((const ushort_t*)(vrow + ((ks * 64 + lk * 2) ^ sw)));
                o[n] = mfma16(av, bpf, o[n]);
            }
            __builtin_amdgcn_s_setprio(0);
        }
        __syncthreads();
    }
#undef FLASH_STAGE

    const float inv_l = 1.0f / l;
    const int qrow = b * TLEN + q0 + lrow;
#pragma unroll
    for (int n = 0; n < 4; ++n) {
        ushort_t o4[4];
#pragma unroll
        for (int r = 0; r < 4; ++r) o4[r] = f2b(o[n][r] * inv_l);
        *(uint2*)(attn + (size_t)qrow * DIMD + h * HDIM + n * 16 + g * 4) = *(uint2*)&o4[0];
    }
}

extern "C" void kernel_launch(void* const* d_in, const int* in_sizes, int n_in,
                              void* d_out, int out_size, void* d_ws, size_t ws_size,
                              hipStream_t stream) {
    const float* x = (const float*)d_in[0];
    const float* ln1_g = (const float*)d_in[2];
    const float* ln1_b = (const float*)d_in[3];
    const float* Wq = (const float*)d_in[4];
    const float* bq = (const float*)d_in[5];
    const float* Wk = (const float*)d_in[6];
    const float* bk = (const float*)d_in[7];
    const float* Wv = (const float*)d_in[8];
    const float* bv = (const float*)d_in[9];
    const float* Wo = (const float*)d_in[10];
    const float* bo = (const float*)d_in[11];
    const float* ln2_g = (const float*)d_in[12];
    const float* ln2_b = (const float*)d_in[13];
    const float* W1 = (const float*)d_in[14];
    const float* b1 = (const float*)d_in[15];
    const float* W2 = (const float*)d_in[16];
    const float* b2 = (const float*)d_in[17];
    float* out = (float*)d_out;

    char* p = (char*)d_ws;
    ushort_t* wt_qkv = (ushort_t*)p; p += (size_t)3072 * 1024 * 2;
    ushort_t* wot = (ushort_t*)p;    p += (size_t)1024 * 1024 * 2;
    ushort_t* w1t = (ushort_t*)p;    p += (size_t)4096 * 1024 * 2;
    ushort_t* w2t = (ushort_t*)p;    p += (size_t)4096 * 1024 * 2;
    float* cosv = (float*)p;         p += (size_t)TLEN * 32 * 4;
    float* sinv = (float*)p;         p += (size_t)TLEN * 32 * 4;
    float* bias_qkv = (float*)p;     p += 3072 * 4;
    ushort_t* n1 = (ushort_t*)p;     p += (size_t)MROWS * DIMD * 2;
    ushort_t* qkv = (ushort_t*)p;    p += (size_t)MROWS * 3072 * 2;
    ushort_t* Qb = (ushort_t*)p;     p += (size_t)MROWS * DIMD * 2;
    ushort_t* Kb = (ushort_t*)p;     p += (size_t)MROWS * DIMD * 2;
    ushort_t* VtG = (ushort_t*)p;    p += (size_t)MROWS * DIMD * 2;
    ushort_t* attn = (ushort_t*)p;   p += (size_t)MROWS * DIMD * 2;
    float* x1 = (float*)p;           p += (size_t)MROWS * DIMD * 4;
    ushort_t* n2 = (ushort_t*)p;     p += (size_t)MROWS * DIMD * 2;
    ushort_t* ff1 = (ushort_t*)p;    p += (size_t)MROWS * FFD * 2;

    dim3 tb(32, 8);
    transpose_cvt_kernel<<<dim3(32, 32), tb, 0, stream>>>(Wq, wt_qkv, 1024, 1024);
    transpose_cvt_kernel<<<dim3(32, 32), tb, 0, stream>>>(Wk, wt_qkv + (size_t)1024 * 1024, 1024, 1024);
    transpose_cvt_kernel<<<dim3(32, 32), tb, 0, stream>>>(Wv, wt_qkv + (size_t)2048 * 1024, 1024, 1024);
    transpose_cvt_kernel<<<dim3(32, 32), tb, 0, stream>>>(Wo, wot, 1024, 1024);
    transpose_cvt_kernel<<<dim3(128, 32), tb, 0, stream>>>(W1, w1t, 1024, 4096);
    transpose_cvt_kernel<<<dim3(32, 128), tb, 0, stream>>>(W2, w2t, 4096, 1024);
    rope_tables_kernel<<<TLEN * 32 / 256, 256, 0, stream>>>(cosv, sinv);
    pack_bias_kernel<<<12, 256, 0, stream>>>(bq, bk, bv, bias_qkv);
    ln_kernel<<<MROWS, 256, 0, stream>>>(x, ln1_g, ln1_b, n1);
    gemm8_kernel<false, true><<<dim3(3072 / 256, MROWS / 256), 512, 0, stream>>>(
        n1, wt_qkv, bias_qkv, nullptr, qkv, MROWS, 3072, 1024);
    rope_apply_kernel<<<BATCH * NHEAD * TLEN * 32 / 256, 256, 0, stream>>>(qkv, cosv, sinv, Qb, Kb);
    transpose_v_kernel<<<dim3(TLEN / 64, BATCH * NHEAD), 256, 0, stream>>>(qkv, VtG);
    flash_kernel<<<dim3(TLEN / 64, BATCH * NHEAD), 256, 0, stream>>>(Qb, Kb, VtG, attn);
    gemm_kernel<false, true, false><<<dim3(1024 / 128, MROWS / 128), 256, 0, stream>>>(
        attn, wot, bo, x, x1, nullptr, MROWS, 1024, 1024);
    ln_kernel<<<MROWS, 256, 0, stream>>>(x1, ln2_g, ln2_b, n2);
    gemm8_kernel<true, true><<<dim3(4096 / 256, MROWS / 256), 512, 0, stream>>>(
        n2, w1t, b1, nullptr, ff1, MROWS, 4096, 1024);
    gemm_kernel<false, true, false><<<dim3(1024 / 128, MROWS / 128), 256, 0, stream>>>(
        ff1, w2t, b2, x1, out, nullptr, MROWS, 1024, 4096);
}

// Round 5
// 312.204 us; speedup vs baseline: 1.6259x; 1.1076x over previous
//
#include <hip/hip_runtime.h>

typedef unsigned short ushort_t;
typedef unsigned int uint_t;
typedef __bf16 bf16x8 __attribute__((ext_vector_type(8)));
typedef float f32x4 __attribute__((ext_vector_type(4)));

#define DIMD 1024
#define FFD 4096
#define NHEAD 16
#define HDIM 64
#define TLEN 2048
#define BATCH 2
#define MROWS (BATCH * TLEN)  // 4096
// 0.125 * log2(e): folds the 1/sqrt(64) scale and exp->exp2 conversion into Q
#define QSCALE 0.18033688011112042f
// static softmax shift (log2 units): |s| bound ~12, shift is a pure FP rescale
#define SMAX 20.0f

__device__ __forceinline__ ushort_t f2b(float f) {
    uint_t u = __builtin_bit_cast(uint_t, f);
    u = u + 0x7fffu + ((u >> 16) & 1u);
    return (ushort_t)(u >> 16);
}
__device__ __forceinline__ float b2f(ushort_t b) {
    uint_t u = ((uint_t)b) << 16;
    return __builtin_bit_cast(float, u);
}
__device__ __forceinline__ bf16x8 ld8(const ushort_t* p) {
    uint4 v = *(const uint4*)(p);
    return __builtin_bit_cast(bf16x8, v);
}
__device__ __forceinline__ bf16x8 ld8b(const char* p) {
    uint4 v = *(const uint4*)(p);
    return __builtin_bit_cast(bf16x8, v);
}
__device__ __forceinline__ f32x4 mfma16(bf16x8 a, bf16x8 b, f32x4 c) {
    return __builtin_amdgcn_mfma_f32_16x16x32_bf16(a, b, c, 0, 0, 0);
}
__device__ __forceinline__ uint_t cvtpk(float lo, float hi) {
    uint_t r;
    asm("v_cvt_pk_bf16_f32 %0, %1, %2" : "=v"(r) : "v"(lo), "v"(hi));
    return r;
}
__device__ __forceinline__ float exp2a(float x) {
    float r;
    asm("v_exp_f32 %0, %1" : "=v"(r) : "v"(x));
    return r;
}
__device__ __forceinline__ void gload16(const void* g, void* l) {
    __builtin_amdgcn_global_load_lds(
        (const __attribute__((address_space(1))) void*)g,
        (__attribute__((address_space(3))) void*)l, 16, 0, 0);
}

// ================= prep: all weight transposes + rope tables + bias pack =================
// blocks [0,4096): Wq/Wk/Wv/Wo 32x32 tiles; [4096,8192): W1; [8192,12288): W2;
// [12288,12544): rope tables; [12544,12556): bias pack.
__global__ __launch_bounds__(256) void prep_kernel(
    const float* __restrict__ Wq, const float* __restrict__ Wk,
    const float* __restrict__ Wv, const float* __restrict__ Wo,
    const float* __restrict__ W1, const float* __restrict__ W2,
    const float* __restrict__ bq, const float* __restrict__ bk,
    const float* __restrict__ bv,
    ushort_t* __restrict__ wt_qkv, ushort_t* __restrict__ wot,
    ushort_t* __restrict__ w1t, ushort_t* __restrict__ w2t,
    float* __restrict__ cosv, float* __restrict__ sinv,
    float* __restrict__ bias_qkv) {
    __shared__ float tile[32][33];
    const int id = blockIdx.x;
    const int tid = threadIdx.x;
    if (id < 12288) {
        const float* in;
        ushort_t* out;
        int R, C, bx, by;
        if (id < 4096) {
            const int w = id >> 10, loc = id & 1023;
            in = (w == 0) ? Wq : (w == 1) ? Wk : (w == 2) ? Wv : Wo;
            out = (w == 3) ? wot : wt_qkv + (size_t)w * 1024 * 1024;
            R = 1024; C = 1024; bx = loc & 31; by = loc >> 5;
        } else if (id < 8192) {
            const int loc = id - 4096;
            in = W1; out = w1t; R = 1024; C = 4096;
            bx = loc & 127; by = loc >> 7;
        } else {
            const int loc = id - 8192;
            in = W2; out = w2t; R = 4096; C = 1024;
            bx = loc & 31; by = loc >> 5;
        }
        const int c0 = bx * 32, r0 = by * 32;
        const int tx = tid & 31, ty = tid >> 5;  // 32 x 8
#pragma unroll
        for (int i = 0; i < 4; ++i)
            tile[ty + i * 8][tx] = in[(size_t)(r0 + ty + i * 8) * C + c0 + tx];
        __syncthreads();
#pragma unroll
        for (int i = 0; i < 4; ++i)
            out[(size_t)(c0 + ty + i * 8) * R + r0 + tx] = f2b(tile[tx][ty + i * 8]);
    } else if (id < 12544) {
        const int idx = (id - 12288) * 256 + tid;  // T*32
        const int i = idx & 31;
        const int t = idx >> 5;
        const float invf = powf(10000.0f, -(float)i / 32.0f);
        const float a = (float)t * invf;
        cosv[idx] = cosf(a);
        sinv[idx] = sinf(a);
    } else {
        const int i = (id - 12544) * 256 + tid;
        if (i < 3072) {
            float v = (i < 1024) ? bq[i] : (i < 2048) ? bk[i - 1024] : bv[i - 2048];
            bias_qkv[i] = v;
        }
    }
}

// ---------------- layernorm fp32 -> bf16, one row (1024) per block ----------------
__global__ __launch_bounds__(256) void ln_kernel(const float* __restrict__ x,
                                                 const float* __restrict__ g,
                                                 const float* __restrict__ bta,
                                                 ushort_t* __restrict__ out) {
    const int row = blockIdx.x;
    const int tid = threadIdx.x;
    const float4 v = *(const float4*)(x + (size_t)row * DIMD + tid * 4);
    float s = v.x + v.y + v.z + v.w;
    float sq = v.x * v.x + v.y * v.y + v.z * v.z + v.w * v.w;
#pragma unroll
    for (int off = 1; off < 64; off <<= 1) {
        s += __shfl_xor(s, off);
        sq += __shfl_xor(sq, off);
    }
    __shared__ float rs[4], rq[4];
    const int wave = tid >> 6;
    if ((tid & 63) == 0) { rs[wave] = s; rq[wave] = sq; }
    __syncthreads();
    s = rs[0] + rs[1] + rs[2] + rs[3];
    sq = rq[0] + rq[1] + rq[2] + rq[3];
    const float mean = s * (1.0f / DIMD);
    const float var = sq * (1.0f / DIMD) - mean * mean;
    const float rstd = rsqrtf(var + 1e-5f);
    const float4 gv = *(const float4*)(g + tid * 4);
    const float4 bv = *(const float4*)(bta + tid * 4);
    ushort_t o[4];
    o[0] = f2b((v.x - mean) * rstd * gv.x + bv.x);
    o[1] = f2b((v.y - mean) * rstd * gv.y + bv.y);
    o[2] = f2b((v.z - mean) * rstd * gv.z + bv.z);
    o[3] = f2b((v.w - mean) * rstd * gv.w + bv.w);
    *(uint2*)(out + (size_t)row * DIMD + tid * 4) = *(uint2*)&o[0];
}

// ================= GEMM 256x256 8-phase (m201 template, plain HIP) =================
template <bool GELU, bool OUTBF16>
__global__ __launch_bounds__(512, 2) void gemm8_kernel(
    const ushort_t* __restrict__ A, const ushort_t* __restrict__ Bt,
    const float* __restrict__ bias,
    float* __restrict__ outf, ushort_t* __restrict__ outb,
    int M, int N, int K) {
    __shared__ __align__(16) ushort_t Abuf[2][2][128 * 64];
    __shared__ __align__(16) ushort_t Bbuf[2][2][128 * 64];
    const int tid = threadIdx.x;
    const int lane = tid & 63;
    const int wave = tid >> 6;
    const int wm = wave >> 2;
    const int wn = wave & 3;
    const int bm = blockIdx.y * 256;
    const int bn = blockIdx.x * 256;
    const int lrow = lane & 15;
    const int lk16 = (lane >> 4) << 4;
    const int swz = (lrow & 7) << 4;

    const int srow = (wave << 4) + (lane >> 3);
    const int scol = ((lane & 7) ^ (lane >> 3)) << 4;
    const ushort_t* aLane = A + (size_t)(bm + srow) * K + (scol >> 1);
    const ushort_t* bLane = Bt + (size_t)(bn + srow) * K + (scol >> 1);
    const size_t h1 = (size_t)128 * K;

    char* const stA00 = (char*)&Abuf[0][0][0];
    char* const stA01 = (char*)&Abuf[0][1][0];
    char* const stA10 = (char*)&Abuf[1][0][0];
    char* const stA11 = (char*)&Abuf[1][1][0];
    char* const stB00 = (char*)&Bbuf[0][0][0];
    char* const stB01 = (char*)&Bbuf[0][1][0];
    char* const stB10 = (char*)&Bbuf[1][0][0];
    char* const stB11 = (char*)&Bbuf[1][1][0];
    const char* const ArdB[2] = {(const char*)&Abuf[0][wm][0],
                                 (const char*)&Abuf[1][wm][0]};
    const char* const BrdB[2] = {(const char*)&Bbuf[0][wn >> 1][0],
                                 (const char*)&Bbuf[1][wn >> 1][0]};
    const int brow0 = (wn & 1) * 64;

#define STG(gp, ldsp)                                                \
    do {                                                             \
        gload16((gp), (ldsp) + (wave << 11));                        \
        gload16((gp) + 8 * (size_t)K, (ldsp) + (wave << 11) + 1024); \
    } while (0)

#define RD_A(buf, MH)                                                          \
    _Pragma("unroll") for (int ii = 0; ii < 4; ++ii)                           \
    _Pragma("unroll") for (int ss = 0; ss < 2; ++ss)                           \
        af[ii][ss] = ld8b(ArdB[buf] + ((((MH)*4 + ii) * 16 + lrow) << 7) +     \
                          (((ss * 64) + lk16) ^ swz));

#define RD_B(buf, NH, DST)                                                     \
    _Pragma("unroll") for (int jj = 0; jj < 2; ++jj)                           \
    _Pragma("unroll") for (int ss = 0; ss < 2; ++ss)                           \
        DST[jj][ss] =                                                          \
            ld8b(BrdB[buf] + ((brow0 + ((NH)*2 + jj) * 16 + lrow) << 7) +      \
                 (((ss * 64) + lk16) ^ swz));

#define MMA(MH, NH, BF)                                                        \
    __builtin_amdgcn_s_setprio(1);                                             \
    _Pragma("unroll") for (int ii = 0; ii < 4; ++ii)                           \
    _Pragma("unroll") for (int jj = 0; jj < 2; ++jj)                           \
    _Pragma("unroll") for (int ss = 0; ss < 2; ++ss)                           \
        acc[(MH)*4 + ii][(NH)*2 + jj] = mfma16(                                \
            af[ii][ss], BF[jj][ss], acc[(MH)*4 + ii][(NH)*2 + jj]);            \
    __builtin_amdgcn_s_setprio(0);

#define BAR() __builtin_amdgcn_s_barrier()

#define GITER(t, LAST)                                                         \
    {                                                                          \
        RD_A(0, 0); RD_B(0, 0, bf0);                                           \
        STG(aLane + (size_t)((t) + 1) * 64, stA10);                            \
        BAR(); MMA(0, 0, bf0); BAR();                                          \
        RD_B(0, 1, bf1);                                                       \
        STG(aLane + h1 + (size_t)((t) + 1) * 64, stA11);                       \
        BAR(); MMA(0, 1, bf1); BAR();                                          \
        RD_A(0, 1);                                                            \
        if (!(LAST)) STG(bLane + (size_t)((t) + 2) * 64, stB00);               \
        BAR(); MMA(1, 1, bf1); BAR();                                          \
        if (!(LAST)) STG(bLane + h1 + (size_t)((t) + 2) * 64, stB01);          \
        BAR(); MMA(1, 0, bf0);                                                 \
        if (LAST) { asm volatile("s_waitcnt vmcnt(0)" ::: "memory"); }         \
        else      { asm volatile("s_waitcnt vmcnt(4)" ::: "memory"); }         \
        BAR();                                                                 \
        RD_A(1, 0); RD_B(1, 0, bf0);                                           \
        if (!(LAST)) STG(aLane + (size_t)((t) + 2) * 64, stA00);               \
        BAR(); MMA(0, 0, bf0); BAR();                                          \
        RD_B(1, 1, bf1);                                                       \
        if (!(LAST)) STG(aLane + h1 + (size_t)((t) + 2) * 64, stA01);          \
        BAR(); MMA(0, 1, bf1); BAR();                                          \
        RD_A(1, 1);                                                            \
        if (!(LAST)) STG(bLane + (size_t)((t) + 3) * 64, stB10);               \
        BAR(); MMA(1, 1, bf1); BAR();                                          \
        if (!(LAST)) STG(bLane + h1 + (size_t)((t) + 3) * 64, stB11);          \
        BAR(); MMA(1, 0, bf0);                                                 \
        if (!(LAST)) { asm volatile("s_waitcnt vmcnt(4)" ::: "memory"); }      \
        BAR();                                                                 \
    }

    f32x4 acc[8][4] = {};
    bf16x8 af[4][2], bf0[2][2], bf1[2][2];

    STG(aLane, stA00);
    STG(aLane + h1, stA01);
    STG(bLane, stB00);
    STG(bLane + h1, stB01);
    STG(bLane + 64, stB10);
    STG(bLane + h1 + 64, stB11);
    asm volatile("s_waitcnt vmcnt(4)" ::: "memory");
    BAR();

    const int niter = K >> 7;
    for (int i = 0; i < niter - 1; ++i) GITER(2 * i, false);
    GITER(2 * (niter - 1), true);

#undef GITER
#undef BAR
#undef MMA
#undef RD_B
#undef RD_A
#undef STG

    const int erow = (lane >> 4) << 2;
#pragma unroll
    for (int i = 0; i < 8; ++i) {
#pragma unroll
        for (int j = 0; j < 4; ++j) {
            const int row = bm + wm * 128 + i * 16 + erow;
            const int col = bn + wn * 64 + j * 16 + lrow;
            const float bz = bias[col];
#pragma unroll
            for (int q = 0; q < 4; ++q) {
                float v = acc[i][j][q] + bz;
                if (GELU) v = 0.5f * v * (1.0f + erff(v * 0.70710678118f));
                if (OUTBF16)
                    outb[(size_t)(row + q) * N + col] = f2b(v);
                else
                    outf[(size_t)(row + q) * N + col] = v;
            }
        }
    }
}

// ---------------- GEMM: 2-phase dbuf, BK=32, 128x128 (for N=1024 shapes) ----------------
template <bool GELU, bool RES, bool OUTBF16>
__global__ __launch_bounds__(256) void gemm_kernel(
    const ushort_t* __restrict__ A, const ushort_t* __restrict__ Bt,
    const float* __restrict__ bias, const float* __restrict__ res,
    float* __restrict__ outf, ushort_t* __restrict__ outb, int M, int N, int K) {
    __shared__ __align__(16) ushort_t Asm[2][128 * 32];
    __shared__ __align__(16) ushort_t Bsm[2][128 * 32];
    const int tid = threadIdx.x;
    const int lane = tid & 63;
    const int wave = tid >> 6;
    const int wr = (wave >> 1) * 64;
    const int wc = (wave & 1) * 64;
    const int bm = blockIdx.y * 128;
    const int bn = blockIdx.x * 128;
    const int lrow = lane & 15;
    const int lk = (lane >> 4) * 8;

    const int ch = wave * 2;
    const int o0 = (ch << 10) + lane * 16;
    const int o1 = ((ch + 1) << 10) + lane * 16;
    const int r0s = o0 >> 6, r1s = o1 >> 6;
    const ushort_t* Ag0 = A + (size_t)(bm + r0s) * K + ((o0 & 63) >> 1);
    const ushort_t* Ag1 = A + (size_t)(bm + r1s) * K + ((o1 & 63) >> 1);
    const ushort_t* Bg0 = Bt + (size_t)(bn + r0s) * K + ((o0 & 63) >> 1);
    const ushort_t* Bg1 = Bt + (size_t)(bn + r1s) * K + ((o1 & 63) >> 1);

#define GEMM_STAGE(buf, k0)                                      \
    {                                                            \
        gload16(Ag0 + (k0), (char*)Asm[buf] + (ch << 10));       \
        gload16(Ag1 + (k0), (char*)Asm[buf] + ((ch + 1) << 10)); \
        gload16(Bg0 + (k0), (char*)Bsm[buf] + (ch << 10));       \
        gload16(Bg1 + (k0), (char*)Bsm[buf] + ((ch + 1) << 10)); \
    }

    f32x4 acc[4][4] = {};
    const int nst = K >> 5;

    GEMM_STAGE(0, 0);
    __syncthreads();
    for (int t = 0; t < nst; ++t) {
        const int buf = t & 1;
        if (t + 1 < nst) GEMM_STAGE(buf ^ 1, (t + 1) << 5);
        bf16x8 af[4], bfr[4];
#pragma unroll
        for (int i = 0; i < 4; ++i)
            af[i] = ld8(Asm[buf] + (wr + i * 16 + lrow) * 32 + lk);
#pragma unroll
        for (int j = 0; j < 4; ++j)
            bfr[j] = ld8(Bsm[buf] + (wc + j * 16 + lrow) * 32 + lk);
        __builtin_amdgcn_s_setprio(1);
#pragma unroll
        for (int i = 0; i < 4; ++i)
#pragma unroll
            for (int j = 0; j < 4; ++j)
                acc[i][j] = mfma16(af[i], bfr[j], acc[i][j]);
        __builtin_amdgcn_s_setprio(0);
        __syncthreads();
    }
#undef GEMM_STAGE

    const int lr4 = (lane >> 4) * 4;
#pragma unroll
    for (int i = 0; i < 4; ++i) {
#pragma unroll
        for (int j = 0; j < 4; ++j) {
#pragma unroll
            for (int q = 0; q < 4; ++q) {
                const int row = bm + wr + i * 16 + lr4 + q;
                const int col = bn + wc + j * 16 + lrow;
                float v = acc[i][j][q] + bias[col];
                if (RES) v += res[(size_t)row * N + col];
                if (GELU) v = 0.5f * v * (1.0f + erff(v * 0.70710678118f));
                if (OUTBF16)
                    outb[(size_t)row * N + col] = f2b(v);
                else
                    outf[(size_t)row * N + col] = v;
            }
        }
    }
}

// ================= fused rope-apply + V-transpose =================
// grid (T/64, B*H), 256 thr. Writes Qb,Kb [bh][t][d] and VtG [bh][d][t].
__global__ __launch_bounds__(256) void qkv_post_kernel(
    const ushort_t* __restrict__ qkv, const float* __restrict__ cosv,
    const float* __restrict__ sinv, ushort_t* __restrict__ Qb,
    ushort_t* __restrict__ Kb, ushort_t* __restrict__ VtG) {
    __shared__ ushort_t tile[64][72];
    const int bh = blockIdx.y;
    const int b = bh >> 4, h = bh & 15;
    const int t0 = blockIdx.x * 64;
    const int tid = threadIdx.x;
    // RoPE Q/K: 4 threads per row; thread handles i in [i0, i0+8)
    {
        const int r = tid >> 2;
        const int i0 = (tid & 3) * 8;
        const int t = t0 + r;
        const size_t rowoff = ((size_t)(b * TLEN + t)) * 3072 + h * 64;
        union { uint4 u; ushort_t s[8]; } q1v, q2v, k1v, k2v;
        q1v.u = *(const uint4*)(qkv + rowoff + i0);
        q2v.u = *(const uint4*)(qkv + rowoff + 32 + i0);
        k1v.u = *(const uint4*)(qkv + rowoff + 1024 + i0);
        k2v.u = *(const uint4*)(qkv + rowoff + 1024 + 32 + i0);
        const size_t ooff = ((size_t)bh * TLEN + t) * 64;
        ushort_t oq1[8], oq2[8], ok1[8], ok2[8];
#pragma unroll
        for (int j = 0; j < 8; ++j) {
            const float c = cosv[t * 32 + i0 + j];
            const float s = sinv[t * 32 + i0 + j];
            const float a1 = b2f(q1v.s[j]), a2 = b2f(q2v.s[j]);
            const float c1 = b2f(k1v.s[j]), c2 = b2f(k2v.s[j]);
            oq1[j] = f2b((a1 * c - a2 * s) * QSCALE);
            oq2[j] = f2b((a2 * c + a1 * s) * QSCALE);
            ok1[j] = f2b(c1 * c - c2 * s);
            ok2[j] = f2b(c2 * c + c1 * s);
        }
        *(uint4*)(Qb + ooff + i0) = *(uint4*)oq1;
        *(uint4*)(Qb + ooff + 32 + i0) = *(uint4*)oq2;
        *(uint4*)(Kb + ooff + i0) = *(uint4*)ok1;
        *(uint4*)(Kb + ooff + 32 + i0) = *(uint4*)ok2;
    }
    // V transpose via LDS
    {
        const int r = tid >> 2;
        const int dp = (tid & 3) * 16;
        const ushort_t* src =
            qkv + (size_t)(b * TLEN + t0 + r) * 3072 + 2048 + h * 64 + dp;
        *(uint4*)&tile[r][dp] = *(const uint4*)src;
        *(uint4*)&tile[r][dp + 8] = *(const uint4*)(src + 8);
        __syncthreads();
        const int d = tid >> 2;
        const int tp = (tid & 3) * 16;
        ushort_t* dst = VtG + (size_t)bh * HDIM * TLEN + (size_t)d * TLEN + t0 + tp;
        ushort_t tmp[16];
#pragma unroll
        for (int j = 0; j < 16; ++j) tmp[j] = tile[tp + j][d];
        *(uint4*)dst = *(uint4*)&tmp[0];
        *(uint4*)(dst + 8) = *(uint4*)&tmp[8];
    }
}

// ---------------- flash attention v4: static-max softmax, deferred l-reduce ----------------
// 1D grid 1024 (XCD-chunked swizzle), 256 threads; wave owns 16 q rows.
__global__ __launch_bounds__(256) void flash_kernel(const ushort_t* __restrict__ Qb,
                                                    const ushort_t* __restrict__ Kb,
                                                    const ushort_t* __restrict__ VtG,
                                                    ushort_t* __restrict__ attn) {
    __shared__ __align__(16) ushort_t Ksm[2][64 * 64];
    __shared__ __align__(16) ushort_t Vsm[2][64 * 64];
    // XCD-chunked: XCD k handles 4 consecutive bh (K/V working set 2MB < 4MB L2)
    const int wg = (blockIdx.x & 7) * 128 + (blockIdx.x >> 3);
    const int bh = wg >> 5;
    const int qblk = wg & 31;
    const int b = bh >> 4, h = bh & 15;
    const int lane = threadIdx.x & 63;
    const int wave = threadIdx.x >> 6;
    const int q0 = qblk * 64 + wave * 16;
    const int lrow = lane & 15;
    const int g = lane >> 4;
    const int lk = g * 8;

    const ushort_t* Qp = Qb + ((size_t)bh * TLEN + q0) * HDIM;
    const ushort_t* Kp = Kb + (size_t)bh * TLEN * HDIM;
    const ushort_t* Vt = VtG + (size_t)bh * HDIM * TLEN;

    const int ch0 = wave * 2, ch1 = wave * 2 + 1;
    const int so0 = (ch0 << 10) + lane * 16;
    const int so1 = (ch1 << 10) + lane * 16;
    const int sr0 = so0 >> 7, sr1 = so1 >> 7;
    const int cb0 = (so0 & 127) ^ ((sr0 & 7) << 4);
    const int cb1 = (so1 & 127) ^ ((sr1 & 7) << 4);
    const ushort_t* Kg0 = Kp + (size_t)sr0 * HDIM + (cb0 >> 1);
    const ushort_t* Kg1 = Kp + (size_t)sr1 * HDIM + (cb1 >> 1);
    const ushort_t* Vg0 = Vt + (size_t)sr0 * TLEN + (cb0 >> 1);
    const ushort_t* Vg1 = Vt + (size_t)sr1 * TLEN + (cb1 >> 1);

#define FLASH_STAGE(buf, kb)                                               \
    {                                                                      \
        gload16(Kg0 + (size_t)(kb) * HDIM, (char*)Ksm[buf] + (ch0 << 10)); \
        gload16(Kg1 + (size_t)(kb) * HDIM, (char*)Ksm[buf] + (ch1 << 10)); \
        gload16(Vg0 + (kb), (char*)Vsm[buf] + (ch0 << 10));                \
        gload16(Vg1 + (kb), (char*)Vsm[buf] + (ch1 << 10));                \
    }

    bf16x8 bq0 = ld8(Qp + lrow * 64 + lk);
    bf16x8 bq1 = ld8(Qp + lrow * 64 + 32 + lk);

    f32x4 o[4] = {};
    float ls0 = 0.0f, ls1 = 0.0f;

    const int srcA = lrow + ((g & 1) << 5);
    const int srcB = srcA + 16;
    const int csel = g >> 1;

    FLASH_STAGE(0, 0);
    __syncthreads();

    for (int it = 0; it < TLEN / 64; ++it) {
        const int buf = it & 1;
        if (it + 1 < TLEN / 64) FLASH_STAGE(buf ^ 1, (it + 1) * 64);

        f32x4 s[4];
        __builtin_amdgcn_s_setprio(1);
#pragma unroll
        for (int kt = 0; kt < 4; ++kt) {
            const int r = kt * 16 + lrow;
            const int sw = (r & 7) << 4;
            const char* krow = (const char*)(Ksm[buf] + r * 64);
            f32x4 a = {-SMAX, -SMAX, -SMAX, -SMAX};  // fold -max into QK C-init
            a = mfma16(ld8((const ushort_t*)(krow + ((lk * 2) ^ sw))), bq0, a);
            a = mfma16(ld8((const ushort_t*)(krow + ((64 + lk * 2) ^ sw))), bq1, a);
            s[kt] = a;
        }
        __builtin_amdgcn_s_setprio(0);
        uint_t pk0[4], pk1[4];
#pragma unroll
        for (int kt = 0; kt < 4; ++kt) {
            const float p0 = exp2a(s[kt][0]);
            const float p1 = exp2a(s[kt][1]);
            const float p2 = exp2a(s[kt][2]);
            const float p3 = exp2a(s[kt][3]);
            ls0 += p0 + p1;
            ls1 += p2 + p3;
            pk0[kt] = cvtpk(p0, p1);
            pk1[kt] = cvtpk(p2, p3);
        }
#pragma unroll
        for (int ks = 0; ks < 2; ++ks) {
            const int ktA = 2 * ks, ktB = 2 * ks + 1;
            const uint_t d0a = (uint_t)__shfl((int)pk0[ktA], srcA);
            const uint_t d0b = (uint_t)__shfl((int)pk0[ktB], srcA);
            const uint_t d1a = (uint_t)__shfl((int)pk1[ktA], srcA);
            const uint_t d1b = (uint_t)__shfl((int)pk1[ktB], srcA);
            const uint_t d2a = (uint_t)__shfl((int)pk0[ktA], srcB);
            const uint_t d2b = (uint_t)__shfl((int)pk0[ktB], srcB);
            const uint_t d3a = (uint_t)__shfl((int)pk1[ktA], srcB);
            const uint_t d3b = (uint_t)__shfl((int)pk1[ktB], srcB);
            uint4 bp;
            bp.x = csel ? d0b : d0a;
            bp.y = csel ? d1b : d1a;
            bp.z = csel ? d2b : d2a;
            bp.w = csel ? d3b : d3a;
            const bf16x8 bpf = __builtin_bit_cast(bf16x8, bp);
            __builtin_amdgcn_s_setprio(1);
#pragma unroll
            for (int n = 0; n < 4; ++n) {
                const int r = n * 16 + lrow;
                const int sw = (r & 7) << 4;
                const char* vrow = (const char*)(Vsm[buf] + r * 64);
                const bf16x8 av =
                    ld8((const ushort_t*)(vrow + ((ks * 64 + lk * 2) ^ sw)));
                o[n] = mfma16(av, bpf, o[n]);
            }
            __builtin_amdgcn_s_setprio(0);
        }
        __syncthreads();
    }
#undef FLASH_STAGE

    float l = ls0 + ls1;
    l += __shfl_xor(l, 16);
    l += __shfl_xor(l, 32);
    const float inv_l = 1.0f / l;
    const int qrow = b * TLEN + q0 + lrow;
#pragma unroll
    for (int n = 0; n < 4; ++n) {
        ushort_t o4[4];
#pragma unroll
        for (int r = 0; r < 4; ++r) o4[r] = f2b(o[n][r] * inv_l);
        *(uint2*)(attn + (size_t)qrow * DIMD + h * HDIM + n * 16 + g * 4) = *(uint2*)&o4[0];
    }
}

extern "C" void kernel_launch(void* const* d_in, const int* in_sizes, int n_in,
                              void* d_out, int out_size, void* d_ws, size_t ws_size,
                              hipStream_t stream) {
    const float* x = (const float*)d_in[0];
    const float* ln1_g = (const float*)d_in[2];
    const float* ln1_b = (const float*)d_in[3];
    const float* Wq = (const float*)d_in[4];
    const float* bq = (const float*)d_in[5];
    const float* Wk = (const float*)d_in[6];
    const float* bk = (const float*)d_in[7];
    const float* Wv = (const float*)d_in[8];
    const float* bv = (const float*)d_in[9];
    const float* Wo = (const float*)d_in[10];
    const float* bo = (const float*)d_in[11];
    const float* ln2_g = (const float*)d_in[12];
    const float* ln2_b = (const float*)d_in[13];
    const float* W1 = (const float*)d_in[14];
    const float* b1 = (const float*)d_in[15];
    const float* W2 = (const float*)d_in[16];
    const float* b2 = (const float*)d_in[17];
    float* out = (float*)d_out;

    char* p = (char*)d_ws;
    ushort_t* wt_qkv = (ushort_t*)p; p += (size_t)3072 * 1024 * 2;
    ushort_t* wot = (ushort_t*)p;    p += (size_t)1024 * 1024 * 2;
    ushort_t* w1t = (ushort_t*)p;    p += (size_t)4096 * 1024 * 2;
    ushort_t* w2t = (ushort_t*)p;    p += (size_t)4096 * 1024 * 2;
    float* cosv = (float*)p;         p += (size_t)TLEN * 32 * 4;
    float* sinv = (float*)p;         p += (size_t)TLEN * 32 * 4;
    float* bias_qkv = (float*)p;     p += 3072 * 4;
    ushort_t* n1 = (ushort_t*)p;     p += (size_t)MROWS * DIMD * 2;
    ushort_t* qkv = (ushort_t*)p;    p += (size_t)MROWS * 3072 * 2;
    ushort_t* Qb = (ushort_t*)p;     p += (size_t)MROWS * DIMD * 2;
    ushort_t* Kb = (ushort_t*)p;     p += (size_t)MROWS * DIMD * 2;
    ushort_t* VtG = (ushort_t*)p;    p += (size_t)MROWS * DIMD * 2;
    ushort_t* attn = (ushort_t*)p;   p += (size_t)MROWS * DIMD * 2;
    float* x1 = (float*)p;           p += (size_t)MROWS * DIMD * 4;
    ushort_t* n2 = (ushort_t*)p;     p += (size_t)MROWS * DIMD * 2;
    ushort_t* ff1 = (ushort_t*)p;    p += (size_t)MROWS * FFD * 2;

    prep_kernel<<<12556, 256, 0, stream>>>(Wq, Wk, Wv, Wo, W1, W2, bq, bk, bv,
                                           wt_qkv, wot, w1t, w2t, cosv, sinv,
                                           bias_qkv);
    ln_kernel<<<MROWS, 256, 0, stream>>>(x, ln1_g, ln1_b, n1);
    gemm8_kernel<false, true><<<dim3(3072 / 256, MROWS / 256), 512, 0, stream>>>(
        n1, wt_qkv, bias_qkv, nullptr, qkv, MROWS, 3072, 1024);
    qkv_post_kernel<<<dim3(TLEN / 64, BATCH * NHEAD), 256, 0, stream>>>(
        qkv, cosv, sinv, Qb, Kb, VtG);
    flash_kernel<<<1024, 256, 0, stream>>>(Qb, Kb, VtG, attn);
    gemm_kernel<false, true, false><<<dim3(1024 / 128, MROWS / 128), 256, 0, stream>>>(
        attn, wot, bo, x, x1, nullptr, MROWS, 1024, 1024);
    ln_kernel<<<MROWS, 256, 0, stream>>>(x1, ln2_g, ln2_b, n2);
    gemm8_kernel<true, true><<<dim3(4096 / 256, MROWS / 256), 512, 0, stream>>>(
        n2, w1t, b1, nullptr, ff1, MROWS, 4096, 1024);
    gemm_kernel<false, true, false><<<dim3(1024 / 128, MROWS / 128), 256, 0, stream>>>(
        ff1, w2t, b2, x1, out, nullptr, MROWS, 1024, 4096);
}

// Round 6
// 290.654 us; speedup vs baseline: 1.7465x; 1.0741x over previous
//
#include <hip/hip_runtime.h>

typedef unsigned short ushort_t;
typedef unsigned int uint_t;
typedef __bf16 bf16x8 __attribute__((ext_vector_type(8)));
typedef float f32x4 __attribute__((ext_vector_type(4)));

#define DIMD 1024
#define FFD 4096
#define NHEAD 16
#define HDIM 64
#define TLEN 2048
#define BATCH 2
#define MROWS (BATCH * TLEN)  // 4096
// 0.125 * log2(e): folds the 1/sqrt(64) scale and exp->exp2 conversion into Q
#define QSCALE 0.18033688011112042f
// static softmax shift (log2 units): |s| bound ~12, shift is a pure FP rescale
#define SMAX 20.0f

__device__ __forceinline__ ushort_t f2b(float f) {
    uint_t u = __builtin_bit_cast(uint_t, f);
    u = u + 0x7fffu + ((u >> 16) & 1u);
    return (ushort_t)(u >> 16);
}
__device__ __forceinline__ float b2f(ushort_t b) {
    uint_t u = ((uint_t)b) << 16;
    return __builtin_bit_cast(float, u);
}
__device__ __forceinline__ bf16x8 ld8(const ushort_t* p) {
    uint4 v = *(const uint4*)(p);
    return __builtin_bit_cast(bf16x8, v);
}
__device__ __forceinline__ bf16x8 ld8b(const char* p) {
    uint4 v = *(const uint4*)(p);
    return __builtin_bit_cast(bf16x8, v);
}
__device__ __forceinline__ f32x4 mfma16(bf16x8 a, bf16x8 b, f32x4 c) {
    return __builtin_amdgcn_mfma_f32_16x16x32_bf16(a, b, c, 0, 0, 0);
}
__device__ __forceinline__ uint_t cvtpk(float lo, float hi) {
    uint_t r;
    asm("v_cvt_pk_bf16_f32 %0, %1, %2" : "=v"(r) : "v"(lo), "v"(hi));
    return r;
}
__device__ __forceinline__ float exp2a(float x) {
    float r;
    asm("v_exp_f32 %0, %1" : "=v"(r) : "v"(x));
    return r;
}
__device__ __forceinline__ void gload16(const void* g, void* l) {
    __builtin_amdgcn_global_load_lds(
        (const __attribute__((address_space(1))) void*)g,
        (__attribute__((address_space(3))) void*)l, 16, 0, 0);
}

// ================= prep: all weight transposes + rope tables + bias pack =================
__global__ __launch_bounds__(256) void prep_kernel(
    const float* __restrict__ Wq, const float* __restrict__ Wk,
    const float* __restrict__ Wv, const float* __restrict__ Wo,
    const float* __restrict__ W1, const float* __restrict__ W2,
    const float* __restrict__ bq, const float* __restrict__ bk,
    const float* __restrict__ bv,
    ushort_t* __restrict__ wt_qkv, ushort_t* __restrict__ wot,
    ushort_t* __restrict__ w1t, ushort_t* __restrict__ w2t,
    float* __restrict__ cosv, float* __restrict__ sinv,
    float* __restrict__ bias_qkv) {
    __shared__ float tile[32][33];
    const int id = blockIdx.x;
    const int tid = threadIdx.x;
    if (id < 12288) {
        const float* in;
        ushort_t* out;
        int R, C, bx, by;
        if (id < 4096) {
            const int w = id >> 10, loc = id & 1023;
            in = (w == 0) ? Wq : (w == 1) ? Wk : (w == 2) ? Wv : Wo;
            out = (w == 3) ? wot : wt_qkv + (size_t)w * 1024 * 1024;
            R = 1024; C = 1024; bx = loc & 31; by = loc >> 5;
        } else if (id < 8192) {
            const int loc = id - 4096;
            in = W1; out = w1t; R = 1024; C = 4096;
            bx = loc & 127; by = loc >> 7;
        } else {
            const int loc = id - 8192;
            in = W2; out = w2t; R = 4096; C = 1024;
            bx = loc & 31; by = loc >> 5;
        }
        const int c0 = bx * 32, r0 = by * 32;
        const int tx = tid & 31, ty = tid >> 5;  // 32 x 8
#pragma unroll
        for (int i = 0; i < 4; ++i)
            tile[ty + i * 8][tx] = in[(size_t)(r0 + ty + i * 8) * C + c0 + tx];
        __syncthreads();
#pragma unroll
        for (int i = 0; i < 4; ++i)
            out[(size_t)(c0 + ty + i * 8) * R + r0 + tx] = f2b(tile[tx][ty + i * 8]);
    } else if (id < 12544) {
        const int idx = (id - 12288) * 256 + tid;  // T*32
        const int i = idx & 31;
        const int t = idx >> 5;
        const float invf = powf(10000.0f, -(float)i / 32.0f);
        const float a = (float)t * invf;
        cosv[idx] = cosf(a);
        sinv[idx] = sinf(a);
    } else {
        const int i = (id - 12544) * 256 + tid;
        if (i < 3072) {
            float v = (i < 1024) ? bq[i] : (i < 2048) ? bk[i - 1024] : bv[i - 2048];
            bias_qkv[i] = v;
        }
    }
}

// ---------------- layernorm fp32 -> bf16, one row (1024) per block ----------------
__global__ __launch_bounds__(256) void ln_kernel(const float* __restrict__ x,
                                                 const float* __restrict__ g,
                                                 const float* __restrict__ bta,
                                                 ushort_t* __restrict__ out) {
    const int row = blockIdx.x;
    const int tid = threadIdx.x;
    const float4 v = *(const float4*)(x + (size_t)row * DIMD + tid * 4);
    float s = v.x + v.y + v.z + v.w;
    float sq = v.x * v.x + v.y * v.y + v.z * v.z + v.w * v.w;
#pragma unroll
    for (int off = 1; off < 64; off <<= 1) {
        s += __shfl_xor(s, off);
        sq += __shfl_xor(sq, off);
    }
    __shared__ float rs[4], rq[4];
    const int wave = tid >> 6;
    if ((tid & 63) == 0) { rs[wave] = s; rq[wave] = sq; }
    __syncthreads();
    s = rs[0] + rs[1] + rs[2] + rs[3];
    sq = rq[0] + rq[1] + rq[2] + rq[3];
    const float mean = s * (1.0f / DIMD);
    const float var = sq * (1.0f / DIMD) - mean * mean;
    const float rstd = rsqrtf(var + 1e-5f);
    const float4 gv = *(const float4*)(g + tid * 4);
    const float4 bv = *(const float4*)(bta + tid * 4);
    ushort_t o[4];
    o[0] = f2b((v.x - mean) * rstd * gv.x + bv.x);
    o[1] = f2b((v.y - mean) * rstd * gv.y + bv.y);
    o[2] = f2b((v.z - mean) * rstd * gv.z + bv.z);
    o[3] = f2b((v.w - mean) * rstd * gv.w + bv.w);
    *(uint2*)(out + (size_t)row * DIMD + tid * 4) = *(uint2*)&o[0];
}

// ================= GEMM 256x256 8-phase (m201 template) + XCD swizzle =================
template <bool GELU, bool OUTBF16>
__global__ __launch_bounds__(512, 2) void gemm8_kernel(
    const ushort_t* __restrict__ A, const ushort_t* __restrict__ Bt,
    const float* __restrict__ bias,
    float* __restrict__ outf, ushort_t* __restrict__ outb,
    int M, int N, int K) {
    __shared__ __align__(16) ushort_t Abuf[2][2][128 * 64];
    __shared__ __align__(16) ushort_t Bbuf[2][2][128 * 64];
    const int tid = threadIdx.x;
    const int lane = tid & 63;
    const int wave = tid >> 6;
    const int wm = wave >> 2;
    const int wn = wave & 3;
    // XCD-chunked swizzle (nwg % 8 == 0 for all our shapes)
    const int nwg = gridDim.x * gridDim.y;
    const int lin = blockIdx.y * gridDim.x + blockIdx.x;
    const int wg = (lin & 7) * (nwg >> 3) + (lin >> 3);
    const int bm = (wg / gridDim.x) * 256;
    const int bn = (wg % gridDim.x) * 256;
    const int lrow = lane & 15;
    const int lk16 = (lane >> 4) << 4;
    const int swz = (lrow & 7) << 4;

    const int srow = (wave << 4) + (lane >> 3);
    const int scol = ((lane & 7) ^ (lane >> 3)) << 4;
    const ushort_t* aLane = A + (size_t)(bm + srow) * K + (scol >> 1);
    const ushort_t* bLane = Bt + (size_t)(bn + srow) * K + (scol >> 1);
    const size_t h1 = (size_t)128 * K;

    char* const stA00 = (char*)&Abuf[0][0][0];
    char* const stA01 = (char*)&Abuf[0][1][0];
    char* const stA10 = (char*)&Abuf[1][0][0];
    char* const stA11 = (char*)&Abuf[1][1][0];
    char* const stB00 = (char*)&Bbuf[0][0][0];
    char* const stB01 = (char*)&Bbuf[0][1][0];
    char* const stB10 = (char*)&Bbuf[1][0][0];
    char* const stB11 = (char*)&Bbuf[1][1][0];
    const char* const ArdB[2] = {(const char*)&Abuf[0][wm][0],
                                 (const char*)&Abuf[1][wm][0]};
    const char* const BrdB[2] = {(const char*)&Bbuf[0][wn >> 1][0],
                                 (const char*)&Bbuf[1][wn >> 1][0]};
    const int brow0 = (wn & 1) * 64;

#define STG(gp, ldsp)                                                \
    do {                                                             \
        gload16((gp), (ldsp) + (wave << 11));                        \
        gload16((gp) + 8 * (size_t)K, (ldsp) + (wave << 11) + 1024); \
    } while (0)

#define RD_A(buf, MH)                                                          \
    _Pragma("unroll") for (int ii = 0; ii < 4; ++ii)                           \
    _Pragma("unroll") for (int ss = 0; ss < 2; ++ss)                           \
        af[ii][ss] = ld8b(ArdB[buf] + ((((MH)*4 + ii) * 16 + lrow) << 7) +     \
                          (((ss * 64) + lk16) ^ swz));

#define RD_B(buf, NH, DST)                                                     \
    _Pragma("unroll") for (int jj = 0; jj < 2; ++jj)                           \
    _Pragma("unroll") for (int ss = 0; ss < 2; ++ss)                           \
        DST[jj][ss] =                                                          \
            ld8b(BrdB[buf] + ((brow0 + ((NH)*2 + jj) * 16 + lrow) << 7) +      \
                 (((ss * 64) + lk16) ^ swz));

#define MMA(MH, NH, BF)                                                        \
    __builtin_amdgcn_s_setprio(1);                                             \
    _Pragma("unroll") for (int ii = 0; ii < 4; ++ii)                           \
    _Pragma("unroll") for (int jj = 0; jj < 2; ++jj)                           \
    _Pragma("unroll") for (int ss = 0; ss < 2; ++ss)                           \
        acc[(MH)*4 + ii][(NH)*2 + jj] = mfma16(                                \
            af[ii][ss], BF[jj][ss], acc[(MH)*4 + ii][(NH)*2 + jj]);            \
    __builtin_amdgcn_s_setprio(0);

#define BAR() __builtin_amdgcn_s_barrier()

#define GITER(t, LAST)                                                         \
    {                                                                          \
        RD_A(0, 0); RD_B(0, 0, bf0);                                           \
        STG(aLane + (size_t)((t) + 1) * 64, stA10);                            \
        BAR(); MMA(0, 0, bf0); BAR();                                          \
        RD_B(0, 1, bf1);                                                       \
        STG(aLane + h1 + (size_t)((t) + 1) * 64, stA11);                       \
        BAR(); MMA(0, 1, bf1); BAR();                                          \
        RD_A(0, 1);                                                            \
        if (!(LAST)) STG(bLane + (size_t)((t) + 2) * 64, stB00);               \
        BAR(); MMA(1, 1, bf1); BAR();                                          \
        if (!(LAST)) STG(bLane + h1 + (size_t)((t) + 2) * 64, stB01);          \
        BAR(); MMA(1, 0, bf0);                                                 \
        if (LAST) { asm volatile("s_waitcnt vmcnt(0)" ::: "memory"); }         \
        else      { asm volatile("s_waitcnt vmcnt(4)" ::: "memory"); }         \
        BAR();                                                                 \
        RD_A(1, 0); RD_B(1, 0, bf0);                                           \
        if (!(LAST)) STG(aLane + (size_t)((t) + 2) * 64, stA00);               \
        BAR(); MMA(0, 0, bf0); BAR();                                          \
        RD_B(1, 1, bf1);                                                       \
        if (!(LAST)) STG(aLane + h1 + (size_t)((t) + 2) * 64, stA01);          \
        BAR(); MMA(0, 1, bf1); BAR();                                          \
        RD_A(1, 1);                                                            \
        if (!(LAST)) STG(bLane + (size_t)((t) + 3) * 64, stB10);               \
        BAR(); MMA(1, 1, bf1); BAR();                                          \
        if (!(LAST)) STG(bLane + h1 + (size_t)((t) + 3) * 64, stB11);          \
        BAR(); MMA(1, 0, bf0);                                                 \
        if (!(LAST)) { asm volatile("s_waitcnt vmcnt(4)" ::: "memory"); }      \
        BAR();                                                                 \
    }

    f32x4 acc[8][4] = {};
    bf16x8 af[4][2], bf0[2][2], bf1[2][2];

    STG(aLane, stA00);
    STG(aLane + h1, stA01);
    STG(bLane, stB00);
    STG(bLane + h1, stB01);
    STG(bLane + 64, stB10);
    STG(bLane + h1 + 64, stB11);
    asm volatile("s_waitcnt vmcnt(4)" ::: "memory");
    BAR();

    const int niter = K >> 7;
    for (int i = 0; i < niter - 1; ++i) GITER(2 * i, false);
    GITER(2 * (niter - 1), true);

#undef GITER
#undef BAR
#undef MMA
#undef RD_B
#undef RD_A
#undef STG

    const int erow = (lane >> 4) << 2;
#pragma unroll
    for (int i = 0; i < 8; ++i) {
#pragma unroll
        for (int j = 0; j < 4; ++j) {
            const int row = bm + wm * 128 + i * 16 + erow;
            const int col = bn + wn * 64 + j * 16 + lrow;
            const float bz = bias[col];
#pragma unroll
            for (int q = 0; q < 4; ++q) {
                float v = acc[i][j][q] + bz;
                if (GELU) v = 0.5f * v * (1.0f + erff(v * 0.70710678118f));
                if (OUTBF16)
                    outb[(size_t)(row + q) * N + col] = f2b(v);
                else
                    outf[(size_t)(row + q) * N + col] = v;
            }
        }
    }
}

// ================= GEMM p4: 128x64 tile, 4-deep multibuffer, counted vmcnt =================
// For small-N shapes (N=1024): grid (N/64)*(M/128) = 512 blocks = 2/CU.
// BK=32 (64B LDS rows, (row&3)<<4 both-sides XOR swizzle). 4 waves 2x2,
// wave tile 64x32 (4x2 frags, 8 MFMA/iter). 3 stages in flight, never drains.
template <bool GELU, bool RES, bool OUTBF16>
__global__ __launch_bounds__(256) void gemm_p4_kernel(
    const ushort_t* __restrict__ A, const ushort_t* __restrict__ Bt,
    const float* __restrict__ bias, const float* __restrict__ res,
    float* __restrict__ outf, ushort_t* __restrict__ outb,
    int M, int N, int K) {
    __shared__ __align__(16) ushort_t Asm[4][128 * 32];  // 4 x 8KB
    __shared__ __align__(16) ushort_t Bsm[4][64 * 32];   // 4 x 4KB  => 48KB
    const int tid = threadIdx.x;
    const int lane = tid & 63;
    const int wave = tid >> 6;
    const int wm = wave >> 1;  // 0..1
    const int wn = wave & 1;   // 0..1
    const int gx = N >> 6;
    const int nwg = gridDim.x;
    const int lin = blockIdx.x;
    const int wg = (lin & 7) * (nwg >> 3) + (lin >> 3);  // XCD chunking
    const int bm = (wg / gx) << 7;
    const int bn = (wg % gx) << 6;
    const int lrow = lane & 15;
    const int g = lane >> 4;

    // staging: dest byte o = chunk*1024 + lane*16; row = o>>6 (64B rows)
    // pre-swizzled source col byte = ((lane&3) ^ (row&3))<<4
    const int r16 = lane >> 2;  // row within chunk (16 rows/chunk)
    const int scb = (((lane & 3) ^ (r16 & 3)) << 4) >> 1;  // elems
    const ushort_t* AgP0 = A + (size_t)(bm + (wave * 2 + 0) * 16 + r16) * K + scb;
    const ushort_t* AgP1 = A + (size_t)(bm + (wave * 2 + 1) * 16 + r16) * K + scb;
    const ushort_t* BgP = Bt + (size_t)(bn + wave * 16 + r16) * K + scb;
    const int dA0 = (wave * 2 + 0) * 1024 + lane * 16;
    const int dA1 = (wave * 2 + 1) * 1024 + lane * 16;
    const int dB = wave * 1024 + lane * 16;

#define P4_STAGE(buf, k0)                           \
    do {                                            \
        gload16(AgP0 + (k0), (char*)Asm[buf] + dA0); \
        gload16(AgP1 + (k0), (char*)Asm[buf] + dA1); \
        gload16(BgP + (k0), (char*)Bsm[buf] + dB);   \
    } while (0)

#define P4_BODY(t)                                                           \
    {                                                                        \
        const int buf = (t) & 3;                                             \
        if ((t) + 3 < nst) P4_STAGE(((t) + 3) & 3, ((t) + 3) << 5);          \
        bf16x8 af[4], bfr[2];                                                \
        _Pragma("unroll") for (int i = 0; i < 4; ++i)                        \
            af[i] = ld8b((char*)Asm[buf] + ((wm * 64 + i * 16 + lrow) << 6) +\
                         ((g * 16) ^ ((lrow & 3) << 4)));                    \
        _Pragma("unroll") for (int j = 0; j < 2; ++j)                        \
            bfr[j] = ld8b((char*)Bsm[buf] + ((wn * 32 + j * 16 + lrow) << 6)+\
                          ((g * 16) ^ ((lrow & 3) << 4)));                   \
        __builtin_amdgcn_s_setprio(1);                                       \
        _Pragma("unroll") for (int i = 0; i < 4; ++i)                        \
        _Pragma("unroll") for (int j = 0; j < 2; ++j)                        \
            acc[i][j] = mfma16(af[i], bfr[j], acc[i][j]);                    \
        __builtin_amdgcn_s_setprio(0);                                       \
    }

    f32x4 acc[4][2] = {};
    const int nst = K >> 5;  // assumes nst >= 4

    P4_STAGE(0, 0);
    P4_STAGE(1, 32);
    P4_STAGE(2, 64);

    for (int t = 0; t < nst - 2; ++t) {
        asm volatile("s_waitcnt vmcnt(6)" ::: "memory");
        __builtin_amdgcn_s_barrier();
        __builtin_amdgcn_sched_barrier(0);
        P4_BODY(t);
    }
    {
        asm volatile("s_waitcnt vmcnt(3)" ::: "memory");
        __builtin_amdgcn_s_barrier();
        __builtin_amdgcn_sched_barrier(0);
        P4_BODY(nst - 2);
    }
    {
        asm volatile("s_waitcnt vmcnt(0)" ::: "memory");
        __builtin_amdgcn_s_barrier();
        __builtin_amdgcn_sched_barrier(0);
        P4_BODY(nst - 1);
    }
#undef P4_BODY
#undef P4_STAGE

#pragma unroll
    for (int i = 0; i < 4; ++i) {
#pragma unroll
        for (int j = 0; j < 2; ++j) {
#pragma unroll
            for (int q = 0; q < 4; ++q) {
                const int row = bm + wm * 64 + i * 16 + g * 4 + q;
                const int col = bn + wn * 32 + j * 16 + lrow;
                float v = acc[i][j][q] + bias[col];
                if (RES) v += res[(size_t)row * N + col];
                if (GELU) v = 0.5f * v * (1.0f + erff(v * 0.70710678118f));
                if (OUTBF16)
                    outb[(size_t)row * N + col] = f2b(v);
                else
                    outf[(size_t)row * N + col] = v;
            }
        }
    }
}

// ================= fused rope-apply + V-transpose =================
__global__ __launch_bounds__(256) void qkv_post_kernel(
    const ushort_t* __restrict__ qkv, const float* __restrict__ cosv,
    const float* __restrict__ sinv, ushort_t* __restrict__ Qb,
    ushort_t* __restrict__ Kb, ushort_t* __restrict__ VtG) {
    __shared__ ushort_t tile[64][72];
    const int bh = blockIdx.y;
    const int b = bh >> 4, h = bh & 15;
    const int t0 = blockIdx.x * 64;
    const int tid = threadIdx.x;
    {
        const int r = tid >> 2;
        const int i0 = (tid & 3) * 8;
        const int t = t0 + r;
        const size_t rowoff = ((size_t)(b * TLEN + t)) * 3072 + h * 64;
        union { uint4 u; ushort_t s[8]; } q1v, q2v, k1v, k2v;
        q1v.u = *(const uint4*)(qkv + rowoff + i0);
        q2v.u = *(const uint4*)(qkv + rowoff + 32 + i0);
        k1v.u = *(const uint4*)(qkv + rowoff + 1024 + i0);
        k2v.u = *(const uint4*)(qkv + rowoff + 1024 + 32 + i0);
        const size_t ooff = ((size_t)bh * TLEN + t) * 64;
        ushort_t oq1[8], oq2[8], ok1[8], ok2[8];
#pragma unroll
        for (int j = 0; j < 8; ++j) {
            const float c = cosv[t * 32 + i0 + j];
            const float s = sinv[t * 32 + i0 + j];
            const float a1 = b2f(q1v.s[j]), a2 = b2f(q2v.s[j]);
            const float c1 = b2f(k1v.s[j]), c2 = b2f(k2v.s[j]);
            oq1[j] = f2b((a1 * c - a2 * s) * QSCALE);
            oq2[j] = f2b((a2 * c + a1 * s) * QSCALE);
            ok1[j] = f2b(c1 * c - c2 * s);
            ok2[j] = f2b(c2 * c + c1 * s);
        }
        *(uint4*)(Qb + ooff + i0) = *(uint4*)oq1;
        *(uint4*)(Qb + ooff + 32 + i0) = *(uint4*)oq2;
        *(uint4*)(Kb + ooff + i0) = *(uint4*)ok1;
        *(uint4*)(Kb + ooff + 32 + i0) = *(uint4*)ok2;
    }
    {
        const int r = tid >> 2;
        const int dp = (tid & 3) * 16;
        const ushort_t* src =
            qkv + (size_t)(b * TLEN + t0 + r) * 3072 + 2048 + h * 64 + dp;
        *(uint4*)&tile[r][dp] = *(const uint4*)src;
        *(uint4*)&tile[r][dp + 8] = *(const uint4*)(src + 8);
        __syncthreads();
        const int d = tid >> 2;
        const int tp = (tid & 3) * 16;
        ushort_t* dst = VtG + (size_t)bh * HDIM * TLEN + (size_t)d * TLEN + t0 + tp;
        ushort_t tmp[16];
#pragma unroll
        for (int j = 0; j < 16; ++j) tmp[j] = tile[tp + j][d];
        *(uint4*)dst = *(uint4*)&tmp[0];
        *(uint4*)(dst + 8) = *(uint4*)&tmp[8];
    }
}

// ---------------- flash attention v4: static-max softmax, deferred l-reduce ----------------
__global__ __launch_bounds__(256) void flash_kernel(const ushort_t* __restrict__ Qb,
                                                    const ushort_t* __restrict__ Kb,
                                                    const ushort_t* __restrict__ VtG,
                                                    ushort_t* __restrict__ attn) {
    __shared__ __align__(16) ushort_t Ksm[2][64 * 64];
    __shared__ __align__(16) ushort_t Vsm[2][64 * 64];
    const int wg = (blockIdx.x & 7) * 128 + (blockIdx.x >> 3);
    const int bh = wg >> 5;
    const int qblk = wg & 31;
    const int b = bh >> 4, h = bh & 15;
    const int lane = threadIdx.x & 63;
    const int wave = threadIdx.x >> 6;
    const int q0 = qblk * 64 + wave * 16;
    const int lrow = lane & 15;
    const int g = lane >> 4;
    const int lk = g * 8;

    const ushort_t* Qp = Qb + ((size_t)bh * TLEN + q0) * HDIM;
    const ushort_t* Kp = Kb + (size_t)bh * TLEN * HDIM;
    const ushort_t* Vt = VtG + (size_t)bh * HDIM * TLEN;

    const int ch0 = wave * 2, ch1 = wave * 2 + 1;
    const int so0 = (ch0 << 10) + lane * 16;
    const int so1 = (ch1 << 10) + lane * 16;
    const int sr0 = so0 >> 7, sr1 = so1 >> 7;
    const int cb0 = (so0 & 127) ^ ((sr0 & 7) << 4);
    const int cb1 = (so1 & 127) ^ ((sr1 & 7) << 4);
    const ushort_t* Kg0 = Kp + (size_t)sr0 * HDIM + (cb0 >> 1);
    const ushort_t* Kg1 = Kp + (size_t)sr1 * HDIM + (cb1 >> 1);
    const ushort_t* Vg0 = Vt + (size_t)sr0 * TLEN + (cb0 >> 1);
    const ushort_t* Vg1 = Vt + (size_t)sr1 * TLEN + (cb1 >> 1);

#define FLASH_STAGE(buf, kb)                                               \
    {                                                                      \
        gload16(Kg0 + (size_t)(kb) * HDIM, (char*)Ksm[buf] + (ch0 << 10)); \
        gload16(Kg1 + (size_t)(kb) * HDIM, (char*)Ksm[buf] + (ch1 << 10)); \
        gload16(Vg0 + (kb), (char*)Vsm[buf] + (ch0 << 10));                \
        gload16(Vg1 + (kb), (char*)Vsm[buf] + (ch1 << 10));                \
    }

    bf16x8 bq0 = ld8(Qp + lrow * 64 + lk);
    bf16x8 bq1 = ld8(Qp + lrow * 64 + 32 + lk);

    f32x4 o[4] = {};
    float ls0 = 0.0f, ls1 = 0.0f;

    const int srcA = lrow + ((g & 1) << 5);
    const int srcB = srcA + 16;
    const int csel = g >> 1;

    FLASH_STAGE(0, 0);
    __syncthreads();

    for (int it = 0; it < TLEN / 64; ++it) {
        const int buf = it & 1;
        if (it + 1 < TLEN / 64) FLASH_STAGE(buf ^ 1, (it + 1) * 64);

        f32x4 s[4];
        __builtin_amdgcn_s_setprio(1);
#pragma unroll
        for (int kt = 0; kt < 4; ++kt) {
            const int r = kt * 16 + lrow;
            const int sw = (r & 7) << 4;
            const char* krow = (const char*)(Ksm[buf] + r * 64);
            f32x4 a = {-SMAX, -SMAX, -SMAX, -SMAX};
            a = mfma16(ld8((const ushort_t*)(krow + ((lk * 2) ^ sw))), bq0, a);
            a = mfma16(ld8((const ushort_t*)(krow + ((64 + lk * 2) ^ sw))), bq1, a);
            s[kt] = a;
        }
        __builtin_amdgcn_s_setprio(0);
        uint_t pk0[4], pk1[4];
#pragma unroll
        for (int kt = 0; kt < 4; ++kt) {
            const float p0 = exp2a(s[kt][0]);
            const float p1 = exp2a(s[kt][1]);
            const float p2 = exp2a(s[kt][2]);
            const float p3 = exp2a(s[kt][3]);
            ls0 += p0 + p1;
            ls1 += p2 + p3;
            pk0[kt] = cvtpk(p0, p1);
            pk1[kt] = cvtpk(p2, p3);
        }
#pragma unroll
        for (int ks = 0; ks < 2; ++ks) {
            const int ktA = 2 * ks, ktB = 2 * ks + 1;
            const uint_t d0a = (uint_t)__shfl((int)pk0[ktA], srcA);
            const uint_t d0b = (uint_t)__shfl((int)pk0[ktB], srcA);
            const uint_t d1a = (uint_t)__shfl((int)pk1[ktA], srcA);
            const uint_t d1b = (uint_t)__shfl((int)pk1[ktB], srcA);
            const uint_t d2a = (uint_t)__shfl((int)pk0[ktA], srcB);
            const uint_t d2b = (uint_t)__shfl((int)pk0[ktB], srcB);
            const uint_t d3a = (uint_t)__shfl((int)pk1[ktA], srcB);
            const uint_t d3b = (uint_t)__shfl((int)pk1[ktB], srcB);
            uint4 bp;
            bp.x = csel ? d0b : d0a;
            bp.y = csel ? d1b : d1a;
            bp.z = csel ? d2b : d2a;
            bp.w = csel ? d3b : d3a;
            const bf16x8 bpf = __builtin_bit_cast(bf16x8, bp);
            __builtin_amdgcn_s_setprio(1);
#pragma unroll
            for (int n = 0; n < 4; ++n) {
                const int r = n * 16 + lrow;
                const int sw = (r & 7) << 4;
                const char* vrow = (const char*)(Vsm[buf] + r * 64);
                const bf16x8 av =
                    ld8((const ushort_t*)(vrow + ((ks * 64 + lk * 2) ^ sw)));
                o[n] = mfma16(av, bpf, o[n]);
            }
            __builtin_amdgcn_s_setprio(0);
        }
        __syncthreads();
    }
#undef FLASH_STAGE

    float l = ls0 + ls1;
    l += __shfl_xor(l, 16);
    l += __shfl_xor(l, 32);
    const float inv_l = 1.0f / l;
    const int qrow = b * TLEN + q0 + lrow;
#pragma unroll
    for (int n = 0; n < 4; ++n) {
        ushort_t o4[4];
#pragma unroll
        for (int r = 0; r < 4; ++r) o4[r] = f2b(o[n][r] * inv_l);
        *(uint2*)(attn + (size_t)qrow * DIMD + h * HDIM + n * 16 + g * 4) = *(uint2*)&o4[0];
    }
}

extern "C" void kernel_launch(void* const* d_in, const int* in_sizes, int n_in,
                              void* d_out, int out_size, void* d_ws, size_t ws_size,
                              hipStream_t stream) {
    const float* x = (const float*)d_in[0];
    const float* ln1_g = (const float*)d_in[2];
    const float* ln1_b = (const float*)d_in[3];
    const float* Wq = (const float*)d_in[4];
    const float* bq = (const float*)d_in[5];
    const float* Wk = (const float*)d_in[6];
    const float* bk = (const float*)d_in[7];
    const float* Wv = (const float*)d_in[8];
    const float* bv = (const float*)d_in[9];
    const float* Wo = (const float*)d_in[10];
    const float* bo = (const float*)d_in[11];
    const float* ln2_g = (const float*)d_in[12];
    const float* ln2_b = (const float*)d_in[13];
    const float* W1 = (const float*)d_in[14];
    const float* b1 = (const float*)d_in[15];
    const float* W2 = (const float*)d_in[16];
    const float* b2 = (const float*)d_in[17];
    float* out = (float*)d_out;

    char* p = (char*)d_ws;
    ushort_t* wt_qkv = (ushort_t*)p; p += (size_t)3072 * 1024 * 2;
    ushort_t* wot = (ushort_t*)p;    p += (size_t)1024 * 1024 * 2;
    ushort_t* w1t = (ushort_t*)p;    p += (size_t)4096 * 1024 * 2;
    ushort_t* w2t = (ushort_t*)p;    p += (size_t)4096 * 1024 * 2;
    float* cosv = (float*)p;         p += (size_t)TLEN * 32 * 4;
    float* sinv = (float*)p;         p += (size_t)TLEN * 32 * 4;
    float* bias_qkv = (float*)p;     p += 3072 * 4;
    ushort_t* n1 = (ushort_t*)p;     p += (size_t)MROWS * DIMD * 2;
    ushort_t* qkv = (ushort_t*)p;    p += (size_t)MROWS * 3072 * 2;
    ushort_t* Qb = (ushort_t*)p;     p += (size_t)MROWS * DIMD * 2;
    ushort_t* Kb = (ushort_t*)p;     p += (size_t)MROWS * DIMD * 2;
    ushort_t* VtG = (ushort_t*)p;    p += (size_t)MROWS * DIMD * 2;
    ushort_t* attn = (ushort_t*)p;   p += (size_t)MROWS * DIMD * 2;
    float* x1 = (float*)p;           p += (size_t)MROWS * DIMD * 4;
    ushort_t* n2 = (ushort_t*)p;     p += (size_t)MROWS * DIMD * 2;
    ushort_t* ff1 = (ushort_t*)p;    p += (size_t)MROWS * FFD * 2;

    prep_kernel<<<12556, 256, 0, stream>>>(Wq, Wk, Wv, Wo, W1, W2, bq, bk, bv,
                                           wt_qkv, wot, w1t, w2t, cosv, sinv,
                                           bias_qkv);
    ln_kernel<<<MROWS, 256, 0, stream>>>(x, ln1_g, ln1_b, n1);
    gemm8_kernel<false, true><<<dim3(3072 / 256, MROWS / 256), 512, 0, stream>>>(
        n1, wt_qkv, bias_qkv, nullptr, qkv, MROWS, 3072, 1024);
    qkv_post_kernel<<<dim3(TLEN / 64, BATCH * NHEAD), 256, 0, stream>>>(
        qkv, cosv, sinv, Qb, Kb, VtG);
    flash_kernel<<<1024, 256, 0, stream>>>(Qb, Kb, VtG, attn);
    gemm_p4_kernel<false, true, false><<<512, 256, 0, stream>>>(
        attn, wot, bo, x, x1, nullptr, MROWS, 1024, 1024);
    ln_kernel<<<MROWS, 256, 0, stream>>>(x1, ln2_g, ln2_b, n2);
    gemm8_kernel<true, true><<<dim3(4096 / 256, MROWS / 256), 512, 0, stream>>>(
        n2, w1t, b1, nullptr, ff1, MROWS, 4096, 1024);
    gemm_p4_kernel<false, true, false><<<512, 256, 0, stream>>>(
        ff1, w2t, b2, x1, out, nullptr, MROWS, 1024, 4096);
}

// Round 7
// 283.491 us; speedup vs baseline: 1.7906x; 1.0253x over previous
//
#include <hip/hip_runtime.h>

typedef unsigned short ushort_t;
typedef unsigned int uint_t;
typedef __bf16 bf16x8 __attribute__((ext_vector_type(8)));
typedef float f32x4 __attribute__((ext_vector_type(4)));

#define DIMD 1024
#define FFD 4096
#define NHEAD 16
#define HDIM 64
#define TLEN 2048
#define BATCH 2
#define MROWS (BATCH * TLEN)  // 4096
// 0.125 * log2(e): folds the 1/sqrt(64) scale and exp->exp2 conversion into Q
#define QSCALE 0.18033688011112042f
// static softmax shift (log2 units): |s| bound ~12, shift is a pure FP rescale
#define SMAX 20.0f

__device__ __forceinline__ ushort_t f2b(float f) {
    uint_t u = __builtin_bit_cast(uint_t, f);
    u = u + 0x7fffu + ((u >> 16) & 1u);
    return (ushort_t)(u >> 16);
}
__device__ __forceinline__ float b2f(ushort_t b) {
    uint_t u = ((uint_t)b) << 16;
    return __builtin_bit_cast(float, u);
}
__device__ __forceinline__ bf16x8 ld8(const ushort_t* p) {
    uint4 v = *(const uint4*)(p);
    return __builtin_bit_cast(bf16x8, v);
}
__device__ __forceinline__ bf16x8 ld8b(const char* p) {
    uint4 v = *(const uint4*)(p);
    return __builtin_bit_cast(bf16x8, v);
}
__device__ __forceinline__ f32x4 mfma16(bf16x8 a, bf16x8 b, f32x4 c) {
    return __builtin_amdgcn_mfma_f32_16x16x32_bf16(a, b, c, 0, 0, 0);
}
__device__ __forceinline__ uint_t cvtpk(float lo, float hi) {
    uint_t r;
    asm("v_cvt_pk_bf16_f32 %0, %1, %2" : "=v"(r) : "v"(lo), "v"(hi));
    return r;
}
__device__ __forceinline__ float exp2a(float x) {
    float r;
    asm("v_exp_f32 %0, %1" : "=v"(r) : "v"(x));
    return r;
}
__device__ __forceinline__ void gload16(const void* g, void* l) {
    __builtin_amdgcn_global_load_lds(
        (const __attribute__((address_space(1))) void*)g,
        (__attribute__((address_space(3))) void*)l, 16, 0, 0);
}

// ================= prep: all weight transposes + rope tables + bias pack =================
__global__ __launch_bounds__(256) void prep_kernel(
    const float* __restrict__ Wq, const float* __restrict__ Wk,
    const float* __restrict__ Wv, const float* __restrict__ Wo,
    const float* __restrict__ W1, const float* __restrict__ W2,
    const float* __restrict__ bq, const float* __restrict__ bk,
    const float* __restrict__ bv,
    ushort_t* __restrict__ wt_qkv, ushort_t* __restrict__ wot,
    ushort_t* __restrict__ w1t, ushort_t* __restrict__ w2t,
    float* __restrict__ cosv, float* __restrict__ sinv,
    float* __restrict__ bias_qkv) {
    __shared__ float tile[32][33];
    const int id = blockIdx.x;
    const int tid = threadIdx.x;
    if (id < 12288) {
        const float* in;
        ushort_t* out;
        int R, C, bx, by;
        if (id < 4096) {
            const int w = id >> 10, loc = id & 1023;
            in = (w == 0) ? Wq : (w == 1) ? Wk : (w == 2) ? Wv : Wo;
            out = (w == 3) ? wot : wt_qkv + (size_t)w * 1024 * 1024;
            R = 1024; C = 1024; bx = loc & 31; by = loc >> 5;
        } else if (id < 8192) {
            const int loc = id - 4096;
            in = W1; out = w1t; R = 1024; C = 4096;
            bx = loc & 127; by = loc >> 7;
        } else {
            const int loc = id - 8192;
            in = W2; out = w2t; R = 4096; C = 1024;
            bx = loc & 31; by = loc >> 5;
        }
        const int c0 = bx * 32, r0 = by * 32;
        const int tx = tid & 31, ty = tid >> 5;  // 32 x 8
#pragma unroll
        for (int i = 0; i < 4; ++i)
            tile[ty + i * 8][tx] = in[(size_t)(r0 + ty + i * 8) * C + c0 + tx];
        __syncthreads();
#pragma unroll
        for (int i = 0; i < 4; ++i)
            out[(size_t)(c0 + ty + i * 8) * R + r0 + tx] = f2b(tile[tx][ty + i * 8]);
    } else if (id < 12544) {
        const int idx = (id - 12288) * 256 + tid;  // T*32
        const int i = idx & 31;
        const int t = idx >> 5;
        const float invf = powf(10000.0f, -(float)i / 32.0f);
        const float a = (float)t * invf;
        cosv[idx] = cosf(a);
        sinv[idx] = sinf(a);
    } else {
        const int i = (id - 12544) * 256 + tid;
        if (i < 3072) {
            float v = (i < 1024) ? bq[i] : (i < 2048) ? bk[i - 1024] : bv[i - 2048];
            bias_qkv[i] = v;
        }
    }
}

// ---------------- layernorm fp32 -> bf16, one row (1024) per block ----------------
__global__ __launch_bounds__(256) void ln_kernel(const float* __restrict__ x,
                                                 const float* __restrict__ g,
                                                 const float* __restrict__ bta,
                                                 ushort_t* __restrict__ out) {
    const int row = blockIdx.x;
    const int tid = threadIdx.x;
    const float4 v = *(const float4*)(x + (size_t)row * DIMD + tid * 4);
    float s = v.x + v.y + v.z + v.w;
    float sq = v.x * v.x + v.y * v.y + v.z * v.z + v.w * v.w;
#pragma unroll
    for (int off = 1; off < 64; off <<= 1) {
        s += __shfl_xor(s, off);
        sq += __shfl_xor(sq, off);
    }
    __shared__ float rs[4], rq[4];
    const int wave = tid >> 6;
    if ((tid & 63) == 0) { rs[wave] = s; rq[wave] = sq; }
    __syncthreads();
    s = rs[0] + rs[1] + rs[2] + rs[3];
    sq = rq[0] + rq[1] + rq[2] + rq[3];
    const float mean = s * (1.0f / DIMD);
    const float var = sq * (1.0f / DIMD) - mean * mean;
    const float rstd = rsqrtf(var + 1e-5f);
    const float4 gv = *(const float4*)(g + tid * 4);
    const float4 bv = *(const float4*)(bta + tid * 4);
    ushort_t o[4];
    o[0] = f2b((v.x - mean) * rstd * gv.x + bv.x);
    o[1] = f2b((v.y - mean) * rstd * gv.y + bv.y);
    o[2] = f2b((v.z - mean) * rstd * gv.z + bv.z);
    o[3] = f2b((v.w - mean) * rstd * gv.w + bv.w);
    *(uint2*)(out + (size_t)row * DIMD + tid * 4) = *(uint2*)&o[0];
}

// ================= GEMM 256x256 8-phase (m201 template) + XCD swizzle + split-K =================
// C = A[M][*ldk] x Bt[N][*ldk]^T over K columns starting at blockIdx.z*K.
// PARTIAL: write raw fp32 partials to outf + z*M*N (no bias/gelu).
template <bool GELU, bool OUTBF16, bool PARTIAL>
__global__ __launch_bounds__(512, 2) void gemm8_kernel(
    const ushort_t* __restrict__ A, const ushort_t* __restrict__ Bt,
    const float* __restrict__ bias,
    float* __restrict__ outf, ushort_t* __restrict__ outb,
    int M, int N, int K, int ldk) {
    __shared__ __align__(16) ushort_t Abuf[2][2][128 * 64];
    __shared__ __align__(16) ushort_t Bbuf[2][2][128 * 64];
    const int tid = threadIdx.x;
    const int lane = tid & 63;
    const int wave = tid >> 6;
    const int wm = wave >> 2;
    const int wn = wave & 3;
    const int kz = blockIdx.z;
    A += (size_t)kz * K;
    Bt += (size_t)kz * K;
    float* outp = PARTIAL ? outf + (size_t)kz * M * N : outf;
    // XCD-chunked swizzle (nwg % 8 == 0 for all our shapes)
    const int nwg = gridDim.x * gridDim.y;
    const int lin = blockIdx.y * gridDim.x + blockIdx.x;
    const int wg = (lin & 7) * (nwg >> 3) + (lin >> 3);
    const int bm = (wg / gridDim.x) * 256;
    const int bn = (wg % gridDim.x) * 256;
    const int lrow = lane & 15;
    const int lk16 = (lane >> 4) << 4;
    const int swz = (lrow & 7) << 4;

    const int srow = (wave << 4) + (lane >> 3);
    const int scol = ((lane & 7) ^ (lane >> 3)) << 4;
    const ushort_t* aLane = A + (size_t)(bm + srow) * ldk + (scol >> 1);
    const ushort_t* bLane = Bt + (size_t)(bn + srow) * ldk + (scol >> 1);
    const size_t h1 = (size_t)128 * ldk;

    char* const stA00 = (char*)&Abuf[0][0][0];
    char* const stA01 = (char*)&Abuf[0][1][0];
    char* const stA10 = (char*)&Abuf[1][0][0];
    char* const stA11 = (char*)&Abuf[1][1][0];
    char* const stB00 = (char*)&Bbuf[0][0][0];
    char* const stB01 = (char*)&Bbuf[0][1][0];
    char* const stB10 = (char*)&Bbuf[1][0][0];
    char* const stB11 = (char*)&Bbuf[1][1][0];
    const char* const ArdB[2] = {(const char*)&Abuf[0][wm][0],
                                 (const char*)&Abuf[1][wm][0]};
    const char* const BrdB[2] = {(const char*)&Bbuf[0][wn >> 1][0],
                                 (const char*)&Bbuf[1][wn >> 1][0]};
    const int brow0 = (wn & 1) * 64;

#define STG(gp, ldsp)                                                  \
    do {                                                               \
        gload16((gp), (ldsp) + (wave << 11));                          \
        gload16((gp) + 8 * (size_t)ldk, (ldsp) + (wave << 11) + 1024); \
    } while (0)

#define RD_A(buf, MH)                                                          \
    _Pragma("unroll") for (int ii = 0; ii < 4; ++ii)                           \
    _Pragma("unroll") for (int ss = 0; ss < 2; ++ss)                           \
        af[ii][ss] = ld8b(ArdB[buf] + ((((MH)*4 + ii) * 16 + lrow) << 7) +     \
                          (((ss * 64) + lk16) ^ swz));

#define RD_B(buf, NH, DST)                                                     \
    _Pragma("unroll") for (int jj = 0; jj < 2; ++jj)                           \
    _Pragma("unroll") for (int ss = 0; ss < 2; ++ss)                           \
        DST[jj][ss] =                                                          \
            ld8b(BrdB[buf] + ((brow0 + ((NH)*2 + jj) * 16 + lrow) << 7) +      \
                 (((ss * 64) + lk16) ^ swz));

#define MMA(MH, NH, BF)                                                        \
    __builtin_amdgcn_s_setprio(1);                                             \
    _Pragma("unroll") for (int ii = 0; ii < 4; ++ii)                           \
    _Pragma("unroll") for (int jj = 0; jj < 2; ++jj)                           \
    _Pragma("unroll") for (int ss = 0; ss < 2; ++ss)                           \
        acc[(MH)*4 + ii][(NH)*2 + jj] = mfma16(                                \
            af[ii][ss], BF[jj][ss], acc[(MH)*4 + ii][(NH)*2 + jj]);            \
    __builtin_amdgcn_s_setprio(0);

#define BAR() __builtin_amdgcn_s_barrier()

#define GITER(t, LAST)                                                         \
    {                                                                          \
        RD_A(0, 0); RD_B(0, 0, bf0);                                           \
        STG(aLane + (size_t)((t) + 1) * 64, stA10);                            \
        BAR(); MMA(0, 0, bf0); BAR();                                          \
        RD_B(0, 1, bf1);                                                       \
        STG(aLane + h1 + (size_t)((t) + 1) * 64, stA11);                       \
        BAR(); MMA(0, 1, bf1); BAR();                                          \
        RD_A(0, 1);                                                            \
        if (!(LAST)) STG(bLane + (size_t)((t) + 2) * 64, stB00);               \
        BAR(); MMA(1, 1, bf1); BAR();                                          \
        if (!(LAST)) STG(bLane + h1 + (size_t)((t) + 2) * 64, stB01);          \
        BAR(); MMA(1, 0, bf0);                                                 \
        if (LAST) { asm volatile("s_waitcnt vmcnt(0)" ::: "memory"); }         \
        else      { asm volatile("s_waitcnt vmcnt(4)" ::: "memory"); }         \
        BAR();                                                                 \
        RD_A(1, 0); RD_B(1, 0, bf0);                                           \
        if (!(LAST)) STG(aLane + (size_t)((t) + 2) * 64, stA00);               \
        BAR(); MMA(0, 0, bf0); BAR();                                          \
        RD_B(1, 1, bf1);                                                       \
        if (!(LAST)) STG(aLane + h1 + (size_t)((t) + 2) * 64, stA01);          \
        BAR(); MMA(0, 1, bf1); BAR();                                          \
        RD_A(1, 1);                                                            \
        if (!(LAST)) STG(bLane + (size_t)((t) + 3) * 64, stB10);               \
        BAR(); MMA(1, 1, bf1); BAR();                                          \
        if (!(LAST)) STG(bLane + h1 + (size_t)((t) + 3) * 64, stB11);          \
        BAR(); MMA(1, 0, bf0);                                                 \
        if (!(LAST)) { asm volatile("s_waitcnt vmcnt(4)" ::: "memory"); }      \
        BAR();                                                                 \
    }

    f32x4 acc[8][4] = {};
    bf16x8 af[4][2], bf0[2][2], bf1[2][2];

    STG(aLane, stA00);
    STG(aLane + h1, stA01);
    STG(bLane, stB00);
    STG(bLane + h1, stB01);
    STG(bLane + 64, stB10);
    STG(bLane + h1 + 64, stB11);
    asm volatile("s_waitcnt vmcnt(4)" ::: "memory");
    BAR();

    const int niter = K >> 7;
    for (int i = 0; i < niter - 1; ++i) GITER(2 * i, false);
    GITER(2 * (niter - 1), true);

#undef GITER
#undef BAR
#undef MMA
#undef RD_B
#undef RD_A
#undef STG

    const int erow = (lane >> 4) << 2;
#pragma unroll
    for (int i = 0; i < 8; ++i) {
#pragma unroll
        for (int j = 0; j < 4; ++j) {
            const int row = bm + wm * 128 + i * 16 + erow;
            const int col = bn + wn * 64 + j * 16 + lrow;
            const float bz = PARTIAL ? 0.0f : bias[col];
#pragma unroll
            for (int q = 0; q < 4; ++q) {
                float v = acc[i][j][q] + bz;
                if (GELU) v = 0.5f * v * (1.0f + erff(v * 0.70710678118f));
                if (OUTBF16)
                    outb[(size_t)(row + q) * N + col] = f2b(v);
                else
                    outp[(size_t)(row + q) * N + col] = v;
            }
        }
    }
}

// ---------------- ff2 split-K reduce: out = x1 + b2 + sum of 4 partials ----------------
__global__ __launch_bounds__(256) void ff2_reduce_kernel(
    const float* __restrict__ parts, const float* __restrict__ x1,
    const float* __restrict__ b2, float* __restrict__ out) {
    const size_t e = ((size_t)blockIdx.x * 256 + threadIdx.x) * 4;
    const size_t np = (size_t)MROWS * DIMD;
    const float4 r = *(const float4*)(x1 + e);
    const float4 bz = *(const float4*)(b2 + (e & (DIMD - 1)));
    const float4 p0 = *(const float4*)(parts + e);
    const float4 p1 = *(const float4*)(parts + np + e);
    const float4 p2 = *(const float4*)(parts + 2 * np + e);
    const float4 p3 = *(const float4*)(parts + 3 * np + e);
    float4 o;
    o.x = r.x + bz.x + ((p0.x + p1.x) + (p2.x + p3.x));
    o.y = r.y + bz.y + ((p0.y + p1.y) + (p2.y + p3.y));
    o.z = r.z + bz.z + ((p0.z + p1.z) + (p2.z + p3.z));
    o.w = r.w + bz.w + ((p0.w + p1.w) + (p2.w + p3.w));
    *(float4*)(out + e) = o;
}

// ================= GEMM p4: 128x64 tile, 4-deep multibuffer (wo-proj) =================
template <bool GELU, bool RES, bool OUTBF16>
__global__ __launch_bounds__(256) void gemm_p4_kernel(
    const ushort_t* __restrict__ A, const ushort_t* __restrict__ Bt,
    const float* __restrict__ bias, const float* __restrict__ res,
    float* __restrict__ outf, ushort_t* __restrict__ outb,
    int M, int N, int K) {
    __shared__ __align__(16) ushort_t Asm[4][128 * 32];
    __shared__ __align__(16) ushort_t Bsm[4][64 * 32];
    const int tid = threadIdx.x;
    const int lane = tid & 63;
    const int wave = tid >> 6;
    const int wm = wave >> 1;
    const int wn = wave & 1;
    const int gx = N >> 6;
    const int nwg = gridDim.x;
    const int lin = blockIdx.x;
    const int wg = (lin & 7) * (nwg >> 3) + (lin >> 3);
    const int bm = (wg / gx) << 7;
    const int bn = (wg % gx) << 6;
    const int lrow = lane & 15;
    const int g = lane >> 4;

    const int r16 = lane >> 2;
    const int scb = (((lane & 3) ^ (r16 & 3)) << 4) >> 1;
    const ushort_t* AgP0 = A + (size_t)(bm + (wave * 2 + 0) * 16 + r16) * K + scb;
    const ushort_t* AgP1 = A + (size_t)(bm + (wave * 2 + 1) * 16 + r16) * K + scb;
    const ushort_t* BgP = Bt + (size_t)(bn + wave * 16 + r16) * K + scb;
    const int dA0 = (wave * 2 + 0) * 1024 + lane * 16;
    const int dA1 = (wave * 2 + 1) * 1024 + lane * 16;
    const int dB = wave * 1024 + lane * 16;

#define P4_STAGE(buf, k0)                            \
    do {                                             \
        gload16(AgP0 + (k0), (char*)Asm[buf] + dA0); \
        gload16(AgP1 + (k0), (char*)Asm[buf] + dA1); \
        gload16(BgP + (k0), (char*)Bsm[buf] + dB);   \
    } while (0)

#define P4_BODY(t)                                                           \
    {                                                                        \
        const int buf = (t) & 3;                                             \
        if ((t) + 3 < nst) P4_STAGE(((t) + 3) & 3, ((t) + 3) << 5);          \
        bf16x8 af[4], bfr[2];                                                \
        _Pragma("unroll") for (int i = 0; i < 4; ++i)                        \
            af[i] = ld8b((char*)Asm[buf] + ((wm * 64 + i * 16 + lrow) << 6) +\
                         ((g * 16) ^ ((lrow & 3) << 4)));                    \
        _Pragma("unroll") for (int j = 0; j < 2; ++j)                        \
            bfr[j] = ld8b((char*)Bsm[buf] + ((wn * 32 + j * 16 + lrow) << 6)+\
                          ((g * 16) ^ ((lrow & 3) << 4)));                   \
        __builtin_amdgcn_s_setprio(1);                                       \
        _Pragma("unroll") for (int i = 0; i < 4; ++i)                        \
        _Pragma("unroll") for (int j = 0; j < 2; ++j)                        \
            acc[i][j] = mfma16(af[i], bfr[j], acc[i][j]);                    \
        __builtin_amdgcn_s_setprio(0);                                       \
    }

    f32x4 acc[4][2] = {};
    const int nst = K >> 5;

    P4_STAGE(0, 0);
    P4_STAGE(1, 32);
    P4_STAGE(2, 64);

    for (int t = 0; t < nst - 2; ++t) {
        asm volatile("s_waitcnt vmcnt(6)" ::: "memory");
        __builtin_amdgcn_s_barrier();
        __builtin_amdgcn_sched_barrier(0);
        P4_BODY(t);
    }
    {
        asm volatile("s_waitcnt vmcnt(3)" ::: "memory");
        __builtin_amdgcn_s_barrier();
        __builtin_amdgcn_sched_barrier(0);
        P4_BODY(nst - 2);
    }
    {
        asm volatile("s_waitcnt vmcnt(0)" ::: "memory");
        __builtin_amdgcn_s_barrier();
        __builtin_amdgcn_sched_barrier(0);
        P4_BODY(nst - 1);
    }
#undef P4_BODY
#undef P4_STAGE

#pragma unroll
    for (int i = 0; i < 4; ++i) {
#pragma unroll
        for (int j = 0; j < 2; ++j) {
#pragma unroll
            for (int q = 0; q < 4; ++q) {
                const int row = bm + wm * 64 + i * 16 + g * 4 + q;
                const int col = bn + wn * 32 + j * 16 + lrow;
                float v = acc[i][j][q] + bias[col];
                if (RES) v += res[(size_t)row * N + col];
                if (GELU) v = 0.5f * v * (1.0f + erff(v * 0.70710678118f));
                if (OUTBF16)
                    outb[(size_t)row * N + col] = f2b(v);
                else
                    outf[(size_t)row * N + col] = v;
            }
        }
    }
}

// ================= fused rope-apply + V-transpose =================
__global__ __launch_bounds__(256) void qkv_post_kernel(
    const ushort_t* __restrict__ qkv, const float* __restrict__ cosv,
    const float* __restrict__ sinv, ushort_t* __restrict__ Qb,
    ushort_t* __restrict__ Kb, ushort_t* __restrict__ VtG) {
    __shared__ ushort_t tile[64][72];
    const int bh = blockIdx.y;
    const int b = bh >> 4, h = bh & 15;
    const int t0 = blockIdx.x * 64;
    const int tid = threadIdx.x;
    {
        const int r = tid >> 2;
        const int i0 = (tid & 3) * 8;
        const int t = t0 + r;
        const size_t rowoff = ((size_t)(b * TLEN + t)) * 3072 + h * 64;
        union { uint4 u; ushort_t s[8]; } q1v, q2v, k1v, k2v;
        q1v.u = *(const uint4*)(qkv + rowoff + i0);
        q2v.u = *(const uint4*)(qkv + rowoff + 32 + i0);
        k1v.u = *(const uint4*)(qkv + rowoff + 1024 + i0);
        k2v.u = *(const uint4*)(qkv + rowoff + 1024 + 32 + i0);
        const size_t ooff = ((size_t)bh * TLEN + t) * 64;
        ushort_t oq1[8], oq2[8], ok1[8], ok2[8];
#pragma unroll
        for (int j = 0; j < 8; ++j) {
            const float c = cosv[t * 32 + i0 + j];
            const float s = sinv[t * 32 + i0 + j];
            const float a1 = b2f(q1v.s[j]), a2 = b2f(q2v.s[j]);
            const float c1 = b2f(k1v.s[j]), c2 = b2f(k2v.s[j]);
            oq1[j] = f2b((a1 * c - a2 * s) * QSCALE);
            oq2[j] = f2b((a2 * c + a1 * s) * QSCALE);
            ok1[j] = f2b(c1 * c - c2 * s);
            ok2[j] = f2b(c2 * c + c1 * s);
        }
        *(uint4*)(Qb + ooff + i0) = *(uint4*)oq1;
        *(uint4*)(Qb + ooff + 32 + i0) = *(uint4*)oq2;
        *(uint4*)(Kb + ooff + i0) = *(uint4*)ok1;
        *(uint4*)(Kb + ooff + 32 + i0) = *(uint4*)ok2;
    }
    {
        const int r = tid >> 2;
        const int dp = (tid & 3) * 16;
        const ushort_t* src =
            qkv + (size_t)(b * TLEN + t0 + r) * 3072 + 2048 + h * 64 + dp;
        *(uint4*)&tile[r][dp] = *(const uint4*)src;
        *(uint4*)&tile[r][dp + 8] = *(const uint4*)(src + 8);
        __syncthreads();
        const int d = tid >> 2;
        const int tp = (tid & 3) * 16;
        ushort_t* dst = VtG + (size_t)bh * HDIM * TLEN + (size_t)d * TLEN + t0 + tp;
        ushort_t tmp[16];
#pragma unroll
        for (int j = 0; j < 16; ++j) tmp[j] = tile[tp + j][d];
        *(uint4*)dst = *(uint4*)&tmp[0];
        *(uint4*)(dst + 8) = *(uint4*)&tmp[8];
    }
}

// ---------------- flash attention v4: static-max softmax, deferred l-reduce ----------------
__global__ __launch_bounds__(256) void flash_kernel(const ushort_t* __restrict__ Qb,
                                                    const ushort_t* __restrict__ Kb,
                                                    const ushort_t* __restrict__ VtG,
                                                    ushort_t* __restrict__ attn) {
    __shared__ __align__(16) ushort_t Ksm[2][64 * 64];
    __shared__ __align__(16) ushort_t Vsm[2][64 * 64];
    const int wg = (blockIdx.x & 7) * 128 + (blockIdx.x >> 3);
    const int bh = wg >> 5;
    const int qblk = wg & 31;
    const int b = bh >> 4, h = bh & 15;
    const int lane = threadIdx.x & 63;
    const int wave = threadIdx.x >> 6;
    const int q0 = qblk * 64 + wave * 16;
    const int lrow = lane & 15;
    const int g = lane >> 4;
    const int lk = g * 8;

    const ushort_t* Qp = Qb + ((size_t)bh * TLEN + q0) * HDIM;
    const ushort_t* Kp = Kb + (size_t)bh * TLEN * HDIM;
    const ushort_t* Vt = VtG + (size_t)bh * HDIM * TLEN;

    const int ch0 = wave * 2, ch1 = wave * 2 + 1;
    const int so0 = (ch0 << 10) + lane * 16;
    const int so1 = (ch1 << 10) + lane * 16;
    const int sr0 = so0 >> 7, sr1 = so1 >> 7;
    const int cb0 = (so0 & 127) ^ ((sr0 & 7) << 4);
    const int cb1 = (so1 & 127) ^ ((sr1 & 7) << 4);
    const ushort_t* Kg0 = Kp + (size_t)sr0 * HDIM + (cb0 >> 1);
    const ushort_t* Kg1 = Kp + (size_t)sr1 * HDIM + (cb1 >> 1);
    const ushort_t* Vg0 = Vt + (size_t)sr0 * TLEN + (cb0 >> 1);
    const ushort_t* Vg1 = Vt + (size_t)sr1 * TLEN + (cb1 >> 1);

#define FLASH_STAGE(buf, kb)                                               \
    {                                                                      \
        gload16(Kg0 + (size_t)(kb) * HDIM, (char*)Ksm[buf] + (ch0 << 10)); \
        gload16(Kg1 + (size_t)(kb) * HDIM, (char*)Ksm[buf] + (ch1 << 10)); \
        gload16(Vg0 + (kb), (char*)Vsm[buf] + (ch0 << 10));                \
        gload16(Vg1 + (kb), (char*)Vsm[buf] + (ch1 << 10));                \
    }

    bf16x8 bq0 = ld8(Qp + lrow * 64 + lk);
    bf16x8 bq1 = ld8(Qp + lrow * 64 + 32 + lk);

    f32x4 o[4] = {};
    float ls0 = 0.0f, ls1 = 0.0f;

    const int srcA = lrow + ((g & 1) << 5);
    const int srcB = srcA + 16;
    const int csel = g >> 1;

    FLASH_STAGE(0, 0);
    __syncthreads();

    for (int it = 0; it < TLEN / 64; ++it) {
        const int buf = it & 1;
        if (it + 1 < TLEN / 64) FLASH_STAGE(buf ^ 1, (it + 1) * 64);

        f32x4 s[4];
        __builtin_amdgcn_s_setprio(1);
#pragma unroll
        for (int kt = 0; kt < 4; ++kt) {
            const int r = kt * 16 + lrow;
            const int sw = (r & 7) << 4;
            const char* krow = (const char*)(Ksm[buf] + r * 64);
            f32x4 a = {-SMAX, -SMAX, -SMAX, -SMAX};
            a = mfma16(ld8((const ushort_t*)(krow + ((lk * 2) ^ sw))), bq0, a);
            a = mfma16(ld8((const ushort_t*)(krow + ((64 + lk * 2) ^ sw))), bq1, a);
            s[kt] = a;
        }
        __builtin_amdgcn_s_setprio(0);
        uint_t pk0[4], pk1[4];
#pragma unroll
        for (int kt = 0; kt < 4; ++kt) {
            const float p0 = exp2a(s[kt][0]);
            const float p1 = exp2a(s[kt][1]);
            const float p2 = exp2a(s[kt][2]);
            const float p3 = exp2a(s[kt][3]);
            ls0 += p0 + p1;
            ls1 += p2 + p3;
            pk0[kt] = cvtpk(p0, p1);
            pk1[kt] = cvtpk(p2, p3);
        }
#pragma unroll
        for (int ks = 0; ks < 2; ++ks) {
            const int ktA = 2 * ks, ktB = 2 * ks + 1;
            const uint_t d0a = (uint_t)__shfl((int)pk0[ktA], srcA);
            const uint_t d0b = (uint_t)__shfl((int)pk0[ktB], srcA);
            const uint_t d1a = (uint_t)__shfl((int)pk1[ktA], srcA);
            const uint_t d1b = (uint_t)__shfl((int)pk1[ktB], srcA);
            const uint_t d2a = (uint_t)__shfl((int)pk0[ktA], srcB);
            const uint_t d2b = (uint_t)__shfl((int)pk0[ktB], srcB);
            const uint_t d3a = (uint_t)__shfl((int)pk1[ktA], srcB);
            const uint_t d3b = (uint_t)__shfl((int)pk1[ktB], srcB);
            uint4 bp;
            bp.x = csel ? d0b : d0a;
            bp.y = csel ? d1b : d1a;
            bp.z = csel ? d2b : d2a;
            bp.w = csel ? d3b : d3a;
            const bf16x8 bpf = __builtin_bit_cast(bf16x8, bp);
            __builtin_amdgcn_s_setprio(1);
#pragma unroll
            for (int n = 0; n < 4; ++n) {
                const int r = n * 16 + lrow;
                const int sw = (r & 7) << 4;
                const char* vrow = (const char*)(Vsm[buf] + r * 64);
                const bf16x8 av =
                    ld8((const ushort_t*)(vrow + ((ks * 64 + lk * 2) ^ sw)));
                o[n] = mfma16(av, bpf, o[n]);
            }
            __builtin_amdgcn_s_setprio(0);
        }
        __syncthreads();
    }
#undef FLASH_STAGE

    float l = ls0 + ls1;
    l += __shfl_xor(l, 16);
    l += __shfl_xor(l, 32);
    const float inv_l = 1.0f / l;
    const int qrow = b * TLEN + q0 + lrow;
#pragma unroll
    for (int n = 0; n < 4; ++n) {
        ushort_t o4[4];
#pragma unroll
        for (int r = 0; r < 4; ++r) o4[r] = f2b(o[n][r] * inv_l);
        *(uint2*)(attn + (size_t)qrow * DIMD + h * HDIM + n * 16 + g * 4) = *(uint2*)&o4[0];
    }
}

extern "C" void kernel_launch(void* const* d_in, const int* in_sizes, int n_in,
                              void* d_out, int out_size, void* d_ws, size_t ws_size,
                              hipStream_t stream) {
    const float* x = (const float*)d_in[0];
    const float* ln1_g = (const float*)d_in[2];
    const float* ln1_b = (const float*)d_in[3];
    const float* Wq = (const float*)d_in[4];
    const float* bq = (const float*)d_in[5];
    const float* Wk = (const float*)d_in[6];
    const float* bk = (const float*)d_in[7];
    const float* Wv = (const float*)d_in[8];
    const float* bv = (const float*)d_in[9];
    const float* Wo = (const float*)d_in[10];
    const float* bo = (const float*)d_in[11];
    const float* ln2_g = (const float*)d_in[12];
    const float* ln2_b = (const float*)d_in[13];
    const float* W1 = (const float*)d_in[14];
    const float* b1 = (const float*)d_in[15];
    const float* W2 = (const float*)d_in[16];
    const float* b2 = (const float*)d_in[17];
    float* out = (float*)d_out;

    char* p = (char*)d_ws;
    ushort_t* wt_qkv = (ushort_t*)p; p += (size_t)3072 * 1024 * 2;
    ushort_t* wot = (ushort_t*)p;    p += (size_t)1024 * 1024 * 2;
    ushort_t* w1t = (ushort_t*)p;    p += (size_t)4096 * 1024 * 2;
    ushort_t* w2t = (ushort_t*)p;    p += (size_t)4096 * 1024 * 2;
    float* cosv = (float*)p;         p += (size_t)TLEN * 32 * 4;
    float* sinv = (float*)p;         p += (size_t)TLEN * 32 * 4;
    float* bias_qkv = (float*)p;     p += 3072 * 4;
    char* reuse0 = p;  // 64MB region reused for ff2 split-K partials
    ushort_t* n1 = (ushort_t*)p;     p += (size_t)MROWS * DIMD * 2;
    ushort_t* qkv = (ushort_t*)p;    p += (size_t)MROWS * 3072 * 2;
    ushort_t* Qb = (ushort_t*)p;     p += (size_t)MROWS * DIMD * 2;
    ushort_t* Kb = (ushort_t*)p;     p += (size_t)MROWS * DIMD * 2;
    ushort_t* VtG = (ushort_t*)p;    p += (size_t)MROWS * DIMD * 2;
    ushort_t* attn = (ushort_t*)p;   p += (size_t)MROWS * DIMD * 2;
    float* x1 = (float*)p;           p += (size_t)MROWS * DIMD * 4;
    ushort_t* n2 = (ushort_t*)p;     p += (size_t)MROWS * DIMD * 2;
    ushort_t* ff1 = (ushort_t*)p;    p += (size_t)MROWS * FFD * 2;
    float* partials = (float*)reuse0;  // 4 x MROWS x DIMD fp32 = 64MB (dead bufs)

    prep_kernel<<<12556, 256, 0, stream>>>(Wq, Wk, Wv, Wo, W1, W2, bq, bk, bv,
                                           wt_qkv, wot, w1t, w2t, cosv, sinv,
                                           bias_qkv);
    ln_kernel<<<MROWS, 256, 0, stream>>>(x, ln1_g, ln1_b, n1);
    gemm8_kernel<false, true, false><<<dim3(3072 / 256, MROWS / 256), 512, 0, stream>>>(
        n1, wt_qkv, bias_qkv, nullptr, qkv, MROWS, 3072, 1024, 1024);
    qkv_post_kernel<<<dim3(TLEN / 64, BATCH * NHEAD), 256, 0, stream>>>(
        qkv, cosv, sinv, Qb, Kb, VtG);
    flash_kernel<<<1024, 256, 0, stream>>>(Qb, Kb, VtG, attn);
    gemm_p4_kernel<false, true, false><<<512, 256, 0, stream>>>(
        attn, wot, bo, x, x1, nullptr, MROWS, 1024, 1024);
    ln_kernel<<<MROWS, 256, 0, stream>>>(x1, ln2_g, ln2_b, n2);
    gemm8_kernel<true, true, false><<<dim3(4096 / 256, MROWS / 256), 512, 0, stream>>>(
        n2, w1t, b1, nullptr, ff1, MROWS, 4096, 1024, 1024);
    gemm8_kernel<false, false, true><<<dim3(1024 / 256, MROWS / 256, 4), 512, 0, stream>>>(
        ff1, w2t, nullptr, partials, nullptr, MROWS, 1024, 1024, 4096);
    ff2_reduce_kernel<<<MROWS * DIMD / 1024, 256, 0, stream>>>(partials, x1, b2, out);
}

// Round 8
// 269.045 us; speedup vs baseline: 1.8867x; 1.0537x over previous
//
#include <hip/hip_runtime.h>

typedef unsigned short ushort_t;
typedef unsigned int uint_t;
typedef __bf16 bf16x8 __attribute__((ext_vector_type(8)));
typedef float f32x4 __attribute__((ext_vector_type(4)));
typedef float f32x16 __attribute__((ext_vector_type(16)));
typedef int i32x2 __attribute__((ext_vector_type(2)));

#define DIMD 1024
#define FFD 4096
#define NHEAD 16
#define HDIM 64
#define TLEN 2048
#define BATCH 2
#define MROWS (BATCH * TLEN)  // 4096
// 0.125 * log2(e): folds the 1/sqrt(64) scale and exp->exp2 conversion into Q
#define QSCALE 0.18033688011112042f
// static softmax shift (log2 units): |s| bound ~12, shift is a pure FP rescale
#define SMAX 20.0f

__device__ __forceinline__ ushort_t f2b(float f) {
    uint_t u = __builtin_bit_cast(uint_t, f);
    u = u + 0x7fffu + ((u >> 16) & 1u);
    return (ushort_t)(u >> 16);
}
__device__ __forceinline__ float b2f(ushort_t b) {
    uint_t u = ((uint_t)b) << 16;
    return __builtin_bit_cast(float, u);
}
__device__ __forceinline__ bf16x8 ld8(const ushort_t* p) {
    uint4 v = *(const uint4*)(p);
    return __builtin_bit_cast(bf16x8, v);
}
__device__ __forceinline__ bf16x8 ld8b(const char* p) {
    uint4 v = *(const uint4*)(p);
    return __builtin_bit_cast(bf16x8, v);
}
__device__ __forceinline__ f32x4 mfma16(bf16x8 a, bf16x8 b, f32x4 c) {
    return __builtin_amdgcn_mfma_f32_16x16x32_bf16(a, b, c, 0, 0, 0);
}
__device__ __forceinline__ f32x16 mfma32(bf16x8 a, bf16x8 b, f32x16 c) {
    return __builtin_amdgcn_mfma_f32_32x32x16_bf16(a, b, c, 0, 0, 0);
}
__device__ __forceinline__ uint_t cvtpk(float lo, float hi) {
    uint_t r;
    asm("v_cvt_pk_bf16_f32 %0, %1, %2" : "=v"(r) : "v"(lo), "v"(hi));
    return r;
}
__device__ __forceinline__ void plswap(uint_t& a, uint_t& b) {
    i32x2 r = __builtin_amdgcn_permlane32_swap((int)a, (int)b, false, false);
    a = (uint_t)r.x;  // [a_lo | b_lo]
    b = (uint_t)r.y;  // [a_hi | b_hi]
}
__device__ __forceinline__ float exp2a(float x) {
    float r;
    asm("v_exp_f32 %0, %1" : "=v"(r) : "v"(x));
    return r;
}
__device__ __forceinline__ void gload16(const void* g, void* l) {
    __builtin_amdgcn_global_load_lds(
        (const __attribute__((address_space(1))) void*)g,
        (__attribute__((address_space(3))) void*)l, 16, 0, 0);
}

// ================= prep: all weight transposes + rope tables + bias pack =================
__global__ __launch_bounds__(256) void prep_kernel(
    const float* __restrict__ Wq, const float* __restrict__ Wk,
    const float* __restrict__ Wv, const float* __restrict__ Wo,
    const float* __restrict__ W1, const float* __restrict__ W2,
    const float* __restrict__ bq, const float* __restrict__ bk,
    const float* __restrict__ bv,
    ushort_t* __restrict__ wt_qkv, ushort_t* __restrict__ wot,
    ushort_t* __restrict__ w1t, ushort_t* __restrict__ w2t,
    float* __restrict__ cosv, float* __restrict__ sinv,
    float* __restrict__ bias_qkv) {
    __shared__ float tile[32][33];
    const int id = blockIdx.x;
    const int tid = threadIdx.x;
    if (id < 12288) {
        const float* in;
        ushort_t* out;
        int R, C, bx, by;
        if (id < 4096) {
            const int w = id >> 10, loc = id & 1023;
            in = (w == 0) ? Wq : (w == 1) ? Wk : (w == 2) ? Wv : Wo;
            out = (w == 3) ? wot : wt_qkv + (size_t)w * 1024 * 1024;
            R = 1024; C = 1024; bx = loc & 31; by = loc >> 5;
        } else if (id < 8192) {
            const int loc = id - 4096;
            in = W1; out = w1t; R = 1024; C = 4096;
            bx = loc & 127; by = loc >> 7;
        } else {
            const int loc = id - 8192;
            in = W2; out = w2t; R = 4096; C = 1024;
            bx = loc & 31; by = loc >> 5;
        }
        const int c0 = bx * 32, r0 = by * 32;
        const int tx = tid & 31, ty = tid >> 5;  // 32 x 8
#pragma unroll
        for (int i = 0; i < 4; ++i)
            tile[ty + i * 8][tx] = in[(size_t)(r0 + ty + i * 8) * C + c0 + tx];
        __syncthreads();
#pragma unroll
        for (int i = 0; i < 4; ++i)
            out[(size_t)(c0 + ty + i * 8) * R + r0 + tx] = f2b(tile[tx][ty + i * 8]);
    } else if (id < 12544) {
        const int idx = (id - 12288) * 256 + tid;  // T*32
        const int i = idx & 31;
        const int t = idx >> 5;
        const float invf = powf(10000.0f, -(float)i / 32.0f);
        const float a = (float)t * invf;
        cosv[idx] = cosf(a);
        sinv[idx] = sinf(a);
    } else {
        const int i = (id - 12544) * 256 + tid;
        if (i < 3072) {
            float v = (i < 1024) ? bq[i] : (i < 2048) ? bk[i - 1024] : bv[i - 2048];
            bias_qkv[i] = v;
        }
    }
}

// ---------------- layernorm fp32 -> bf16, one row (1024) per block ----------------
__global__ __launch_bounds__(256) void ln_kernel(const float* __restrict__ x,
                                                 const float* __restrict__ g,
                                                 const float* __restrict__ bta,
                                                 ushort_t* __restrict__ out) {
    const int row = blockIdx.x;
    const int tid = threadIdx.x;
    const float4 v = *(const float4*)(x + (size_t)row * DIMD + tid * 4);
    float s = v.x + v.y + v.z + v.w;
    float sq = v.x * v.x + v.y * v.y + v.z * v.z + v.w * v.w;
#pragma unroll
    for (int off = 1; off < 64; off <<= 1) {
        s += __shfl_xor(s, off);
        sq += __shfl_xor(sq, off);
    }
    __shared__ float rs[4], rq[4];
    const int wave = tid >> 6;
    if ((tid & 63) == 0) { rs[wave] = s; rq[wave] = sq; }
    __syncthreads();
    s = rs[0] + rs[1] + rs[2] + rs[3];
    sq = rq[0] + rq[1] + rq[2] + rq[3];
    const float mean = s * (1.0f / DIMD);
    const float var = sq * (1.0f / DIMD) - mean * mean;
    const float rstd = rsqrtf(var + 1e-5f);
    const float4 gv = *(const float4*)(g + tid * 4);
    const float4 bv = *(const float4*)(bta + tid * 4);
    ushort_t o[4];
    o[0] = f2b((v.x - mean) * rstd * gv.x + bv.x);
    o[1] = f2b((v.y - mean) * rstd * gv.y + bv.y);
    o[2] = f2b((v.z - mean) * rstd * gv.z + bv.z);
    o[3] = f2b((v.w - mean) * rstd * gv.w + bv.w);
    *(uint2*)(out + (size_t)row * DIMD + tid * 4) = *(uint2*)&o[0];
}

// ================= GEMM 256x256 8-phase (m201 template) + XCD swizzle + split-K =================
template <bool GELU, bool OUTBF16, bool PARTIAL>
__global__ __launch_bounds__(512, 2) void gemm8_kernel(
    const ushort_t* __restrict__ A, const ushort_t* __restrict__ Bt,
    const float* __restrict__ bias,
    float* __restrict__ outf, ushort_t* __restrict__ outb,
    int M, int N, int K, int ldk) {
    __shared__ __align__(16) ushort_t Abuf[2][2][128 * 64];
    __shared__ __align__(16) ushort_t Bbuf[2][2][128 * 64];
    const int tid = threadIdx.x;
    const int lane = tid & 63;
    const int wave = tid >> 6;
    const int wm = wave >> 2;
    const int wn = wave & 3;
    const int kz = blockIdx.z;
    A += (size_t)kz * K;
    Bt += (size_t)kz * K;
    float* outp = PARTIAL ? outf + (size_t)kz * M * N : outf;
    const int nwg = gridDim.x * gridDim.y;
    const int lin = blockIdx.y * gridDim.x + blockIdx.x;
    const int wg = (lin & 7) * (nwg >> 3) + (lin >> 3);
    const int bm = (wg / gridDim.x) * 256;
    const int bn = (wg % gridDim.x) * 256;
    const int lrow = lane & 15;
    const int lk16 = (lane >> 4) << 4;
    const int swz = (lrow & 7) << 4;

    const int srow = (wave << 4) + (lane >> 3);
    const int scol = ((lane & 7) ^ (lane >> 3)) << 4;
    const ushort_t* aLane = A + (size_t)(bm + srow) * ldk + (scol >> 1);
    const ushort_t* bLane = Bt + (size_t)(bn + srow) * ldk + (scol >> 1);
    const size_t h1 = (size_t)128 * ldk;

    char* const stA00 = (char*)&Abuf[0][0][0];
    char* const stA01 = (char*)&Abuf[0][1][0];
    char* const stA10 = (char*)&Abuf[1][0][0];
    char* const stA11 = (char*)&Abuf[1][1][0];
    char* const stB00 = (char*)&Bbuf[0][0][0];
    char* const stB01 = (char*)&Bbuf[0][1][0];
    char* const stB10 = (char*)&Bbuf[1][0][0];
    char* const stB11 = (char*)&Bbuf[1][1][0];
    const char* const ArdB[2] = {(const char*)&Abuf[0][wm][0],
                                 (const char*)&Abuf[1][wm][0]};
    const char* const BrdB[2] = {(const char*)&Bbuf[0][wn >> 1][0],
                                 (const char*)&Bbuf[1][wn >> 1][0]};
    const int brow0 = (wn & 1) * 64;

#define STG(gp, ldsp)                                                  \
    do {                                                               \
        gload16((gp), (ldsp) + (wave << 11));                          \
        gload16((gp) + 8 * (size_t)ldk, (ldsp) + (wave << 11) + 1024); \
    } while (0)

#define RD_A(buf, MH)                                                          \
    _Pragma("unroll") for (int ii = 0; ii < 4; ++ii)                           \
    _Pragma("unroll") for (int ss = 0; ss < 2; ++ss)                           \
        af[ii][ss] = ld8b(ArdB[buf] + ((((MH)*4 + ii) * 16 + lrow) << 7) +     \
                          (((ss * 64) + lk16) ^ swz));

#define RD_B(buf, NH, DST)                                                     \
    _Pragma("unroll") for (int jj = 0; jj < 2; ++jj)                           \
    _Pragma("unroll") for (int ss = 0; ss < 2; ++ss)                           \
        DST[jj][ss] =                                                          \
            ld8b(BrdB[buf] + ((brow0 + ((NH)*2 + jj) * 16 + lrow) << 7) +      \
                 (((ss * 64) + lk16) ^ swz));

#define MMA(MH, NH, BF)                                                        \
    __builtin_amdgcn_s_setprio(1);                                             \
    _Pragma("unroll") for (int ii = 0; ii < 4; ++ii)                           \
    _Pragma("unroll") for (int jj = 0; jj < 2; ++jj)                           \
    _Pragma("unroll") for (int ss = 0; ss < 2; ++ss)                           \
        acc[(MH)*4 + ii][(NH)*2 + jj] = mfma16(                                \
            af[ii][ss], BF[jj][ss], acc[(MH)*4 + ii][(NH)*2 + jj]);            \
    __builtin_amdgcn_s_setprio(0);

#define BAR() __builtin_amdgcn_s_barrier()

#define GITER(t, LAST)                                                         \
    {                                                                          \
        RD_A(0, 0); RD_B(0, 0, bf0);                                           \
        STG(aLane + (size_t)((t) + 1) * 64, stA10);                            \
        BAR(); MMA(0, 0, bf0); BAR();                                          \
        RD_B(0, 1, bf1);                                                       \
        STG(aLane + h1 + (size_t)((t) + 1) * 64, stA11);                       \
        BAR(); MMA(0, 1, bf1); BAR();                                          \
        RD_A(0, 1);                                                            \
        if (!(LAST)) STG(bLane + (size_t)((t) + 2) * 64, stB00);               \
        BAR(); MMA(1, 1, bf1); BAR();                                          \
        if (!(LAST)) STG(bLane + h1 + (size_t)((t) + 2) * 64, stB01);          \
        BAR(); MMA(1, 0, bf0);                                                 \
        if (LAST) { asm volatile("s_waitcnt vmcnt(0)" ::: "memory"); }         \
        else      { asm volatile("s_waitcnt vmcnt(4)" ::: "memory"); }         \
        BAR();                                                                 \
        RD_A(1, 0); RD_B(1, 0, bf0);                                           \
        if (!(LAST)) STG(aLane + (size_t)((t) + 2) * 64, stA00);               \
        BAR(); MMA(0, 0, bf0); BAR();                                          \
        RD_B(1, 1, bf1);                                                       \
        if (!(LAST)) STG(aLane + h1 + (size_t)((t) + 2) * 64, stA01);          \
        BAR(); MMA(0, 1, bf1); BAR();                                          \
        RD_A(1, 1);                                                            \
        if (!(LAST)) STG(bLane + (size_t)((t) + 3) * 64, stB10);               \
        BAR(); MMA(1, 1, bf1); BAR();                                          \
        if (!(LAST)) STG(bLane + h1 + (size_t)((t) + 3) * 64, stB11);          \
        BAR(); MMA(1, 0, bf0);                                                 \
        if (!(LAST)) { asm volatile("s_waitcnt vmcnt(4)" ::: "memory"); }      \
        BAR();                                                                 \
    }

    f32x4 acc[8][4] = {};
    bf16x8 af[4][2], bf0[2][2], bf1[2][2];

    STG(aLane, stA00);
    STG(aLane + h1, stA01);
    STG(bLane, stB00);
    STG(bLane + h1, stB01);
    STG(bLane + 64, stB10);
    STG(bLane + h1 + 64, stB11);
    asm volatile("s_waitcnt vmcnt(4)" ::: "memory");
    BAR();

    const int niter = K >> 7;
    for (int i = 0; i < niter - 1; ++i) GITER(2 * i, false);
    GITER(2 * (niter - 1), true);

#undef GITER
#undef BAR
#undef MMA
#undef RD_B
#undef RD_A
#undef STG

    const int erow = (lane >> 4) << 2;
#pragma unroll
    for (int i = 0; i < 8; ++i) {
#pragma unroll
        for (int j = 0; j < 4; ++j) {
            const int row = bm + wm * 128 + i * 16 + erow;
            const int col = bn + wn * 64 + j * 16 + lrow;
            const float bz = PARTIAL ? 0.0f : bias[col];
#pragma unroll
            for (int q = 0; q < 4; ++q) {
                float v = acc[i][j][q] + bz;
                if (GELU) v = 0.5f * v * (1.0f + erff(v * 0.70710678118f));
                if (OUTBF16)
                    outb[(size_t)(row + q) * N + col] = f2b(v);
                else
                    outp[(size_t)(row + q) * N + col] = v;
            }
        }
    }
}

// ---------------- ff2 split-K reduce: out = x1 + b2 + sum of 4 partials ----------------
__global__ __launch_bounds__(256) void ff2_reduce_kernel(
    const float* __restrict__ parts, const float* __restrict__ x1,
    const float* __restrict__ b2, float* __restrict__ out) {
    const size_t e = ((size_t)blockIdx.x * 256 + threadIdx.x) * 4;
    const size_t np = (size_t)MROWS * DIMD;
    const float4 r = *(const float4*)(x1 + e);
    const float4 bz = *(const float4*)(b2 + (e & (DIMD - 1)));
    const float4 p0 = *(const float4*)(parts + e);
    const float4 p1 = *(const float4*)(parts + np + e);
    const float4 p2 = *(const float4*)(parts + 2 * np + e);
    const float4 p3 = *(const float4*)(parts + 3 * np + e);
    float4 o;
    o.x = r.x + bz.x + ((p0.x + p1.x) + (p2.x + p3.x));
    o.y = r.y + bz.y + ((p0.y + p1.y) + (p2.y + p3.y));
    o.z = r.z + bz.z + ((p0.z + p1.z) + (p2.z + p3.z));
    o.w = r.w + bz.w + ((p0.w + p1.w) + (p2.w + p3.w));
    *(float4*)(out + e) = o;
}

// ================= GEMM p4: 128x64 tile, 4-deep multibuffer (wo-proj) =================
template <bool GELU, bool RES, bool OUTBF16>
__global__ __launch_bounds__(256) void gemm_p4_kernel(
    const ushort_t* __restrict__ A, const ushort_t* __restrict__ Bt,
    const float* __restrict__ bias, const float* __restrict__ res,
    float* __restrict__ outf, ushort_t* __restrict__ outb,
    int M, int N, int K) {
    __shared__ __align__(16) ushort_t Asm[4][128 * 32];
    __shared__ __align__(16) ushort_t Bsm[4][64 * 32];
    const int tid = threadIdx.x;
    const int lane = tid & 63;
    const int wave = tid >> 6;
    const int wm = wave >> 1;
    const int wn = wave & 1;
    const int gx = N >> 6;
    const int nwg = gridDim.x;
    const int lin = blockIdx.x;
    const int wg = (lin & 7) * (nwg >> 3) + (lin >> 3);
    const int bm = (wg / gx) << 7;
    const int bn = (wg % gx) << 6;
    const int lrow = lane & 15;
    const int g = lane >> 4;

    const int r16 = lane >> 2;
    const int scb = (((lane & 3) ^ (r16 & 3)) << 4) >> 1;
    const ushort_t* AgP0 = A + (size_t)(bm + (wave * 2 + 0) * 16 + r16) * K + scb;
    const ushort_t* AgP1 = A + (size_t)(bm + (wave * 2 + 1) * 16 + r16) * K + scb;
    const ushort_t* BgP = Bt + (size_t)(bn + wave * 16 + r16) * K + scb;
    const int dA0 = (wave * 2 + 0) * 1024 + lane * 16;
    const int dA1 = (wave * 2 + 1) * 1024 + lane * 16;
    const int dB = wave * 1024 + lane * 16;

#define P4_STAGE(buf, k0)                            \
    do {                                             \
        gload16(AgP0 + (k0), (char*)Asm[buf] + dA0); \
        gload16(AgP1 + (k0), (char*)Asm[buf] + dA1); \
        gload16(BgP + (k0), (char*)Bsm[buf] + dB);   \
    } while (0)

#define P4_BODY(t)                                                           \
    {                                                                        \
        const int buf = (t) & 3;                                             \
        if ((t) + 3 < nst) P4_STAGE(((t) + 3) & 3, ((t) + 3) << 5);          \
        bf16x8 af[4], bfr[2];                                                \
        _Pragma("unroll") for (int i = 0; i < 4; ++i)                        \
            af[i] = ld8b((char*)Asm[buf] + ((wm * 64 + i * 16 + lrow) << 6) +\
                         ((g * 16) ^ ((lrow & 3) << 4)));                    \
        _Pragma("unroll") for (int j = 0; j < 2; ++j)                        \
            bfr[j] = ld8b((char*)Bsm[buf] + ((wn * 32 + j * 16 + lrow) << 6)+\
                          ((g * 16) ^ ((lrow & 3) << 4)));                   \
        __builtin_amdgcn_s_setprio(1);                                       \
        _Pragma("unroll") for (int i = 0; i < 4; ++i)                        \
        _Pragma("unroll") for (int j = 0; j < 2; ++j)                        \
            acc[i][j] = mfma16(af[i], bfr[j], acc[i][j]);                    \
        __builtin_amdgcn_s_setprio(0);                                       \
    }

    f32x4 acc[4][2] = {};
    const int nst = K >> 5;

    P4_STAGE(0, 0);
    P4_STAGE(1, 32);
    P4_STAGE(2, 64);

    for (int t = 0; t < nst - 2; ++t) {
        asm volatile("s_waitcnt vmcnt(6)" ::: "memory");
        __builtin_amdgcn_s_barrier();
        __builtin_amdgcn_sched_barrier(0);
        P4_BODY(t);
    }
    {
        asm volatile("s_waitcnt vmcnt(3)" ::: "memory");
        __builtin_amdgcn_s_barrier();
        __builtin_amdgcn_sched_barrier(0);
        P4_BODY(nst - 2);
    }
    {
        asm volatile("s_waitcnt vmcnt(0)" ::: "memory");
        __builtin_amdgcn_s_barrier();
        __builtin_amdgcn_sched_barrier(0);
        P4_BODY(nst - 1);
    }
#undef P4_BODY
#undef P4_STAGE

#pragma unroll
    for (int i = 0; i < 4; ++i) {
#pragma unroll
        for (int j = 0; j < 2; ++j) {
#pragma unroll
            for (int q = 0; q < 4; ++q) {
                const int row = bm + wm * 64 + i * 16 + g * 4 + q;
                const int col = bn + wn * 32 + j * 16 + lrow;
                float v = acc[i][j][q] + bias[col];
                if (RES) v += res[(size_t)row * N + col];
                if (GELU) v = 0.5f * v * (1.0f + erff(v * 0.70710678118f));
                if (OUTBF16)
                    outb[(size_t)row * N + col] = f2b(v);
                else
                    outf[(size_t)row * N + col] = v;
            }
        }
    }
}

// ================= fused rope-apply + V-transpose =================
__global__ __launch_bounds__(256) void qkv_post_kernel(
    const ushort_t* __restrict__ qkv, const float* __restrict__ cosv,
    const float* __restrict__ sinv, ushort_t* __restrict__ Qb,
    ushort_t* __restrict__ Kb, ushort_t* __restrict__ VtG) {
    __shared__ ushort_t tile[64][72];
    const int bh = blockIdx.y;
    const int b = bh >> 4, h = bh & 15;
    const int t0 = blockIdx.x * 64;
    const int tid = threadIdx.x;
    {
        const int r = tid >> 2;
        const int i0 = (tid & 3) * 8;
        const int t = t0 + r;
        const size_t rowoff = ((size_t)(b * TLEN + t)) * 3072 + h * 64;
        union { uint4 u; ushort_t s[8]; } q1v, q2v, k1v, k2v;
        q1v.u = *(const uint4*)(qkv + rowoff + i0);
        q2v.u = *(const uint4*)(qkv + rowoff + 32 + i0);
        k1v.u = *(const uint4*)(qkv + rowoff + 1024 + i0);
        k2v.u = *(const uint4*)(qkv + rowoff + 1024 + 32 + i0);
        const size_t ooff = ((size_t)bh * TLEN + t) * 64;
        ushort_t oq1[8], oq2[8], ok1[8], ok2[8];
#pragma unroll
        for (int j = 0; j < 8; ++j) {
            const float c = cosv[t * 32 + i0 + j];
            const float s = sinv[t * 32 + i0 + j];
            const float a1 = b2f(q1v.s[j]), a2 = b2f(q2v.s[j]);
            const float c1 = b2f(k1v.s[j]), c2 = b2f(k2v.s[j]);
            oq1[j] = f2b((a1 * c - a2 * s) * QSCALE);
            oq2[j] = f2b((a2 * c + a1 * s) * QSCALE);
            ok1[j] = f2b(c1 * c - c2 * s);
            ok2[j] = f2b(c2 * c + c1 * s);
        }
        *(uint4*)(Qb + ooff + i0) = *(uint4*)oq1;
        *(uint4*)(Qb + ooff + 32 + i0) = *(uint4*)oq2;
        *(uint4*)(Kb + ooff + i0) = *(uint4*)ok1;
        *(uint4*)(Kb + ooff + 32 + i0) = *(uint4*)ok2;
    }
    {
        const int r = tid >> 2;
        const int dp = (tid & 3) * 16;
        const ushort_t* src =
            qkv + (size_t)(b * TLEN + t0 + r) * 3072 + 2048 + h * 64 + dp;
        *(uint4*)&tile[r][dp] = *(const uint4*)src;
        *(uint4*)&tile[r][dp + 8] = *(const uint4*)(src + 8);
        __syncthreads();
        const int d = tid >> 2;
        const int tp = (tid & 3) * 16;
        ushort_t* dst = VtG + (size_t)bh * HDIM * TLEN + (size_t)d * TLEN + t0 + tp;
        ushort_t tmp[16];
#pragma unroll
        for (int j = 0; j < 16; ++j) tmp[j] = tile[tp + j][d];
        *(uint4*)dst = *(uint4*)&tmp[0];
        *(uint4*)(dst + 8) = *(uint4*)&tmp[8];
    }
}

// ---------------- flash attention v5: 32x32 MFMA, in-register P via permlane32_swap ----------------
// grid 512 (XCD-chunked), 256 thr = 4 waves; wave owns 32 q rows (q = lane&31).
// Swapped QK^T: S^T[key][q] via mfma32(K, Q); P rebuilt with cvtpk+permlane (T12).
__global__ __launch_bounds__(256) void flash_kernel(const ushort_t* __restrict__ Qb,
                                                    const ushort_t* __restrict__ Kb,
                                                    const ushort_t* __restrict__ VtG,
                                                    ushort_t* __restrict__ attn) {
    __shared__ __align__(16) ushort_t Ksm[2][64 * 64];  // [key][d]
    __shared__ __align__(16) ushort_t Vsm[2][64 * 64];  // [d][key]
    const int wg = (blockIdx.x & 7) * 64 + (blockIdx.x >> 3);
    const int bh = wg >> 4;
    const int qblk = wg & 15;
    const int b = bh >> 4, h = bh & 15;
    const int lane = threadIdx.x & 63;
    const int wave = threadIdx.x >> 6;
    const int q0 = qblk * 128 + wave * 32;
    const int lq = lane & 31;   // q column
    const int hl = lane >> 5;   // half

    const ushort_t* Qp = Qb + ((size_t)bh * TLEN + q0) * HDIM;
    const ushort_t* Kp = Kb + (size_t)bh * TLEN * HDIM;
    const ushort_t* Vt = VtG + (size_t)bh * HDIM * TLEN;

    const int ch0 = wave * 2, ch1 = wave * 2 + 1;
    const int so0 = (ch0 << 10) + lane * 16;
    const int so1 = (ch1 << 10) + lane * 16;
    const int sr0 = so0 >> 7, sr1 = so1 >> 7;
    const int cb0 = (so0 & 127) ^ ((sr0 & 7) << 4);
    const int cb1 = (so1 & 127) ^ ((sr1 & 7) << 4);
    const ushort_t* Kg0 = Kp + (size_t)sr0 * HDIM + (cb0 >> 1);
    const ushort_t* Kg1 = Kp + (size_t)sr1 * HDIM + (cb1 >> 1);
    const ushort_t* Vg0 = Vt + (size_t)sr0 * TLEN + (cb0 >> 1);
    const ushort_t* Vg1 = Vt + (size_t)sr1 * TLEN + (cb1 >> 1);

#define FLASH_STAGE(buf, kb)                                               \
    {                                                                      \
        gload16(Kg0 + (size_t)(kb) * HDIM, (char*)Ksm[buf] + (ch0 << 10)); \
        gload16(Kg1 + (size_t)(kb) * HDIM, (char*)Ksm[buf] + (ch1 << 10)); \
        gload16(Vg0 + (kb), (char*)Vsm[buf] + (ch0 << 10));                \
        gload16(Vg1 + (kb), (char*)Vsm[buf] + (ch1 << 10));                \
    }

    // Q as B-operand for 32x32x16: lane -> col=q=lq, k=hl*8+j; 4 d-chunks
    bf16x8 qf[4];
#pragma unroll
    for (int c = 0; c < 4; ++c)
        qf[c] = ld8(Qp + lq * 64 + c * 16 + hl * 8);

    f32x16 oacc[2];
#pragma unroll
    for (int r = 0; r < 16; ++r) { oacc[0][r] = 0.0f; oacc[1][r] = 0.0f; }
    float ls = 0.0f;

    FLASH_STAGE(0, 0);
    __syncthreads();

    for (int it = 0; it < TLEN / 64; ++it) {
        const int buf = it & 1;
        if (it + 1 < TLEN / 64) FLASH_STAGE(buf ^ 1, (it + 1) * 64);

#pragma unroll
        for (int ks2 = 0; ks2 < 2; ++ks2) {
            // QK^T: S[key][q], key = ks2*32 + (reg&3)+8*(reg>>2)+4*hl, q=lq
            const int krow = ks2 * 32 + lq;
            const int swk = (krow & 7) << 4;
            const char* kr = (const char*)(Ksm[buf] + krow * 64);
            f32x16 S;
#pragma unroll
            for (int r = 0; r < 16; ++r) S[r] = -SMAX;
            __builtin_amdgcn_s_setprio(1);
#pragma unroll
            for (int c = 0; c < 4; ++c)
                S = mfma32(ld8b(kr + ((c * 32 + hl * 16) ^ swk)), qf[c], S);
            __builtin_amdgcn_s_setprio(0);
            // softmax (static max folded into C-init)
            float p[16];
#pragma unroll
            for (int r = 0; r < 16; ++r) p[r] = exp2a(S[r]);
#pragma unroll
            for (int r = 0; r < 16; ++r) ls += p[r];
            // P -> B-operand fragments (cvtpk + permlane32_swap, lane keeps q)
            uint_t a0 = cvtpk(p[0], p[1]), a1 = cvtpk(p[2], p[3]);
            uint_t b0 = cvtpk(p[4], p[5]), b1 = cvtpk(p[6], p[7]);
            plswap(a0, b0);
            plswap(a1, b1);
            uint4 w0; w0.x = a0; w0.y = a1; w0.z = b0; w0.w = b1;
            a0 = cvtpk(p[8], p[9]);  a1 = cvtpk(p[10], p[11]);
            b0 = cvtpk(p[12], p[13]); b1 = cvtpk(p[14], p[15]);
            plswap(a0, b0);
            plswap(a1, b1);
            uint4 w1; w1.x = a0; w1.y = a1; w1.z = b0; w1.w = b1;
            const bf16x8 pB0 = __builtin_bit_cast(bf16x8, w0);
            const bf16x8 pB1 = __builtin_bit_cast(bf16x8, w1);
            // PV: O^T[d][q] += V^T[d][key] * P[key][q]
            __builtin_amdgcn_s_setprio(1);
#pragma unroll
            for (int dt = 0; dt < 2; ++dt) {
                const int vrow = dt * 32 + lq;
                const int swv = (vrow & 7) << 4;
                const char* vr = (const char*)(Vsm[buf] + vrow * 64);
                oacc[dt] = mfma32(
                    ld8b(vr + ((ks2 * 64 + hl * 16) ^ swv)), pB0, oacc[dt]);
                oacc[dt] = mfma32(
                    ld8b(vr + ((ks2 * 64 + 32 + hl * 16) ^ swv)), pB1, oacc[dt]);
            }
            __builtin_amdgcn_s_setprio(0);
        }
        __syncthreads();
    }
#undef FLASH_STAGE

    const float l = ls + __shfl_xor(ls, 32);
    const float inv_l = 1.0f / l;
    const int qrow = b * TLEN + q0 + lq;
    ushort_t* op = attn + (size_t)qrow * DIMD + h * HDIM;
#pragma unroll
    for (int dt = 0; dt < 2; ++dt) {
#pragma unroll
        for (int qq = 0; qq < 4; ++qq) {
            ushort_t o4[4];
#pragma unroll
            for (int r = 0; r < 4; ++r)
                o4[r] = f2b(oacc[dt][qq * 4 + r] * inv_l);
            *(uint2*)(op + dt * 32 + qq * 8 + hl * 4) = *(uint2*)&o4[0];
        }
    }
}

extern "C" void kernel_launch(void* const* d_in, const int* in_sizes, int n_in,
                              void* d_out, int out_size, void* d_ws, size_t ws_size,
                              hipStream_t stream) {
    const float* x = (const float*)d_in[0];
    const float* ln1_g = (const float*)d_in[2];
    const float* ln1_b = (const float*)d_in[3];
    const float* Wq = (const float*)d_in[4];
    const float* bq = (const float*)d_in[5];
    const float* Wk = (const float*)d_in[6];
    const float* bk = (const float*)d_in[7];
    const float* Wv = (const float*)d_in[8];
    const float* bv = (const float*)d_in[9];
    const float* Wo = (const float*)d_in[10];
    const float* bo = (const float*)d_in[11];
    const float* ln2_g = (const float*)d_in[12];
    const float* ln2_b = (const float*)d_in[13];
    const float* W1 = (const float*)d_in[14];
    const float* b1 = (const float*)d_in[15];
    const float* W2 = (const float*)d_in[16];
    const float* b2 = (const float*)d_in[17];
    float* out = (float*)d_out;

    char* p = (char*)d_ws;
    ushort_t* wt_qkv = (ushort_t*)p; p += (size_t)3072 * 1024 * 2;
    ushort_t* wot = (ushort_t*)p;    p += (size_t)1024 * 1024 * 2;
    ushort_t* w1t = (ushort_t*)p;    p += (size_t)4096 * 1024 * 2;
    ushort_t* w2t = (ushort_t*)p;    p += (size_t)4096 * 1024 * 2;
    float* cosv = (float*)p;         p += (size_t)TLEN * 32 * 4;
    float* sinv = (float*)p;         p += (size_t)TLEN * 32 * 4;
    float* bias_qkv = (float*)p;     p += 3072 * 4;
    char* reuse0 = p;  // 64MB region reused for ff2 split-K partials
    ushort_t* n1 = (ushort_t*)p;     p += (size_t)MROWS * DIMD * 2;
    ushort_t* qkv = (ushort_t*)p;    p += (size_t)MROWS * 3072 * 2;
    ushort_t* Qb = (ushort_t*)p;     p += (size_t)MROWS * DIMD * 2;
    ushort_t* Kb = (ushort_t*)p;     p += (size_t)MROWS * DIMD * 2;
    ushort_t* VtG = (ushort_t*)p;    p += (size_t)MROWS * DIMD * 2;
    ushort_t* attn = (ushort_t*)p;   p += (size_t)MROWS * DIMD * 2;
    float* x1 = (float*)p;           p += (size_t)MROWS * DIMD * 4;
    ushort_t* n2 = (ushort_t*)p;     p += (size_t)MROWS * DIMD * 2;
    ushort_t* ff1 = (ushort_t*)p;    p += (size_t)MROWS * FFD * 2;
    float* partials = (float*)reuse0;  // 4 x MROWS x DIMD fp32 = 64MB (dead bufs)

    prep_kernel<<<12556, 256, 0, stream>>>(Wq, Wk, Wv, Wo, W1, W2, bq, bk, bv,
                                           wt_qkv, wot, w1t, w2t, cosv, sinv,
                                           bias_qkv);
    ln_kernel<<<MROWS, 256, 0, stream>>>(x, ln1_g, ln1_b, n1);
    gemm8_kernel<false, true, false><<<dim3(3072 / 256, MROWS / 256), 512, 0, stream>>>(
        n1, wt_qkv, bias_qkv, nullptr, qkv, MROWS, 3072, 1024, 1024);
    qkv_post_kernel<<<dim3(TLEN / 64, BATCH * NHEAD), 256, 0, stream>>>(
        qkv, cosv, sinv, Qb, Kb, VtG);
    flash_kernel<<<512, 256, 0, stream>>>(Qb, Kb, VtG, attn);
    gemm_p4_kernel<false, true, false><<<512, 256, 0, stream>>>(
        attn, wot, bo, x, x1, nullptr, MROWS, 1024, 1024);
    ln_kernel<<<MROWS, 256, 0, stream>>>(x1, ln2_g, ln2_b, n2);
    gemm8_kernel<true, true, false><<<dim3(4096 / 256, MROWS / 256), 512, 0, stream>>>(
        n2, w1t, b1, nullptr, ff1, MROWS, 4096, 1024, 1024);
    gemm8_kernel<false, false, true><<<dim3(1024 / 256, MROWS / 256, 4), 512, 0, stream>>>(
        ff1, w2t, nullptr, partials, nullptr, MROWS, 1024, 1024, 4096);
    ff2_reduce_kernel<<<MROWS * DIMD / 1024, 256, 0, stream>>>(partials, x1, b2, out);
}

// Round 9
// 248.747 us; speedup vs baseline: 2.0407x; 1.0816x over previous
//
#include <hip/hip_runtime.h>

typedef unsigned short ushort_t;
typedef unsigned int uint_t;
typedef __bf16 bf16x8 __attribute__((ext_vector_type(8)));
typedef float f32x4 __attribute__((ext_vector_type(4)));
typedef float f32x16 __attribute__((ext_vector_type(16)));
typedef int i32x2 __attribute__((ext_vector_type(2)));

#define DIMD 1024
#define FFD 4096
#define NHEAD 16
#define HDIM 64
#define TLEN 2048
#define BATCH 2
#define MROWS (BATCH * TLEN)  // 4096
// 0.125 * log2(e): folds the 1/sqrt(64) scale and exp->exp2 conversion into Q
#define QSCALE 0.18033688011112042f
// static softmax shift (log2 units): |s| bound ~12, shift is a pure FP rescale
#define SMAX 20.0f

__device__ __forceinline__ ushort_t f2b(float f) {
    uint_t u = __builtin_bit_cast(uint_t, f);
    u = u + 0x7fffu + ((u >> 16) & 1u);
    return (ushort_t)(u >> 16);
}
__device__ __forceinline__ float b2f(ushort_t b) {
    uint_t u = ((uint_t)b) << 16;
    return __builtin_bit_cast(float, u);
}
__device__ __forceinline__ bf16x8 ld8(const ushort_t* p) {
    uint4 v = *(const uint4*)(p);
    return __builtin_bit_cast(bf16x8, v);
}
__device__ __forceinline__ bf16x8 ld8b(const char* p) {
    uint4 v = *(const uint4*)(p);
    return __builtin_bit_cast(bf16x8, v);
}
__device__ __forceinline__ f32x4 mfma16(bf16x8 a, bf16x8 b, f32x4 c) {
    return __builtin_amdgcn_mfma_f32_16x16x32_bf16(a, b, c, 0, 0, 0);
}
__device__ __forceinline__ f32x16 mfma32(bf16x8 a, bf16x8 b, f32x16 c) {
    return __builtin_amdgcn_mfma_f32_32x32x16_bf16(a, b, c, 0, 0, 0);
}
__device__ __forceinline__ uint_t cvtpk(float lo, float hi) {
    uint_t r;
    asm("v_cvt_pk_bf16_f32 %0, %1, %2" : "=v"(r) : "v"(lo), "v"(hi));
    return r;
}
__device__ __forceinline__ void plswap(uint_t& a, uint_t& b) {
    i32x2 r = __builtin_amdgcn_permlane32_swap((int)a, (int)b, false, false);
    a = (uint_t)r.x;
    b = (uint_t)r.y;
}
__device__ __forceinline__ float exp2a(float x) {
    float r;
    asm("v_exp_f32 %0, %1" : "=v"(r) : "v"(x));
    return r;
}
// tanh-form GELU via single v_exp + v_rcp (max abs err ~3e-4)
__device__ __forceinline__ float gelu_fast(float v) {
    const float u = fmaf(0.044715f * v * v, v, v);
    const float t = exp2a(-2.302118131f * u);
    return v * __builtin_amdgcn_rcpf(1.0f + t);
}
__device__ __forceinline__ void gload16(const void* g, void* l) {
    __builtin_amdgcn_global_load_lds(
        (const __attribute__((address_space(1))) void*)g,
        (__attribute__((address_space(3))) void*)l, 16, 0, 0);
}

// ================= prep: all weight transposes + rope tables + bias pack =================
__global__ __launch_bounds__(256) void prep_kernel(
    const float* __restrict__ Wq, const float* __restrict__ Wk,
    const float* __restrict__ Wv, const float* __restrict__ Wo,
    const float* __restrict__ W1, const float* __restrict__ W2,
    const float* __restrict__ bq, const float* __restrict__ bk,
    const float* __restrict__ bv,
    ushort_t* __restrict__ wt_qkv, ushort_t* __restrict__ wot,
    ushort_t* __restrict__ w1t, ushort_t* __restrict__ w2t,
    float* __restrict__ cosv, float* __restrict__ sinv,
    float* __restrict__ bias_qkv) {
    __shared__ float tile[32][33];
    const int id = blockIdx.x;
    const int tid = threadIdx.x;
    if (id < 12288) {
        const float* in;
        ushort_t* out;
        int R, C, bx, by;
        if (id < 4096) {
            const int w = id >> 10, loc = id & 1023;
            in = (w == 0) ? Wq : (w == 1) ? Wk : (w == 2) ? Wv : Wo;
            out = (w == 3) ? wot : wt_qkv + (size_t)w * 1024 * 1024;
            R = 1024; C = 1024; bx = loc & 31; by = loc >> 5;
        } else if (id < 8192) {
            const int loc = id - 4096;
            in = W1; out = w1t; R = 1024; C = 4096;
            bx = loc & 127; by = loc >> 7;
        } else {
            const int loc = id - 8192;
            in = W2; out = w2t; R = 4096; C = 1024;
            bx = loc & 31; by = loc >> 5;
        }
        const int c0 = bx * 32, r0 = by * 32;
        const int tx = tid & 31, ty = tid >> 5;  // 32 x 8
#pragma unroll
        for (int i = 0; i < 4; ++i)
            tile[ty + i * 8][tx] = in[(size_t)(r0 + ty + i * 8) * C + c0 + tx];
        __syncthreads();
#pragma unroll
        for (int i = 0; i < 4; ++i)
            out[(size_t)(c0 + ty + i * 8) * R + r0 + tx] = f2b(tile[tx][ty + i * 8]);
    } else if (id < 12544) {
        const int idx = (id - 12288) * 256 + tid;  // T*32
        const int i = idx & 31;
        const int t = idx >> 5;
        const float invf = powf(10000.0f, -(float)i / 32.0f);
        const float a = (float)t * invf;
        cosv[idx] = cosf(a);
        sinv[idx] = sinf(a);
    } else {
        const int i = (id - 12544) * 256 + tid;
        if (i < 3072) {
            float v = (i < 1024) ? bq[i] : (i < 2048) ? bk[i - 1024] : bv[i - 2048];
            bias_qkv[i] = v;
        }
    }
}

// ---------------- layernorm fp32 -> bf16, one row (1024) per block ----------------
__global__ __launch_bounds__(256) void ln_kernel(const float* __restrict__ x,
                                                 const float* __restrict__ g,
                                                 const float* __restrict__ bta,
                                                 ushort_t* __restrict__ out) {
    const int row = blockIdx.x;
    const int tid = threadIdx.x;
    const float4 v = *(const float4*)(x + (size_t)row * DIMD + tid * 4);
    float s = v.x + v.y + v.z + v.w;
    float sq = v.x * v.x + v.y * v.y + v.z * v.z + v.w * v.w;
#pragma unroll
    for (int off = 1; off < 64; off <<= 1) {
        s += __shfl_xor(s, off);
        sq += __shfl_xor(sq, off);
    }
    __shared__ float rs[4], rq[4];
    const int wave = tid >> 6;
    if ((tid & 63) == 0) { rs[wave] = s; rq[wave] = sq; }
    __syncthreads();
    s = rs[0] + rs[1] + rs[2] + rs[3];
    sq = rq[0] + rq[1] + rq[2] + rq[3];
    const float mean = s * (1.0f / DIMD);
    const float var = sq * (1.0f / DIMD) - mean * mean;
    const float rstd = rsqrtf(var + 1e-5f);
    const float4 gv = *(const float4*)(g + tid * 4);
    const float4 bv = *(const float4*)(bta + tid * 4);
    ushort_t o[4];
    o[0] = f2b((v.x - mean) * rstd * gv.x + bv.x);
    o[1] = f2b((v.y - mean) * rstd * gv.y + bv.y);
    o[2] = f2b((v.z - mean) * rstd * gv.z + bv.z);
    o[3] = f2b((v.w - mean) * rstd * gv.w + bv.w);
    *(uint2*)(out + (size_t)row * DIMD + tid * 4) = *(uint2*)&o[0];
}

// ================= GEMM d2: m97 structure =================
// 128x128 tile, BK=64, SINGLE 32KB LDS buffer, 2 barriers/K-step.
// __launch_bounds__(256,3) -> VGPR<=170 -> 3 blocks/CU (12 waves): barrier
// drains hidden by co-resident blocks (m114 mechanism, m97: 874 TF).
// Both-sides (r&7)<<4 swizzle; XCD-chunked block swizzle; split-K via blockIdx.z.
template <bool GELU, bool OUTBF16, bool PARTIAL>
__global__ __launch_bounds__(256, 3) void gemm_d2_kernel(
    const ushort_t* __restrict__ A, const ushort_t* __restrict__ Bt,
    const float* __restrict__ bias,
    float* __restrict__ outf, ushort_t* __restrict__ outb,
    int M, int N, int K, int ldk) {
    __shared__ __align__(16) ushort_t Asm[128 * 64];
    __shared__ __align__(16) ushort_t Bsm[128 * 64];
    const int tid = threadIdx.x;
    const int lane = tid & 63;
    const int wave = tid >> 6;
    const int wr = (wave >> 1) * 64;
    const int wc = (wave & 1) * 64;
    const int kz = blockIdx.z;
    A += (size_t)kz * K;
    Bt += (size_t)kz * K;
    float* outp = PARTIAL ? outf + (size_t)kz * M * N : outf;
    const int nwg = gridDim.x * gridDim.y;
    const int lin = blockIdx.y * gridDim.x + blockIdx.x;
    const int wg = (lin & 7) * (nwg >> 3) + (lin >> 3);
    const int bm = (wg / gridDim.x) * 128;
    const int bn = (wg % gridDim.x) * 128;
    const int lrow = lane & 15;
    const int lkb = (lane >> 4) << 4;  // k-group byte offset

    // staging: pass j covers LDS bytes [j*4096 + tid*16]; row = byte>>7
    const int so = tid * 16;
    const int srow0 = so >> 7;  // 0..31
    const int scolb = (so & 127) ^ ((srow0 & 7) << 4);  // pre-swizzled src col
    const ushort_t* Ag = A + (size_t)(bm + srow0) * ldk + (scolb >> 1);
    const ushort_t* Bg = Bt + (size_t)(bn + srow0) * ldk + (scolb >> 1);

    f32x4 acc[4][4] = {};
    const int nst = K >> 6;

    for (int t = 0; t < nst; ++t) {
        const int k0 = t << 6;
        __syncthreads();  // prev iteration's LDS reads done
#pragma unroll
        for (int j = 0; j < 4; ++j) {
            gload16(Ag + (size_t)j * 32 * ldk + k0, (char*)Asm + j * 4096 + so);
            gload16(Bg + (size_t)j * 32 * ldk + k0, (char*)Bsm + j * 4096 + so);
        }
        __syncthreads();  // vmcnt(0) drain (hidden by co-resident blocks)
#pragma unroll
        for (int ss = 0; ss < 2; ++ss) {
            bf16x8 af[4], bfr[4];
#pragma unroll
            for (int i = 0; i < 4; ++i) {
                const int r = wr + i * 16 + lrow;
                af[i] = ld8b((char*)Asm + (r << 7) +
                             ((ss * 64 + lkb) ^ ((r & 7) << 4)));
            }
#pragma unroll
            for (int j = 0; j < 4; ++j) {
                const int r = wc + j * 16 + lrow;
                bfr[j] = ld8b((char*)Bsm + (r << 7) +
                              ((ss * 64 + lkb) ^ ((r & 7) << 4)));
            }
            __builtin_amdgcn_s_setprio(1);
#pragma unroll
            for (int i = 0; i < 4; ++i)
#pragma unroll
                for (int j = 0; j < 4; ++j)
                    acc[i][j] = mfma16(af[i], bfr[j], acc[i][j]);
            __builtin_amdgcn_s_setprio(0);
        }
    }

    const int lr4 = (lane >> 4) * 4;
#pragma unroll
    for (int i = 0; i < 4; ++i) {
#pragma unroll
        for (int j = 0; j < 4; ++j) {
            const int col = bn + wc + j * 16 + lrow;
            const float bz = PARTIAL ? 0.0f : bias[col];
#pragma unroll
            for (int q = 0; q < 4; ++q) {
                const int row = bm + wr + i * 16 + lr4 + q;
                float v = acc[i][j][q] + bz;
                if (GELU) v = gelu_fast(v);
                if (OUTBF16)
                    outb[(size_t)row * N + col] = f2b(v);
                else
                    outp[(size_t)row * N + col] = v;
            }
        }
    }
}

// ---------------- ff2 split-K reduce: out = x1 + b2 + sum of 4 partials ----------------
__global__ __launch_bounds__(256) void ff2_reduce_kernel(
    const float* __restrict__ parts, const float* __restrict__ x1,
    const float* __restrict__ b2, float* __restrict__ out) {
    const size_t e = ((size_t)blockIdx.x * 256 + threadIdx.x) * 4;
    const size_t np = (size_t)MROWS * DIMD;
    const float4 r = *(const float4*)(x1 + e);
    const float4 bz = *(const float4*)(b2 + (e & (DIMD - 1)));
    const float4 p0 = *(const float4*)(parts + e);
    const float4 p1 = *(const float4*)(parts + np + e);
    const float4 p2 = *(const float4*)(parts + 2 * np + e);
    const float4 p3 = *(const float4*)(parts + 3 * np + e);
    float4 o;
    o.x = r.x + bz.x + ((p0.x + p1.x) + (p2.x + p3.x));
    o.y = r.y + bz.y + ((p0.y + p1.y) + (p2.y + p3.y));
    o.z = r.z + bz.z + ((p0.z + p1.z) + (p2.z + p3.z));
    o.w = r.w + bz.w + ((p0.w + p1.w) + (p2.w + p3.w));
    *(float4*)(out + e) = o;
}

// ================= GEMM p4: 128x64 tile, 4-deep multibuffer (wo-proj) =================
template <bool GELU, bool RES, bool OUTBF16>
__global__ __launch_bounds__(256) void gemm_p4_kernel(
    const ushort_t* __restrict__ A, const ushort_t* __restrict__ Bt,
    const float* __restrict__ bias, const float* __restrict__ res,
    float* __restrict__ outf, ushort_t* __restrict__ outb,
    int M, int N, int K) {
    __shared__ __align__(16) ushort_t Asm[4][128 * 32];
    __shared__ __align__(16) ushort_t Bsm[4][64 * 32];
    const int tid = threadIdx.x;
    const int lane = tid & 63;
    const int wave = tid >> 6;
    const int wm = wave >> 1;
    const int wn = wave & 1;
    const int gx = N >> 6;
    const int nwg = gridDim.x;
    const int lin = blockIdx.x;
    const int wg = (lin & 7) * (nwg >> 3) + (lin >> 3);
    const int bm = (wg / gx) << 7;
    const int bn = (wg % gx) << 6;
    const int lrow = lane & 15;
    const int g = lane >> 4;

    const int r16 = lane >> 2;
    const int scb = (((lane & 3) ^ (r16 & 3)) << 4) >> 1;
    const ushort_t* AgP0 = A + (size_t)(bm + (wave * 2 + 0) * 16 + r16) * K + scb;
    const ushort_t* AgP1 = A + (size_t)(bm + (wave * 2 + 1) * 16 + r16) * K + scb;
    const ushort_t* BgP = Bt + (size_t)(bn + wave * 16 + r16) * K + scb;
    const int dA0 = (wave * 2 + 0) * 1024 + lane * 16;
    const int dA1 = (wave * 2 + 1) * 1024 + lane * 16;
    const int dB = wave * 1024 + lane * 16;

#define P4_STAGE(buf, k0)                            \
    do {                                             \
        gload16(AgP0 + (k0), (char*)Asm[buf] + dA0); \
        gload16(AgP1 + (k0), (char*)Asm[buf] + dA1); \
        gload16(BgP + (k0), (char*)Bsm[buf] + dB);   \
    } while (0)

#define P4_BODY(t)                                                           \
    {                                                                        \
        const int buf = (t) & 3;                                             \
        if ((t) + 3 < nst) P4_STAGE(((t) + 3) & 3, ((t) + 3) << 5);          \
        bf16x8 af[4], bfr[2];                                                \
        _Pragma("unroll") for (int i = 0; i < 4; ++i)                        \
            af[i] = ld8b((char*)Asm[buf] + ((wm * 64 + i * 16 + lrow) << 6) +\
                         ((g * 16) ^ ((lrow & 3) << 4)));                    \
        _Pragma("unroll") for (int j = 0; j < 2; ++j)                        \
            bfr[j] = ld8b((char*)Bsm[buf] + ((wn * 32 + j * 16 + lrow) << 6)+\
                          ((g * 16) ^ ((lrow & 3) << 4)));                   \
        __builtin_amdgcn_s_setprio(1);                                       \
        _Pragma("unroll") for (int i = 0; i < 4; ++i)                        \
        _Pragma("unroll") for (int j = 0; j < 2; ++j)                        \
            acc[i][j] = mfma16(af[i], bfr[j], acc[i][j]);                    \
        __builtin_amdgcn_s_setprio(0);                                       \
    }

    f32x4 acc[4][2] = {};
    const int nst = K >> 5;

    P4_STAGE(0, 0);
    P4_STAGE(1, 32);
    P4_STAGE(2, 64);

    for (int t = 0; t < nst - 2; ++t) {
        asm volatile("s_waitcnt vmcnt(6)" ::: "memory");
        __builtin_amdgcn_s_barrier();
        __builtin_amdgcn_sched_barrier(0);
        P4_BODY(t);
    }
    {
        asm volatile("s_waitcnt vmcnt(3)" ::: "memory");
        __builtin_amdgcn_s_barrier();
        __builtin_amdgcn_sched_barrier(0);
        P4_BODY(nst - 2);
    }
    {
        asm volatile("s_waitcnt vmcnt(0)" ::: "memory");
        __builtin_amdgcn_s_barrier();
        __builtin_amdgcn_sched_barrier(0);
        P4_BODY(nst - 1);
    }
#undef P4_BODY
#undef P4_STAGE

#pragma unroll
    for (int i = 0; i < 4; ++i) {
#pragma unroll
        for (int j = 0; j < 2; ++j) {
#pragma unroll
            for (int q = 0; q < 4; ++q) {
                const int row = bm + wm * 64 + i * 16 + g * 4 + q;
                const int col = bn + wn * 32 + j * 16 + lrow;
                float v = acc[i][j][q] + bias[col];
                if (RES) v += res[(size_t)row * N + col];
                if (GELU) v = gelu_fast(v);
                if (OUTBF16)
                    outb[(size_t)row * N + col] = f2b(v);
                else
                    outf[(size_t)row * N + col] = v;
            }
        }
    }
}

// ================= fused rope-apply + V-transpose =================
__global__ __launch_bounds__(256) void qkv_post_kernel(
    const ushort_t* __restrict__ qkv, const float* __restrict__ cosv,
    const float* __restrict__ sinv, ushort_t* __restrict__ Qb,
    ushort_t* __restrict__ Kb, ushort_t* __restrict__ VtG) {
    __shared__ ushort_t tile[64][72];
    const int bh = blockIdx.y;
    const int b = bh >> 4, h = bh & 15;
    const int t0 = blockIdx.x * 64;
    const int tid = threadIdx.x;
    {
        const int r = tid >> 2;
        const int i0 = (tid & 3) * 8;
        const int t = t0 + r;
        const size_t rowoff = ((size_t)(b * TLEN + t)) * 3072 + h * 64;
        union { uint4 u; ushort_t s[8]; } q1v, q2v, k1v, k2v;
        q1v.u = *(const uint4*)(qkv + rowoff + i0);
        q2v.u = *(const uint4*)(qkv + rowoff + 32 + i0);
        k1v.u = *(const uint4*)(qkv + rowoff + 1024 + i0);
        k2v.u = *(const uint4*)(qkv + rowoff + 1024 + 32 + i0);
        const size_t ooff = ((size_t)bh * TLEN + t) * 64;
        ushort_t oq1[8], oq2[8], ok1[8], ok2[8];
#pragma unroll
        for (int j = 0; j < 8; ++j) {
            const float c = cosv[t * 32 + i0 + j];
            const float s = sinv[t * 32 + i0 + j];
            const float a1 = b2f(q1v.s[j]), a2 = b2f(q2v.s[j]);
            const float c1 = b2f(k1v.s[j]), c2 = b2f(k2v.s[j]);
            oq1[j] = f2b((a1 * c - a2 * s) * QSCALE);
            oq2[j] = f2b((a2 * c + a1 * s) * QSCALE);
            ok1[j] = f2b(c1 * c - c2 * s);
            ok2[j] = f2b(c2 * c + c1 * s);
        }
        *(uint4*)(Qb + ooff + i0) = *(uint4*)oq1;
        *(uint4*)(Qb + ooff + 32 + i0) = *(uint4*)oq2;
        *(uint4*)(Kb + ooff + i0) = *(uint4*)ok1;
        *(uint4*)(Kb + ooff + 32 + i0) = *(uint4*)ok2;
    }
    {
        const int r = tid >> 2;
        const int dp = (tid & 3) * 16;
        const ushort_t* src =
            qkv + (size_t)(b * TLEN + t0 + r) * 3072 + 2048 + h * 64 + dp;
        *(uint4*)&tile[r][dp] = *(const uint4*)src;
        *(uint4*)&tile[r][dp + 8] = *(const uint4*)(src + 8);
        __syncthreads();
        const int d = tid >> 2;
        const int tp = (tid & 3) * 16;
        ushort_t* dst = VtG + (size_t)bh * HDIM * TLEN + (size_t)d * TLEN + t0 + tp;
        ushort_t tmp[16];
#pragma unroll
        for (int j = 0; j < 16; ++j) tmp[j] = tile[tp + j][d];
        *(uint4*)dst = *(uint4*)&tmp[0];
        *(uint4*)(dst + 8) = *(uint4*)&tmp[8];
    }
}

// ---------------- flash attention v5: 32x32 MFMA, in-register P via permlane32_swap ----------------
__global__ __launch_bounds__(256) void flash_kernel(const ushort_t* __restrict__ Qb,
                                                    const ushort_t* __restrict__ Kb,
                                                    const ushort_t* __restrict__ VtG,
                                                    ushort_t* __restrict__ attn) {
    __shared__ __align__(16) ushort_t Ksm[2][64 * 64];  // [key][d]
    __shared__ __align__(16) ushort_t Vsm[2][64 * 64];  // [d][key]
    const int wg = (blockIdx.x & 7) * 64 + (blockIdx.x >> 3);
    const int bh = wg >> 4;
    const int qblk = wg & 15;
    const int b = bh >> 4, h = bh & 15;
    const int lane = threadIdx.x & 63;
    const int wave = threadIdx.x >> 6;
    const int q0 = qblk * 128 + wave * 32;
    const int lq = lane & 31;
    const int hl = lane >> 5;

    const ushort_t* Qp = Qb + ((size_t)bh * TLEN + q0) * HDIM;
    const ushort_t* Kp = Kb + (size_t)bh * TLEN * HDIM;
    const ushort_t* Vt = VtG + (size_t)bh * HDIM * TLEN;

    const int ch0 = wave * 2, ch1 = wave * 2 + 1;
    const int so0 = (ch0 << 10) + lane * 16;
    const int so1 = (ch1 << 10) + lane * 16;
    const int sr0 = so0 >> 7, sr1 = so1 >> 7;
    const int cb0 = (so0 & 127) ^ ((sr0 & 7) << 4);
    const int cb1 = (so1 & 127) ^ ((sr1 & 7) << 4);
    const ushort_t* Kg0 = Kp + (size_t)sr0 * HDIM + (cb0 >> 1);
    const ushort_t* Kg1 = Kp + (size_t)sr1 * HDIM + (cb1 >> 1);
    const ushort_t* Vg0 = Vt + (size_t)sr0 * TLEN + (cb0 >> 1);
    const ushort_t* Vg1 = Vt + (size_t)sr1 * TLEN + (cb1 >> 1);

#define FLASH_STAGE(buf, kb)                                               \
    {                                                                      \
        gload16(Kg0 + (size_t)(kb) * HDIM, (char*)Ksm[buf] + (ch0 << 10)); \
        gload16(Kg1 + (size_t)(kb) * HDIM, (char*)Ksm[buf] + (ch1 << 10)); \
        gload16(Vg0 + (kb), (char*)Vsm[buf] + (ch0 << 10));                \
        gload16(Vg1 + (kb), (char*)Vsm[buf] + (ch1 << 10));                \
    }

    bf16x8 qf[4];
#pragma unroll
    for (int c = 0; c < 4; ++c)
        qf[c] = ld8(Qp + lq * 64 + c * 16 + hl * 8);

    f32x16 oacc[2];
#pragma unroll
    for (int r = 0; r < 16; ++r) { oacc[0][r] = 0.0f; oacc[1][r] = 0.0f; }
    float ls = 0.0f;

    FLASH_STAGE(0, 0);
    __syncthreads();

    for (int it = 0; it < TLEN / 64; ++it) {
        const int buf = it & 1;
        if (it + 1 < TLEN / 64) FLASH_STAGE(buf ^ 1, (it + 1) * 64);

#pragma unroll
        for (int ks2 = 0; ks2 < 2; ++ks2) {
            const int krow = ks2 * 32 + lq;
            const int swk = (krow & 7) << 4;
            const char* kr = (const char*)(Ksm[buf] + krow * 64);
            f32x16 S;
#pragma unroll
            for (int r = 0; r < 16; ++r) S[r] = -SMAX;
            __builtin_amdgcn_s_setprio(1);
#pragma unroll
            for (int c = 0; c < 4; ++c)
                S = mfma32(ld8b(kr + ((c * 32 + hl * 16) ^ swk)), qf[c], S);
            __builtin_amdgcn_s_setprio(0);
            float p[16];
#pragma unroll
            for (int r = 0; r < 16; ++r) p[r] = exp2a(S[r]);
#pragma unroll
            for (int r = 0; r < 16; ++r) ls += p[r];
            uint_t a0 = cvtpk(p[0], p[1]), a1 = cvtpk(p[2], p[3]);
            uint_t b0 = cvtpk(p[4], p[5]), b1 = cvtpk(p[6], p[7]);
            plswap(a0, b0);
            plswap(a1, b1);
            uint4 w0; w0.x = a0; w0.y = a1; w0.z = b0; w0.w = b1;
            a0 = cvtpk(p[8], p[9]);  a1 = cvtpk(p[10], p[11]);
            b0 = cvtpk(p[12], p[13]); b1 = cvtpk(p[14], p[15]);
            plswap(a0, b0);
            plswap(a1, b1);
            uint4 w1; w1.x = a0; w1.y = a1; w1.z = b0; w1.w = b1;
            const bf16x8 pB0 = __builtin_bit_cast(bf16x8, w0);
            const bf16x8 pB1 = __builtin_bit_cast(bf16x8, w1);
            __builtin_amdgcn_s_setprio(1);
#pragma unroll
            for (int dt = 0; dt < 2; ++dt) {
                const int vrow = dt * 32 + lq;
                const int swv = (vrow & 7) << 4;
                const char* vr = (const char*)(Vsm[buf] + vrow * 64);
                oacc[dt] = mfma32(
                    ld8b(vr + ((ks2 * 64 + hl * 16) ^ swv)), pB0, oacc[dt]);
                oacc[dt] = mfma32(
                    ld8b(vr + ((ks2 * 64 + 32 + hl * 16) ^ swv)), pB1, oacc[dt]);
            }
            __builtin_amdgcn_s_setprio(0);
        }
        __syncthreads();
    }
#undef FLASH_STAGE

    const float l = ls + __shfl_xor(ls, 32);
    const float inv_l = 1.0f / l;
    const int qrow = b * TLEN + q0 + lq;
    ushort_t* op = attn + (size_t)qrow * DIMD + h * HDIM;
#pragma unroll
    for (int dt = 0; dt < 2; ++dt) {
#pragma unroll
        for (int qq = 0; qq < 4; ++qq) {
            ushort_t o4[4];
#pragma unroll
            for (int r = 0; r < 4; ++r)
                o4[r] = f2b(oacc[dt][qq * 4 + r] * inv_l);
            *(uint2*)(op + dt * 32 + qq * 8 + hl * 4) = *(uint2*)&o4[0];
        }
    }
}

extern "C" void kernel_launch(void* const* d_in, const int* in_sizes, int n_in,
                              void* d_out, int out_size, void* d_ws, size_t ws_size,
                              hipStream_t stream) {
    const float* x = (const float*)d_in[0];
    const float* ln1_g = (const float*)d_in[2];
    const float* ln1_b = (const float*)d_in[3];
    const float* Wq = (const float*)d_in[4];
    const float* bq = (const float*)d_in[5];
    const float* Wk = (const float*)d_in[6];
    const float* bk = (const float*)d_in[7];
    const float* Wv = (const float*)d_in[8];
    const float* bv = (const float*)d_in[9];
    const float* Wo = (const float*)d_in[10];
    const float* bo = (const float*)d_in[11];
    const float* ln2_g = (const float*)d_in[12];
    const float* ln2_b = (const float*)d_in[13];
    const float* W1 = (const float*)d_in[14];
    const float* b1 = (const float*)d_in[15];
    const float* W2 = (const float*)d_in[16];
    const float* b2 = (const float*)d_in[17];
    float* out = (float*)d_out;

    char* p = (char*)d_ws;
    ushort_t* wt_qkv = (ushort_t*)p; p += (size_t)3072 * 1024 * 2;
    ushort_t* wot = (ushort_t*)p;    p += (size_t)1024 * 1024 * 2;
    ushort_t* w1t = (ushort_t*)p;    p += (size_t)4096 * 1024 * 2;
    ushort_t* w2t = (ushort_t*)p;    p += (size_t)4096 * 1024 * 2;
    float* cosv = (float*)p;         p += (size_t)TLEN * 32 * 4;
    float* sinv = (float*)p;         p += (size_t)TLEN * 32 * 4;
    float* bias_qkv = (float*)p;     p += 3072 * 4;
    char* reuse0 = p;  // 64MB region reused for ff2 split-K partials
    ushort_t* n1 = (ushort_t*)p;     p += (size_t)MROWS * DIMD * 2;
    ushort_t* qkv = (ushort_t*)p;    p += (size_t)MROWS * 3072 * 2;
    ushort_t* Qb = (ushort_t*)p;     p += (size_t)MROWS * DIMD * 2;
    ushort_t* Kb = (ushort_t*)p;     p += (size_t)MROWS * DIMD * 2;
    ushort_t* VtG = (ushort_t*)p;    p += (size_t)MROWS * DIMD * 2;
    ushort_t* attn = (ushort_t*)p;   p += (size_t)MROWS * DIMD * 2;
    float* x1 = (float*)p;           p += (size_t)MROWS * DIMD * 4;
    ushort_t* n2 = (ushort_t*)p;     p += (size_t)MROWS * DIMD * 2;
    ushort_t* ff1 = (ushort_t*)p;    p += (size_t)MROWS * FFD * 2;
    float* partials = (float*)reuse0;  // 4 x MROWS x DIMD fp32 (dead bufs)

    prep_kernel<<<12556, 256, 0, stream>>>(Wq, Wk, Wv, Wo, W1, W2, bq, bk, bv,
                                           wt_qkv, wot, w1t, w2t, cosv, sinv,
                                           bias_qkv);
    ln_kernel<<<MROWS, 256, 0, stream>>>(x, ln1_g, ln1_b, n1);
    gemm_d2_kernel<false, true, false><<<dim3(3072 / 128, MROWS / 128), 256, 0, stream>>>(
        n1, wt_qkv, bias_qkv, nullptr, qkv, MROWS, 3072, 1024, 1024);
    qkv_post_kernel<<<dim3(TLEN / 64, BATCH * NHEAD), 256, 0, stream>>>(
        qkv, cosv, sinv, Qb, Kb, VtG);
    flash_kernel<<<512, 256, 0, stream>>>(Qb, Kb, VtG, attn);
    gemm_p4_kernel<false, true, false><<<512, 256, 0, stream>>>(
        attn, wot, bo, x, x1, nullptr, MROWS, 1024, 1024);
    ln_kernel<<<MROWS, 256, 0, stream>>>(x1, ln2_g, ln2_b, n2);
    gemm_d2_kernel<true, true, false><<<dim3(4096 / 128, MROWS / 128), 256, 0, stream>>>(
        n2, w1t, b1, nullptr, ff1, MROWS, 4096, 1024, 1024);
    gemm_d2_kernel<false, false, true><<<dim3(1024 / 128, MROWS / 128, 4), 256, 0, stream>>>(
        ff1, w2t, nullptr, partials, nullptr, MROWS, 1024, 1024, 4096);
    ff2_reduce_kernel<<<MROWS * DIMD / 1024, 256, 0, stream>>>(partials, x1, b2, out);
}